// Round 10
// baseline (1020.279 us; speedup 1.0000x reference)
//
#include <hip/hip_runtime.h>
#include <math.h>

#define SEQL 512
#define DMOD 512
#define NHEAD 8
#define DHEAD 64
#define DFFN 2048
#define NBATCH 4
#define NVARS 7
#define NBV 28          // NBATCH*NVARS
#define NBH 224         // NBV*NHEAD
#define NROWS 14336     // NBV*SEQL
#define NSAMP 35        // U_part = u = 35
#define NPRED 96
#define SBIG 7340032    // NBV*SEQL*DMOD floats
#define QKS 1024        // fused QK row stride

typedef short bf16x8 __attribute__((ext_vector_type(8)));
typedef float f32x4 __attribute__((ext_vector_type(4)));

#define GLDS(gptr, lptr) \
  __builtin_amdgcn_global_load_lds((const __attribute__((address_space(1))) void*)(gptr), \
                                   (__attribute__((address_space(3))) void*)(lptr), 16, 0, 0)

__device__ inline unsigned short f2b(float f) {
  unsigned u = __builtin_bit_cast(unsigned, f);
  unsigned r = (u + 0x7FFFu + ((u >> 16) & 1u)) >> 16;
  return (unsigned short)r;
}
__device__ inline float b2f(unsigned short h) {
  return __builtin_bit_cast(float, (unsigned)h << 16);
}

// ---------------- threefry2x32 (matches jax._src.prng) ----------------
__device__ inline void threefry2x32(unsigned k0, unsigned k1,
                                    unsigned x0, unsigned x1,
                                    unsigned &o0, unsigned &o1) {
  unsigned ks2 = k0 ^ k1 ^ 0x1BD11BDAu;
  unsigned ks[3] = {k0, k1, ks2};
  x0 += k0; x1 += k1;
  const unsigned rot[2][4] = {{13u,15u,26u,6u},{17u,29u,16u,24u}};
  #pragma unroll
  for (int i = 0; i < 5; ++i) {
    #pragma unroll
    for (int j = 0; j < 4; ++j) {
      unsigned r = rot[i & 1][j];
      x0 += x1;
      x1 = (x1 << r) | (x1 >> (32u - r));
      x1 ^= x0;
    }
    x0 += ks[(i + 1) % 3];
    x1 += ks[(i + 2) % 3] + (unsigned)(i + 1);
  }
  o0 = x0; o1 = x1;
}

__global__ void make_idx_kernel(int layer, int* idx) {
  int i = blockIdx.x * 256 + threadIdx.x;
  if (i >= SEQL * NSAMP) return;
  unsigned kl0, kl1, o0, o1;
  threefry2x32(0u, 42u, 0u, (unsigned)layer, kl0, kl1);
  threefry2x32(kl0, kl1, (unsigned)i, (unsigned)(SEQL * NSAMP + i), o0, o1);
  idx[i] = (int)(o1 & 511u);
}

// ---------------- embedding (vectorized, fused hi/lo split) ----------------
__global__ void embed_kernel(const float* __restrict__ x_enc,
                             const float* __restrict__ w_emb,
                             const float* __restrict__ b_emb,
                             const float* __restrict__ w_pos,
                             float* __restrict__ h,
                             unsigned short* __restrict__ h_hi,
                             unsigned short* __restrict__ h_lo) {
  size_t i = (size_t)blockIdx.x * 256 + threadIdx.x;
  if (i >= (size_t)(SBIG / 4)) return;
  size_t e = i * 4;
  int dm = (int)(e & 511);
  int l  = (int)((e >> 9) & 511);
  int bv = (int)(e >> 18);
  int b = bv / NVARS, v = bv % NVARS;
  float xs = x_enc[((size_t)b * SEQL + l) * NVARS + v];
  float4 we = *(const float4*)(w_emb + dm);
  float4 bb = *(const float4*)(b_emb + dm);
  float4 wp = *(const float4*)(w_pos + (size_t)l * DMOD + dm);
  float4 val;
  val.x = xs * we.x + bb.x + wp.x;
  val.y = xs * we.y + bb.y + wp.y;
  val.z = xs * we.z + bb.z + wp.z;
  val.w = xs * we.w + bb.w + wp.w;
  *(float4*)(h + e) = val;
  ushort4 hi4, lo4;
  hi4.x = f2b(val.x); lo4.x = f2b(val.x - b2f(hi4.x));
  hi4.y = f2b(val.y); lo4.y = f2b(val.y - b2f(hi4.y));
  hi4.z = f2b(val.z); lo4.z = f2b(val.z - b2f(hi4.z));
  hi4.w = f2b(val.w); lo4.w = f2b(val.w - b2f(hi4.w));
  *(ushort4*)(h_hi + e) = hi4;
  *(ushort4*)(h_lo + e) = lo4;
}

// ---------------- fused per-layer weight prep (one dispatch) ----------------
__global__ void prep_weights(const float* __restrict__ Wq, const float* __restrict__ Wk,
                             const float* __restrict__ Wv, const float* __restrict__ Wo,
                             const float* __restrict__ W1, const float* __restrict__ W2,
                             unsigned short* __restrict__ Wqk_hi, unsigned short* __restrict__ Wqk_lo,
                             unsigned short* __restrict__ Wv_b, unsigned short* __restrict__ Wo_b,
                             unsigned short* __restrict__ W1_b, unsigned short* __restrict__ W2_b) {
  const int Q4 = 65536;   // 262144/4
  int g = blockIdx.x * 256 + threadIdx.x;
  if (g < 2 * Q4) {
    const float* src = g < Q4 ? Wq : Wk;
    unsigned short* hi = Wqk_hi + (g < Q4 ? 0 : DMOD * DMOD);
    unsigned short* lo = Wqk_lo + (g < Q4 ? 0 : DMOD * DMOD);
    int off = (g < Q4 ? g : g - Q4) * 4;
    float4 v = *(const float4*)(src + off);
    ushort4 h4, l4;
    h4.x = f2b(v.x); l4.x = f2b(v.x - b2f(h4.x));
    h4.y = f2b(v.y); l4.y = f2b(v.y - b2f(h4.y));
    h4.z = f2b(v.z); l4.z = f2b(v.z - b2f(h4.z));
    h4.w = f2b(v.w); l4.w = f2b(v.w - b2f(h4.w));
    *(ushort4*)(hi + off) = h4;
    *(ushort4*)(lo + off) = l4;
    return;
  }
  const float* src;
  unsigned short* dst;
  int off;
  if (g < 3 * Q4)      { src = Wv; dst = Wv_b; off = (g - 2 * Q4) * 4; }
  else if (g < 4 * Q4) { src = Wo; dst = Wo_b; off = (g - 3 * Q4) * 4; }
  else if (g < 4 * Q4 + 262144) { src = W1; dst = W1_b; off = (g - 4 * Q4) * 4; }
  else                 { src = W2; dst = W2_b; off = (g - 4 * Q4 - 262144) * 4; }
  float4 v = *(const float4*)(src + off);
  ushort4 o;
  o.x = f2b(v.x); o.y = f2b(v.y); o.z = f2b(v.z); o.w = f2b(v.w);
  *(ushort4*)(dst + off) = o;
}

// ---------------- split-bf16 MFMA GEMM (3-pass hi/lo), BK=32 double-buffered ----------------
// K-blocked LDS layout [kq][row][16B]: conflict-free ds_read_b128, linear GLDS dest.
__global__ __launch_bounds__(256) void gemm_mfma3(const unsigned short* __restrict__ Ah,
                                                  const unsigned short* __restrict__ Al,
                                                  const unsigned short* __restrict__ Bh,
                                                  const unsigned short* __restrict__ Bl,
                                                  const float* __restrict__ bq,
                                                  const float* __restrict__ bk,
                                                  float* __restrict__ C,
                                                  int M, int N, int K, int ldc) {
  __shared__ __align__(16) unsigned short AsH[2][128 * 32];   // 8 KB x2
  __shared__ __align__(16) unsigned short AsL[2][128 * 32];
  __shared__ __align__(16) unsigned short BsH[2][128 * 32];
  __shared__ __align__(16) unsigned short BsL[2][128 * 32];
  int nwg = gridDim.x * gridDim.y;
  int flat = blockIdx.y * gridDim.x + blockIdx.x;
  int swz = (flat & 7) * (nwg >> 3) + (flat >> 3);
  int bxs = swz % gridDim.x, bys = swz / gridDim.x;
  int bm = bys * 128, bn = bxs * 128;
  int tid = threadIdx.x;
  int wave = tid >> 6, lane = tid & 63;
  int wr = wave >> 1, wc = wave & 1;
  int r16 = lane & 15, kq = lane >> 4;

  f32x4 acc[4][4];
  #pragma unroll
  for (int i = 0; i < 4; ++i)
    #pragma unroll
    for (int j = 0; j < 4; ++j) acc[i][j] = (f32x4){0.f, 0.f, 0.f, 0.f};

  // stage: c = i*256+tid in [0,512); kq_ = c>>7, row_ = c&127
  // dest byte = c*16 (linear); src = (base+row)*K + kt + kq_*8
#define STAGE_M3(buf, ktv) \
  { \
    for (int i_ = 0; i_ < 2; ++i_) { \
      int c_ = i_ * 256 + tid; \
      int kq_ = c_ >> 7, row_ = c_ & 127; \
      size_t offA_ = (size_t)(bm + row_) * K + (ktv) + kq_ * 8; \
      size_t offB_ = (size_t)(bn + row_) * K + (ktv) + kq_ * 8; \
      int ldst_ = (i_ * 256 + (tid & 192)) << 4; \
      GLDS(Ah + offA_, (char*)AsH[buf] + ldst_); \
      GLDS(Al + offA_, (char*)AsL[buf] + ldst_); \
      GLDS(Bh + offB_, (char*)BsH[buf] + ldst_); \
      GLDS(Bl + offB_, (char*)BsL[buf] + ldst_); \
    } \
  }

  int nkt = K >> 5;    // BK=32
  STAGE_M3(0, 0);
  __syncthreads();
  for (int t = 0; t < nkt; ++t) {
    int cur = t & 1;
    if (t + 1 < nkt) STAGE_M3(cur ^ 1, (t + 1) << 5);
    const char* AbH = (const char*)AsH[cur];
    const char* AbL = (const char*)AsL[cur];
    const char* BbH = (const char*)BsH[cur];
    const char* BbL = (const char*)BsL[cur];
    bf16x8 ah[4], al[4], bh[4], bl[4];
    #pragma unroll
    for (int mi = 0; mi < 4; ++mi) {
      int row = wr * 64 + mi * 16 + r16;
      int addr = (kq << 11) | (row << 4);
      ah[mi] = *(const bf16x8*)(AbH + addr);
      al[mi] = *(const bf16x8*)(AbL + addr);
    }
    #pragma unroll
    for (int ni = 0; ni < 4; ++ni) {
      int row = wc * 64 + ni * 16 + r16;
      int addr = (kq << 11) | (row << 4);
      bh[ni] = *(const bf16x8*)(BbH + addr);
      bl[ni] = *(const bf16x8*)(BbL + addr);
    }
    #pragma unroll
    for (int mi = 0; mi < 4; ++mi)
      #pragma unroll
      for (int ni = 0; ni < 4; ++ni) {
        acc[mi][ni] = __builtin_amdgcn_mfma_f32_16x16x32_bf16(ah[mi], bh[ni], acc[mi][ni], 0, 0, 0);
        acc[mi][ni] = __builtin_amdgcn_mfma_f32_16x16x32_bf16(ah[mi], bl[ni], acc[mi][ni], 0, 0, 0);
        acc[mi][ni] = __builtin_amdgcn_mfma_f32_16x16x32_bf16(al[mi], bh[ni], acc[mi][ni], 0, 0, 0);
      }
    __syncthreads();
  }
#undef STAGE_M3

  int crow0 = bm + wr * 64 + (lane >> 4) * 4;
  int ccol0 = bn + wc * 64 + (lane & 15);
  #pragma unroll
  for (int mi = 0; mi < 4; ++mi) {
    #pragma unroll
    for (int ni = 0; ni < 4; ++ni) {
      int col = ccol0 + ni * 16;
      float bvv = col < 512 ? bq[col] : bk[col - 512];
      #pragma unroll
      for (int r = 0; r < 4; ++r) {
        int row = crow0 + mi * 16 + r;
        C[(size_t)row * ldc + col] = acc[mi][ni][r] + bvv;
      }
    }
  }
}

// ---------------- bf16 MFMA GEMM, BK=64 double-buffered, K-blocked LDS ----------------
template<int ACT, int OUTBF>
__global__ __launch_bounds__(256) void gemm_mfma(const unsigned short* __restrict__ A,
                                                 const unsigned short* __restrict__ W,
                                                 const float* __restrict__ bias,
                                                 float* __restrict__ Cf,
                                                 unsigned short* __restrict__ Cb,
                                                 int M, int N, int K) {
  __shared__ __align__(16) unsigned short As[2][128 * 64];   // 16 KB x2
  __shared__ __align__(16) unsigned short Bs[2][128 * 64];   // 16 KB x2
  int nwg = gridDim.x * gridDim.y;
  int flat = blockIdx.y * gridDim.x + blockIdx.x;
  int swz = (flat & 7) * (nwg >> 3) + (flat >> 3);
  int bxs = swz % gridDim.x, bys = swz / gridDim.x;
  int bm = bys * 128, bn = bxs * 128;
  int tid = threadIdx.x;
  int wave = tid >> 6, lane = tid & 63;
  int wr = wave >> 1, wc = wave & 1;
  int r16 = lane & 15, kq = lane >> 4;

  f32x4 acc[4][4];
  #pragma unroll
  for (int i = 0; i < 4; ++i)
    #pragma unroll
    for (int j = 0; j < 4; ++j) acc[i][j] = (f32x4){0.f, 0.f, 0.f, 0.f};

  // c = i*256+tid in [0,1024); ks_ = c>>9, kq_ = (c>>7)&3, row_ = c&127
  // dest byte = c*16 (linear); src = row*K + kt + ks_*32 + kq_*8
#define STAGE_MM(buf, ktv) \
  { \
    for (int i_ = 0; i_ < 4; ++i_) { \
      int c_ = i_ * 256 + tid; \
      int ks_ = c_ >> 9, kq_ = (c_ >> 7) & 3, row_ = c_ & 127; \
      size_t offA_ = (size_t)(bm + row_) * K + (ktv) + ks_ * 32 + kq_ * 8; \
      size_t offB_ = (size_t)(bn + row_) * K + (ktv) + ks_ * 32 + kq_ * 8; \
      int ldst_ = (i_ * 256 + (tid & 192)) << 4; \
      GLDS(A + offA_, (char*)As[buf] + ldst_); \
      GLDS(W + offB_, (char*)Bs[buf] + ldst_); \
    } \
  }

  int nkt = K >> 6;
  STAGE_MM(0, 0);
  __syncthreads();
  for (int t = 0; t < nkt; ++t) {
    int cur = t & 1;
    if (t + 1 < nkt) STAGE_MM(cur ^ 1, (t + 1) << 6);
    const char* Ab = (const char*)As[cur];
    const char* Bb = (const char*)Bs[cur];
    #pragma unroll
    for (int ks = 0; ks < 2; ++ks) {
      bf16x8 afr[4], bfr[4];
      #pragma unroll
      for (int mi = 0; mi < 4; ++mi) {
        int row = wr * 64 + mi * 16 + r16;
        int addr = (ks << 13) | (kq << 11) | (row << 4);
        afr[mi] = *(const bf16x8*)(Ab + addr);
      }
      #pragma unroll
      for (int ni = 0; ni < 4; ++ni) {
        int row = wc * 64 + ni * 16 + r16;
        int addr = (ks << 13) | (kq << 11) | (row << 4);
        bfr[ni] = *(const bf16x8*)(Bb + addr);
      }
      #pragma unroll
      for (int mi = 0; mi < 4; ++mi)
        #pragma unroll
        for (int ni = 0; ni < 4; ++ni)
          acc[mi][ni] = __builtin_amdgcn_mfma_f32_16x16x32_bf16(afr[mi], bfr[ni], acc[mi][ni], 0, 0, 0);
    }
    __syncthreads();
  }
#undef STAGE_MM

  int crow0 = bm + wr * 64 + (lane >> 4) * 4;
  int ccol0 = bn + wc * 64 + (lane & 15);
  #pragma unroll
  for (int mi = 0; mi < 4; ++mi) {
    #pragma unroll
    for (int ni = 0; ni < 4; ++ni) {
      int col = ccol0 + ni * 16;
      float bvv = bias[col];
      #pragma unroll
      for (int r = 0; r < 4; ++r) {
        int row = crow0 + mi * 16 + r;
        float v = acc[mi][ni][r] + bvv;
        if (ACT) {
          float x = v;
          float u = x * __builtin_fmaf(0.044715f * x, x, 1.0f);
          float tme = __expf(-1.5957691216057308f * u);
          v = x * __builtin_amdgcn_rcpf(1.0f + tme);
        }
        if (OUTBF) Cb[(size_t)row * N + col] = f2b(v);
        else       Cf[(size_t)row * N + col] = v;
      }
    }
  }
}

// ---------------- M measure: block per (bh), XOR-swizzled float4 K in LDS ----------------
__global__ __launch_bounds__(512) void m2_kernel(const float* __restrict__ QK,
                                                 const int* __restrict__ idx,
                                                 float* __restrict__ Mout) {
  int bh = blockIdx.x;
  int bv = bh >> 3, head = bh & 7;
  int tid = threadIdx.x;                 // 0..511, one q-row each
  __shared__ float Ks[512 * 64];         // 128 KB, word(l,db) = l*64 + ((db^(l&15))<<2)
  const float* base = QK + (size_t)bv * (SEQL * QKS);
  for (int c = tid; c < 512 * 16; c += 512) {
    int l = c >> 4, db = c & 15;
    float4 v = *(const float4*)(base + (size_t)l * QKS + 512 + head * 64 + db * 4);
    *(float4*)(Ks + l * 64 + ((db ^ (l & 15)) << 2)) = v;
  }
  float q[64];
  const float* qp = base + (size_t)tid * QKS + head * 64;
  #pragma unroll
  for (int d4 = 0; d4 < 64; d4 += 4) {
    float4 qv = *(const float4*)(qp + d4);
    q[d4 + 0] = qv.x; q[d4 + 1] = qv.y; q[d4 + 2] = qv.z; q[d4 + 3] = qv.w;
  }
  __syncthreads();
  const int* ip = idx + tid * NSAMP;
  float mx = -INFINITY, sm = 0.f;
  for (int u = 0; u < NSAMP; ++u) {
    int kidx = ip[u];
    const float* kr = Ks + kidx * 64;
    int x = kidx & 15;
    float s = 0.f;
    #pragma unroll
    for (int db = 0; db < 16; ++db) {
      float4 kv = *(const float4*)(kr + ((db ^ x) << 2));
      s += q[db * 4 + 0] * kv.x + q[db * 4 + 1] * kv.y
         + q[db * 4 + 2] * kv.z + q[db * 4 + 3] * kv.w;
    }
    mx = fmaxf(mx, s);
    sm += s;
  }
  Mout[(size_t)bh * SEQL + tid] = mx - sm * (1.0f / 512.0f);
}

// ---------------- top-k (k=35) ----------------
__global__ __launch_bounds__(256) void topk_kernel(const float* __restrict__ Mv,
                                                   int* __restrict__ top) {
  int bh = blockIdx.x;
  int tid = threadIdx.x;
  __shared__ float vals[512];
  __shared__ float rv[256];
  __shared__ int ri[256];
  vals[tid]       = Mv[(size_t)bh * SEQL + tid];
  vals[tid + 256] = Mv[(size_t)bh * SEQL + tid + 256];
  __syncthreads();
  for (int t = 0; t < NSAMP; ++t) {
    float v0 = vals[tid], v1 = vals[tid + 256];
    float bvv; int bii;
    if (v0 >= v1) { bvv = v0; bii = tid; } else { bvv = v1; bii = tid + 256; }
    rv[tid] = bvv; ri[tid] = bii;
    __syncthreads();
    for (int s = 128; s > 0; s >>= 1) {
      if (tid < s) {
        float ov = rv[tid + s]; int oi = ri[tid + s];
        if (ov > rv[tid] || (ov == rv[tid] && oi < ri[tid])) { rv[tid] = ov; ri[tid] = oi; }
      }
      __syncthreads();
    }
    if (tid == 0) { top[bh * NSAMP + t] = ri[0]; vals[ri[0]] = -INFINITY; }
    __syncthreads();
  }
}

// ---------------- mean of V (bf16 V, coalesced: block per bv) ----------------
__global__ __launch_bounds__(256) void vmean_kernel(const unsigned short* __restrict__ Vb,
                                                    float* __restrict__ vmean) {
  int bv = blockIdx.x;                 // 0..27
  int t = threadIdx.x;                 // cols 2t, 2t+1
  const unsigned short* vb = Vb + (size_t)bv * (SEQL * DMOD) + t * 2;
  float s0 = 0.f, s1 = 0.f;
  #pragma unroll 4
  for (int l = 0; l < SEQL; ++l) {
    unsigned u = *(const unsigned*)(vb + (size_t)l * DMOD);
    s0 += b2f((unsigned short)(u & 0xffffu));
    s1 += b2f((unsigned short)(u >> 16));
  }
  vmean[bv * DMOD + t * 2]     = s0 * (1.0f / 512.0f);
  vmean[bv * DMOD + t * 2 + 1] = s1 * (1.0f / 512.0f);
}

// ---------------- ctx = broadcast vmean (bf16 out, vectorized) ----------------
__global__ void ctx_fill_kernel(const float* __restrict__ vmean,
                                unsigned short* __restrict__ ctxb) {
  size_t i = (size_t)blockIdx.x * 256 + threadIdx.x;
  if (i >= (size_t)(SBIG / 4)) return;
  size_t e = i * 4;
  int dm = (int)(e & 511);
  int bv = (int)(e >> 18);
  float4 vm = *(const float4*)(vmean + bv * DMOD + dm);
  ushort4 o;
  o.x = f2b(vm.x); o.y = f2b(vm.y); o.z = f2b(vm.z); o.w = f2b(vm.w);
  *(ushort4*)(ctxb + e) = o;
}

// ---------------- MFMA attention for selected queries: block per (bh) ----------------
__global__ __launch_bounds__(256) void attn2_kernel(const float* __restrict__ QK,
                                                    const unsigned short* __restrict__ Vb,
                                                    const int* __restrict__ top,
                                                    unsigned short* __restrict__ ctxb) {
  __shared__ __align__(16) unsigned short KV[512 * 64];
  __shared__ __align__(16) unsigned short P[48 * 512];
  __shared__ __align__(16) unsigned short Qs[48 * 64];
  __shared__ int topi[NSAMP];
  int bh = blockIdx.x;
  int bv = bh >> 3, head = bh & 7;
  int tid = threadIdx.x;
  int wv = tid >> 6, lane = tid & 63;
  int r16 = lane & 15, kq = lane >> 4;
  const float* base = QK + (size_t)bv * (SEQL * QKS);
  const unsigned short* vbase = Vb + (size_t)bv * (SEQL * DMOD) + head * 64;

  if (tid < NSAMP) topi[tid] = top[bh * NSAMP + tid];
  __syncthreads();

  for (int c = tid; c < NSAMP * 16; c += 256) {
    int u = c >> 4, dq = c & 15;
    float4 q4 = *(const float4*)(base + (size_t)topi[u] * QKS + head * 64 + dq * 4);
    ushort4 o;
    o.x = f2b(q4.x * 0.125f); o.y = f2b(q4.y * 0.125f);
    o.z = f2b(q4.z * 0.125f); o.w = f2b(q4.w * 0.125f);
    int byte = ((u << 7) | (dq << 3)) ^ ((u & 7) << 4);
    *(ushort4*)((char*)Qs + byte) = o;
  }
  for (int c = tid; c < 512 * 16; c += 256) {
    int l = c >> 4, dq = c & 15;
    float4 k4 = *(const float4*)(base + (size_t)l * QKS + 512 + head * 64 + dq * 4);
    ushort4 o;
    o.x = f2b(k4.x); o.y = f2b(k4.y); o.z = f2b(k4.z); o.w = f2b(k4.w);
    int byte = ((l << 7) | (dq << 3)) ^ ((l & 7) << 4);
    *(ushort4*)((char*)KV + byte) = o;
  }
  __syncthreads();

  // QK^T: scores[48][512]
  {
    f32x4 acc[3][8];
    #pragma unroll
    for (int m = 0; m < 3; ++m)
      #pragma unroll
      for (int j = 0; j < 8; ++j) acc[m][j] = (f32x4){0.f, 0.f, 0.f, 0.f};
    bf16x8 afr[3][2];
    #pragma unroll
    for (int m = 0; m < 3; ++m)
      #pragma unroll
      for (int ks = 0; ks < 2; ++ks) {
        int row = m * 16 + r16;
        int addr = ((row << 7) | (ks << 6) | (kq << 4)) ^ ((row & 7) << 4);
        afr[m][ks] = *(const bf16x8*)((const char*)Qs + addr);
      }
    #pragma unroll
    for (int j = 0; j < 8; ++j) {
      int nrow = (wv * 8 + j) * 16 + r16;
      #pragma unroll
      for (int ks = 0; ks < 2; ++ks) {
        int addr = ((nrow << 7) | (ks << 6) | (kq << 4)) ^ ((nrow & 7) << 4);
        bf16x8 bfr = *(const bf16x8*)((const char*)KV + addr);
        #pragma unroll
        for (int m = 0; m < 3; ++m)
          acc[m][j] = __builtin_amdgcn_mfma_f32_16x16x32_bf16(afr[m][ks], bfr, acc[m][j], 0, 0, 0);
      }
    }
    #pragma unroll
    for (int m = 0; m < 3; ++m)
      #pragma unroll
      for (int j = 0; j < 8; ++j) {
        int l = (wv * 8 + j) * 16 + r16;
        #pragma unroll
        for (int r = 0; r < 4; ++r) {
          int u = m * 16 + kq * 4 + r;
          int byte = ((u << 10) | (l << 1)) ^ ((u & 7) << 4);
          *(unsigned short*)((char*)P + byte) = f2b(acc[m][j][r]);
        }
      }
  }
  __syncthreads();

  // stage V^T into KV region (K dead) from bf16 V
  for (int c = tid; c < 512 * 8; c += 256) {
    int l = c >> 3, dq = c & 7;
    bf16x8 v8 = *(const bf16x8*)(vbase + (size_t)l * DMOD + dq * 8);
    #pragma unroll
    for (int j = 0; j < 8; ++j) {
      int d = dq * 8 + j;
      int byte = ((d << 10) | (l << 1)) ^ ((d & 7) << 4);
      *(unsigned short*)((char*)KV + byte) = (unsigned short)v8[j];
    }
  }
  // softmax on P rows
  for (int u = wv; u < NSAMP; u += 4) {
    int byte = ((u << 10) | (lane << 4)) ^ ((u & 7) << 4);
    bf16x8 sv = *(const bf16x8*)((const char*)P + byte);
    float s[8];
    #pragma unroll
    for (int j = 0; j < 8; ++j) s[j] = b2f((unsigned short)sv[j]);
    float mx = s[0];
    #pragma unroll
    for (int j = 1; j < 8; ++j) mx = fmaxf(mx, s[j]);
    #pragma unroll
    for (int off = 32; off > 0; off >>= 1) mx = fmaxf(mx, __shfl_xor(mx, off));
    float e[8], sm = 0.f;
    #pragma unroll
    for (int j = 0; j < 8; ++j) { e[j] = __expf(s[j] - mx); sm += e[j]; }
    #pragma unroll
    for (int off = 32; off > 0; off >>= 1) sm += __shfl_xor(sm, off);
    float inv = 1.0f / sm;
    bf16x8 pv;
    #pragma unroll
    for (int j = 0; j < 8; ++j) pv[j] = (short)f2b(e[j] * inv);
    *(bf16x8*)((char*)P + byte) = pv;
  }
  __syncthreads();

  // PV: ctx[48][64] = P @ V
  {
    f32x4 acc2[3];
    #pragma unroll
    for (int m = 0; m < 3; ++m) acc2[m] = (f32x4){0.f, 0.f, 0.f, 0.f};
    for (int kst = 0; kst < 16; ++kst) {
      int vrow = wv * 16 + r16;
      int baddr = ((vrow << 10) | (kst << 6) | (kq << 4)) ^ ((vrow & 7) << 4);
      bf16x8 bfr = *(const bf16x8*)((const char*)KV + baddr);
      #pragma unroll
      for (int m = 0; m < 3; ++m) {
        int prow = m * 16 + r16;
        int aaddr = ((prow << 10) | (kst << 6) | (kq << 4)) ^ ((prow & 7) << 4);
        bf16x8 afr2 = *(const bf16x8*)((const char*)P + aaddr);
        acc2[m] = __builtin_amdgcn_mfma_f32_16x16x32_bf16(afr2, bfr, acc2[m], 0, 0, 0);
      }
    }
    int d = wv * 16 + r16;
    #pragma unroll
    for (int m = 0; m < 3; ++m)
      #pragma unroll
      for (int r = 0; r < 4; ++r) {
        int u = m * 16 + kq * 4 + r;
        if (u < NSAMP) {
          size_t off = (size_t)bv * (SEQL * DMOD) + (size_t)topi[u] * DMOD + head * 64 + d;
          ctxb[off] = f2b(acc2[m][r]);
        }
      }
  }
}

// ---------------- residual add + layernorm (vectorized: 2 rows/block) ----------------
template<int BMODE, int OUT>
__global__ __launch_bounds__(256) void add_ln(const float* __restrict__ a,
                                              const unsigned short* __restrict__ b,
                                              const float* __restrict__ g,
                                              const float* __restrict__ be,
                                              float* __restrict__ out,
                                              unsigned short* __restrict__ outb,
                                              unsigned short* __restrict__ outh,
                                              unsigned short* __restrict__ outl) {
  int row = blockIdx.x * 2 + (threadIdx.x >> 7);
  int t = threadIdx.x & 127;
  int wave = threadIdx.x >> 6;
  int lane = threadIdx.x & 63;
  size_t base = (size_t)row * DMOD + t * 4;
  float4 x = *(const float4*)(a + base);
  if (BMODE == 2) {
    ushort4 r4 = *(const ushort4*)(b + base);
    x.x += b2f(r4.x); x.y += b2f(r4.y); x.z += b2f(r4.z); x.w += b2f(r4.w);
  }
  float s1 = x.x + x.y + x.z + x.w;
  float s2 = x.x * x.x + x.y * x.y + x.z * x.z + x.w * x.w;
  #pragma unroll
  for (int off = 32; off > 0; off >>= 1) {
    s1 += __shfl_xor(s1, off);
    s2 += __shfl_xor(s2, off);
  }
  __shared__ float sh[8];
  if (lane == 0) { sh[wave * 2] = s1; sh[wave * 2 + 1] = s2; }
  __syncthreads();
  int mate = wave ^ 1;
  s1 += sh[mate * 2];
  s2 += sh[mate * 2 + 1];
  float mu = s1 * (1.0f / 512.0f);
  float var = s2 * (1.0f / 512.0f) - mu * mu;
  float rstd = rsqrtf(var + 1e-5f);
  float4 gg = *(const float4*)(g + t * 4);
  float4 bb = *(const float4*)(be + t * 4);
  float4 o;
  o.x = (x.x - mu) * rstd * gg.x + bb.x;
  o.y = (x.y - mu) * rstd * gg.y + bb.y;
  o.z = (x.z - mu) * rstd * gg.z + bb.z;
  o.w = (x.w - mu) * rstd * gg.w + bb.w;
  *(float4*)(out + base) = o;
  if (OUT == 1) {
    ushort4 ob;
    ob.x = f2b(o.x); ob.y = f2b(o.y); ob.z = f2b(o.z); ob.w = f2b(o.w);
    *(ushort4*)(outb + base) = ob;
  }
  if (OUT == 2) {
    ushort4 hi4, lo4;
    hi4.x = f2b(o.x); lo4.x = f2b(o.x - b2f(hi4.x));
    hi4.y = f2b(o.y); lo4.y = f2b(o.y - b2f(hi4.y));
    hi4.z = f2b(o.z); lo4.z = f2b(o.z - b2f(hi4.z));
    hi4.w = f2b(o.w); lo4.w = f2b(o.w - b2f(hi4.w));
    *(ushort4*)(outh + base) = hi4;
    *(ushort4*)(outl + base) = lo4;
  }
}

// ---------------- head via MFMA: partial[blk*4+w][2688], K-chunk 512/block ----------------
__global__ __launch_bounds__(256) void head_partial_mfma(const unsigned short* __restrict__ hbf,
                                                         const float* __restrict__ Wh,
                                                         float* __restrict__ partial) {
  __shared__ __align__(16) unsigned short Hs[32 * 512];   // 32 KB
  __shared__ __align__(16) unsigned short Ws[96 * 512];   // 96 KB
  int blk = blockIdx.x;            // 0..511
  int k0 = blk * 512;
  int tid = threadIdx.x;
  int wv = tid >> 6, lane = tid & 63;
  int r16 = lane & 15, kq = lane >> 4;

  for (int c = tid; c < 32 * 64; c += 256) {
    int row = c >> 6, col8 = c & 63;
    int src = row < 28 ? row : 0;
    bf16x8 v = *(const bf16x8*)(hbf + (size_t)src * 262144 + k0 + col8 * 8);
    int byte = ((row << 10) | (col8 << 4)) ^ ((row & 7) << 4);
    *(bf16x8*)((char*)Hs + byte) = v;
  }
  for (int c = tid; c < 96 * 64; c += 256) {
    int row = c >> 6, col8 = c & 63;
    const float* src = Wh + (size_t)row * 262144 + k0 + col8 * 8;
    float4 va = *(const float4*)(src);
    float4 vb = *(const float4*)(src + 4);
    bf16x8 o8;
    o8[0] = (short)f2b(va.x); o8[1] = (short)f2b(va.y);
    o8[2] = (short)f2b(va.z); o8[3] = (short)f2b(va.w);
    o8[4] = (short)f2b(vb.x); o8[5] = (short)f2b(vb.y);
    o8[6] = (short)f2b(vb.z); o8[7] = (short)f2b(vb.w);
    int byte = ((row << 10) | (col8 << 4)) ^ ((row & 7) << 4);
    *(bf16x8*)((char*)Ws + byte) = o8;
  }
  __syncthreads();

  f32x4 acc[2][6];
  #pragma unroll
  for (int mt = 0; mt < 2; ++mt)
    #pragma unroll
    for (int nt = 0; nt < 6; ++nt) acc[mt][nt] = (f32x4){0.f, 0.f, 0.f, 0.f};

  #pragma unroll
  for (int kk = 0; kk < 4; ++kk) {
    int kfrag = wv * 4 + kk;     // k = kfrag*32 + kq*8
    bf16x8 afr[2];
    #pragma unroll
    for (int mt = 0; mt < 2; ++mt) {
      int row = mt * 16 + r16;
      int byte = ((row << 10) | (kfrag << 6) | (kq << 4)) ^ ((row & 7) << 4);
      afr[mt] = *(const bf16x8*)((const char*)Hs + byte);
    }
    #pragma unroll
    for (int nt = 0; nt < 6; ++nt) {
      int row = nt * 16 + r16;
      int byte = ((row << 10) | (kfrag << 6) | (kq << 4)) ^ ((row & 7) << 4);
      bf16x8 bfr = *(const bf16x8*)((const char*)Ws + byte);
      #pragma unroll
      for (int mt = 0; mt < 2; ++mt)
        acc[mt][nt] = __builtin_amdgcn_mfma_f32_16x16x32_bf16(afr[mt], bfr, acc[mt][nt], 0, 0, 0);
    }
  }
  size_t prow = (size_t)(blk * 4 + wv) * 2688;
  #pragma unroll
  for (int mt = 0; mt < 2; ++mt)
    #pragma unroll
    for (int nt = 0; nt < 6; ++nt)
      #pragma unroll
      for (int r = 0; r < 4; ++r) {
        int m = mt * 16 + kq * 4 + r;
        int n = nt * 16 + r16;
        if (m < 28) partial[prow + m * 96 + n] = acc[mt][nt][r];
      }
}

__global__ __launch_bounds__(256) void head_reduce(const float* __restrict__ partial,
                                                   const float* __restrict__ bh_,
                                                   float* __restrict__ out) {
  int o = blockIdx.x;              // 0..2687 = m*96+p
  int tid = threadIdx.x;
  float s = 0.f;
  for (int b = tid; b < 2048; b += 256) s += partial[(size_t)b * 2688 + o];
  __shared__ float red[256];
  red[tid] = s;
  __syncthreads();
  for (int st = 128; st > 0; st >>= 1) {
    if (tid < st) red[tid] += red[tid + st];
    __syncthreads();
  }
  if (tid == 0) {
    int m = o / 96, p = o % 96;
    int b = m / NVARS, v = m % NVARS;
    out[(size_t)b * (NPRED * NVARS) + (size_t)p * NVARS + v] = red[0] + bh_[p];
  }
}

extern "C" void kernel_launch(void* const* d_in, const int* in_sizes, int n_in,
                              void* d_out, int out_size, void* d_ws, size_t ws_size,
                              hipStream_t stream) {
  const float* x_enc = (const float*)d_in[0];
  const float* w_emb = (const float*)d_in[1];
  const float* b_emb = (const float*)d_in[2];
  const float* w_pos = (const float*)d_in[3];
  const float* Wq = (const float*)d_in[4];
  const float* bq = (const float*)d_in[5];
  const float* Wk = (const float*)d_in[6];
  const float* bk = (const float*)d_in[7];
  const float* Wv = (const float*)d_in[8];
  const float* bv_ = (const float*)d_in[9];
  const float* Wo = (const float*)d_in[10];
  const float* bo = (const float*)d_in[11];
  const float* W1 = (const float*)d_in[12];
  const float* b1 = (const float*)d_in[13];
  const float* W2 = (const float*)d_in[14];
  const float* b2 = (const float*)d_in[15];
  const float* g1 = (const float*)d_in[16];
  const float* be1 = (const float*)d_in[17];
  const float* g2 = (const float*)d_in[18];
  const float* be2 = (const float*)d_in[19];
  const float* gF = (const float*)d_in[20];
  const float* bF = (const float*)d_in[21];
  const float* Wh = (const float*)d_in[22];
  const float* bh_ = (const float*)d_in[23];
  float* out = (float*)d_out;

  const size_t S = (size_t)SBIG;
  const size_t SB = S * 4;                    // 29,360,128 B
  char* ws = (char*)d_ws;
  float* h    = (float*)(ws);                 // [0, SB)
  float* QKb  = (float*)(ws + SB);            // [SB, 3SB): [14336][1024] fp32
  unsigned short* Vb   = (unsigned short*)(ws + 3 * SB);            // 14.7 MB
  unsigned short* Ob_b = (unsigned short*)(ws + 3 * SB + SB / 2);   // 14.7 MB
  // weight scratch region [4SB, 5SB)
  unsigned short* Wqk_hi = (unsigned short*)(ws + 4 * SB);                  // 1 MB
  unsigned short* Wqk_lo = (unsigned short*)(ws + 4 * SB + 0x100000);       // 1 MB
  unsigned short* Wv_b = (unsigned short*)(ws + 4 * SB + 0x200000);         // 0.5 MB
  unsigned short* Wo_b = (unsigned short*)(ws + 4 * SB + 0x280000);         // 0.5 MB
  unsigned short* W1_b = (unsigned short*)(ws + 4 * SB + 0x300000);         // 2 MB
  unsigned short* W2_b = (unsigned short*)(ws + 4 * SB + 0x500000);         // 2 MB
  unsigned short* h_hi = (unsigned short*)(ws + 5 * SB);           // SB/2
  unsigned short* h_lo = (unsigned short*)(ws + 5 * SB + SB / 2);  // SB/2
  // phase aliases:
  unsigned short* CTXb = h_hi;                 // after QK+V gemms consumed h_hi
  unsigned short* h_bf = h_lo;                 // after QK gemm consumed h_lo
  unsigned short* FFNb = (unsigned short*)QKb; // after attn consumed QK
  float* partial = QKb;                        // head phase (22 MB <= 2SB)
  int*   idx = (int*)(ws + 6 * SB);                        // 70KB
  float* Mv  = (float*)(ws + 6 * SB + 0x20000);            // 448KB
  int*   top = (int*)(ws + 6 * SB + 0xA0000);              // 31KB
  float* vmean = (float*)(ws + 6 * SB + 0xB0000);          // 56KB
  if (ws_size < 6 * SB + 0xC0000) return;

  dim3 b256(256);
  int gVec = (int)(S / 4 / 256);   // 7168

  embed_kernel<<<gVec, b256, 0, stream>>>(x_enc, w_emb, b_emb, w_pos, h, h_hi, h_lo);

  for (int l = 0; l < 2; ++l) {
    const float* Wql = Wq + (size_t)l * DMOD * DMOD;
    const float* Wkl = Wk + (size_t)l * DMOD * DMOD;
    const float* Wvl = Wv + (size_t)l * DMOD * DMOD;
    const float* Wol = Wo + (size_t)l * DMOD * DMOD;
    const float* W1l = W1 + (size_t)l * DFFN * DMOD;
    const float* W2l = W2 + (size_t)l * DMOD * DFFN;

    prep_weights<<<3072, b256, 0, stream>>>(Wql, Wkl, Wvl, Wol, W1l, W2l,
                                            Wqk_hi, Wqk_lo, Wv_b, Wo_b, W1_b, W2_b);

    dim3 gqk(QKS / 128, NROWS / 128);
    gemm_mfma3<<<gqk, b256, 0, stream>>>(h_hi, h_lo, Wqk_hi, Wqk_lo,
                                         bq + l * DMOD, bk + l * DMOD,
                                         QKb, NROWS, QKS, DMOD, QKS);
    dim3 gv(DMOD / 128, NROWS / 128);
    gemm_mfma<0, 1><<<gv, b256, 0, stream>>>(h_hi, Wv_b, bv_ + l * DMOD,
                                             (float*)0, Vb, NROWS, DMOD, DMOD);

    make_idx_kernel<<<(SEQL * NSAMP + 255) / 256, b256, 0, stream>>>(l, idx);
    m2_kernel<<<NBH, dim3(512), 0, stream>>>(QKb, idx, Mv);
    topk_kernel<<<NBH, b256, 0, stream>>>(Mv, top);
    vmean_kernel<<<NBV, b256, 0, stream>>>(Vb, vmean);
    ctx_fill_kernel<<<gVec, b256, 0, stream>>>(vmean, CTXb);
    attn2_kernel<<<NBH, b256, 0, stream>>>(QKb, Vb, top, CTXb);

    dim3 go(DMOD / 128, NROWS / 128);
    gemm_mfma<0, 1><<<go, b256, 0, stream>>>(CTXb, Wo_b, bo + l * DMOD,
                                             (float*)0, Ob_b, NROWS, DMOD, DMOD);
    add_ln<2, 1><<<NROWS / 2, b256, 0, stream>>>(h, Ob_b, g1 + l * DMOD, be1 + l * DMOD,
                                                 h, h_bf, (unsigned short*)0, (unsigned short*)0);

    dim3 gf1(DFFN / 128, NROWS / 128);
    gemm_mfma<1, 1><<<gf1, b256, 0, stream>>>(h_bf, W1_b, b1 + l * DFFN,
                                              (float*)0, FFNb, NROWS, DFFN, DMOD);
    dim3 gf2(DMOD / 128, NROWS / 128);
    gemm_mfma<0, 1><<<gf2, b256, 0, stream>>>(FFNb, W2_b, b2 + l * DMOD,
                                              (float*)0, Ob_b, NROWS, DMOD, DFFN);
    if (l == 0) {
      add_ln<2, 2><<<NROWS / 2, b256, 0, stream>>>(h, Ob_b, g2 + l * DMOD, be2 + l * DMOD,
                                                   h, (unsigned short*)0, h_hi, h_lo);
    } else {
      add_ln<2, 0><<<NROWS / 2, b256, 0, stream>>>(h, Ob_b, g2 + l * DMOD, be2 + l * DMOD,
                                                   h, (unsigned short*)0, (unsigned short*)0, (unsigned short*)0);
    }
  }

  add_ln<0, 1><<<NROWS / 2, b256, 0, stream>>>(h, (const unsigned short*)0, gF, bF,
                                               h, h_bf, (unsigned short*)0, (unsigned short*)0);
  head_partial_mfma<<<512, b256, 0, stream>>>(h_bf, Wh, partial);
  head_reduce<<<NBV * NPRED, b256, 0, stream>>>(partial, bh_, out);
}

// Round 11
// 803.681 us; speedup vs baseline: 1.2695x; 1.2695x over previous
//
#include <hip/hip_runtime.h>
#include <math.h>

#define SEQL 512
#define DMOD 512
#define NHEAD 8
#define DHEAD 64
#define DFFN 2048
#define NBATCH 4
#define NVARS 7
#define NBV 28          // NBATCH*NVARS
#define NBH 224         // NBV*NHEAD
#define NROWS 14336     // NBV*SEQL
#define NSAMP 35        // U_part = u = 35
#define NPRED 96
#define SBIG 7340032    // NBV*SEQL*DMOD floats
#define QKS 1024        // QK row stride
#define K3 1536         // hi/lo-expanded K

typedef short bf16x8 __attribute__((ext_vector_type(8)));
typedef float f32x4 __attribute__((ext_vector_type(4)));

#define GLDS(gptr, lptr) \
  __builtin_amdgcn_global_load_lds((const __attribute__((address_space(1))) void*)(gptr), \
                                   (__attribute__((address_space(3))) void*)(lptr), 16, 0, 0)

__device__ inline unsigned short f2b(float f) {
  unsigned u = __builtin_bit_cast(unsigned, f);
  unsigned r = (u + 0x7FFFu + ((u >> 16) & 1u)) >> 16;
  return (unsigned short)r;
}
__device__ inline float b2f(unsigned short h) {
  return __builtin_bit_cast(float, (unsigned)h << 16);
}

// ---------------- threefry2x32 (matches jax._src.prng) ----------------
__device__ inline void threefry2x32(unsigned k0, unsigned k1,
                                    unsigned x0, unsigned x1,
                                    unsigned &o0, unsigned &o1) {
  unsigned ks2 = k0 ^ k1 ^ 0x1BD11BDAu;
  unsigned ks[3] = {k0, k1, ks2};
  x0 += k0; x1 += k1;
  const unsigned rot[2][4] = {{13u,15u,26u,6u},{17u,29u,16u,24u}};
  #pragma unroll
  for (int i = 0; i < 5; ++i) {
    #pragma unroll
    for (int j = 0; j < 4; ++j) {
      unsigned r = rot[i & 1][j];
      x0 += x1;
      x1 = (x1 << r) | (x1 >> (32u - r));
      x1 ^= x0;
    }
    x0 += ks[(i + 1) % 3];
    x1 += ks[(i + 2) % 3] + (unsigned)(i + 1);
  }
  o0 = x0; o1 = x1;
}

__global__ void make_idx_kernel(int layer, int* idx) {
  int i = blockIdx.x * 256 + threadIdx.x;
  if (i >= SEQL * NSAMP) return;
  unsigned kl0, kl1, o0, o1;
  threefry2x32(0u, 42u, 0u, (unsigned)layer, kl0, kl1);
  threefry2x32(kl0, kl1, (unsigned)i, (unsigned)(SEQL * NSAMP + i), o0, o1);
  idx[i] = (int)(o1 & 511u);
}

// ---------------- embedding: h fp32 + h3 = [hi|hi|lo] triple ----------------
__global__ void embed_kernel(const float* __restrict__ x_enc,
                             const float* __restrict__ w_emb,
                             const float* __restrict__ b_emb,
                             const float* __restrict__ w_pos,
                             float* __restrict__ h,
                             unsigned short* __restrict__ h3) {
  size_t i = (size_t)blockIdx.x * 256 + threadIdx.x;
  if (i >= (size_t)(SBIG / 4)) return;
  size_t e = i * 4;
  int dm = (int)(e & 511);
  int l  = (int)((e >> 9) & 511);
  int bv = (int)(e >> 18);
  int b = bv / NVARS, v = bv % NVARS;
  float xs = x_enc[((size_t)b * SEQL + l) * NVARS + v];
  float4 we = *(const float4*)(w_emb + dm);
  float4 bb = *(const float4*)(b_emb + dm);
  float4 wp = *(const float4*)(w_pos + (size_t)l * DMOD + dm);
  float4 val;
  val.x = xs * we.x + bb.x + wp.x;
  val.y = xs * we.y + bb.y + wp.y;
  val.z = xs * we.z + bb.z + wp.z;
  val.w = xs * we.w + bb.w + wp.w;
  *(float4*)(h + e) = val;
  ushort4 hi4, lo4;
  hi4.x = f2b(val.x); lo4.x = f2b(val.x - b2f(hi4.x));
  hi4.y = f2b(val.y); lo4.y = f2b(val.y - b2f(hi4.y));
  hi4.z = f2b(val.z); lo4.z = f2b(val.z - b2f(hi4.z));
  hi4.w = f2b(val.w); lo4.w = f2b(val.w - b2f(hi4.w));
  size_t row = e >> 9;
  size_t base3 = row * K3 + (e & 511);
  *(ushort4*)(h3 + base3)        = hi4;
  *(ushort4*)(h3 + base3 + 512)  = hi4;
  *(ushort4*)(h3 + base3 + 1024) = lo4;
}

// ---------------- fused per-layer weight prep ----------------
// Wqk3[1024][1536] = [hi|lo|hi] of (Wq rows, then Wk rows); Wv/Wo/W1/W2 f2b; bias_qk
__global__ void prep_weights(const float* __restrict__ Wq, const float* __restrict__ Wk,
                             const float* __restrict__ Wv, const float* __restrict__ Wo,
                             const float* __restrict__ W1, const float* __restrict__ W2,
                             const float* __restrict__ bq, const float* __restrict__ bk,
                             unsigned short* __restrict__ Wqk3,
                             unsigned short* __restrict__ Wv_b, unsigned short* __restrict__ Wo_b,
                             unsigned short* __restrict__ W1_b, unsigned short* __restrict__ W2_b,
                             float* __restrict__ bias_qk) {
  int g = blockIdx.x * 256 + threadIdx.x;
  const int NQK = 1024 * K3 / 4;   // 393216
  if (g < NQK) {
    int n = g / 384, cg = g % 384;
    const float* w = n < 512 ? Wq + (size_t)n * 512 : Wk + (size_t)(n - 512) * 512;
    int lo_mode, sc4;
    if (cg < 128)      { lo_mode = 0; sc4 = cg; }
    else if (cg < 256) { lo_mode = 1; sc4 = cg - 128; }
    else               { lo_mode = 0; sc4 = cg - 256; }
    float4 v = *(const float4*)(w + sc4 * 4);
    ushort4 o;
    if (lo_mode) {
      unsigned short hx = f2b(v.x), hy = f2b(v.y), hz = f2b(v.z), hw = f2b(v.w);
      o.x = f2b(v.x - b2f(hx)); o.y = f2b(v.y - b2f(hy));
      o.z = f2b(v.z - b2f(hz)); o.w = f2b(v.w - b2f(hw));
    } else {
      o.x = f2b(v.x); o.y = f2b(v.y); o.z = f2b(v.z); o.w = f2b(v.w);
    }
    *(ushort4*)(Wqk3 + (size_t)n * K3 + cg * 4) = o;
    return;
  }
  g -= NQK;
  const float* src;
  unsigned short* dst;
  if (g < 65536)        { src = Wv; dst = Wv_b; }
  else if (g < 131072)  { src = Wo; dst = Wo_b; g -= 65536; }
  else if (g < 393216)  { src = W1; dst = W1_b; g -= 131072; }
  else if (g < 655360)  { src = W2; dst = W2_b; g -= 393216; }
  else {
    int i = g - 655360;
    if (i < 1024) bias_qk[i] = i < 512 ? bq[i] : bk[i - 512];
    return;
  }
  int off = g * 4;
  float4 v = *(const float4*)(src + off);
  ushort4 o;
  o.x = f2b(v.x); o.y = f2b(v.y); o.z = f2b(v.z); o.w = f2b(v.w);
  *(ushort4*)(dst + off) = o;
}

// ---------------- bf16 MFMA GEMM, BK=64 double-buffered, XOR-swizzled LDS ----------------
// (round-9 proven structure; lda/ldb/ldc generalized)
template<int ACT, int OUTBF>
__global__ __launch_bounds__(256) void gemm_mfma(const unsigned short* __restrict__ A, int lda,
                                                 const unsigned short* __restrict__ W, int ldb,
                                                 const float* __restrict__ bias,
                                                 float* __restrict__ Cf,
                                                 unsigned short* __restrict__ Cb,
                                                 int M, int N, int K, int ldc) {
  __shared__ __align__(16) unsigned short As[2][128 * 64];
  __shared__ __align__(16) unsigned short Bs[2][128 * 64];
  int nwg = gridDim.x * gridDim.y;
  int flat = blockIdx.y * gridDim.x + blockIdx.x;
  int swz = (flat & 7) * (nwg >> 3) + (flat >> 3);
  int bxs = swz % gridDim.x, bys = swz / gridDim.x;
  int bm = bys * 128, bn = bxs * 128;
  int tid = threadIdx.x;
  int wave = tid >> 6, lane = tid & 63;
  int wr = wave >> 1, wc = wave & 1;
  int r16 = lane & 15, kq = lane >> 4;

  f32x4 acc[4][4];
  #pragma unroll
  for (int i = 0; i < 4; ++i)
    #pragma unroll
    for (int j = 0; j < 4; ++j) acc[i][j] = (f32x4){0.f, 0.f, 0.f, 0.f};

#define STAGE_MM(buf, ktv) \
  { \
    for (int i_ = 0; i_ < 4; ++i_) { \
      int c_ = i_ * 256 + tid; \
      int row_ = c_ >> 3, kb_ = c_ & 7; \
      int kbs_ = kb_ ^ (row_ & 7); \
      size_t offA_ = (size_t)(bm + row_) * lda + (ktv) + kbs_ * 8; \
      size_t offB_ = (size_t)(bn + row_) * ldb + (ktv) + kbs_ * 8; \
      int ldst_ = (i_ * 256 + (tid & 192)) << 4; \
      GLDS(A + offA_, (char*)As[buf] + ldst_); \
      GLDS(W + offB_, (char*)Bs[buf] + ldst_); \
    } \
  }

  int nkt = K >> 6;
  STAGE_MM(0, 0);
  __syncthreads();
  for (int t = 0; t < nkt; ++t) {
    int cur = t & 1;
    if (t + 1 < nkt) STAGE_MM(cur ^ 1, (t + 1) << 6);
    const char* Ab = (const char*)As[cur];
    const char* Bb = (const char*)Bs[cur];
    #pragma unroll
    for (int ks = 0; ks < 2; ++ks) {
      bf16x8 afr[4], bfr[4];
      #pragma unroll
      for (int mi = 0; mi < 4; ++mi) {
        int row = wr * 64 + mi * 16 + r16;
        int addr = ((row << 7) | (ks << 6) | (kq << 4)) ^ ((row & 7) << 4);
        afr[mi] = *(const bf16x8*)(Ab + addr);
      }
      #pragma unroll
      for (int ni = 0; ni < 4; ++ni) {
        int row = wc * 64 + ni * 16 + r16;
        int addr = ((row << 7) | (ks << 6) | (kq << 4)) ^ ((row & 7) << 4);
        bfr[ni] = *(const bf16x8*)(Bb + addr);
      }
      #pragma unroll
      for (int mi = 0; mi < 4; ++mi)
        #pragma unroll
        for (int ni = 0; ni < 4; ++ni)
          acc[mi][ni] = __builtin_amdgcn_mfma_f32_16x16x32_bf16(afr[mi], bfr[ni], acc[mi][ni], 0, 0, 0);
    }
    __syncthreads();
  }
#undef STAGE_MM

  int crow0 = bm + wr * 64 + (lane >> 4) * 4;
  int ccol0 = bn + wc * 64 + (lane & 15);
  #pragma unroll
  for (int mi = 0; mi < 4; ++mi) {
    #pragma unroll
    for (int ni = 0; ni < 4; ++ni) {
      int col = ccol0 + ni * 16;
      float bvv = bias[col];
      #pragma unroll
      for (int r = 0; r < 4; ++r) {
        int row = crow0 + mi * 16 + r;
        float v = acc[mi][ni][r] + bvv;
        if (ACT) {
          float x = v;
          float u = x * __builtin_fmaf(0.044715f * x, x, 1.0f);
          float tme = __expf(-1.5957691216057308f * u);
          v = x * __builtin_amdgcn_rcpf(1.0f + tme);
        }
        if (OUTBF) Cb[(size_t)row * ldc + col] = f2b(v);
        else       Cf[(size_t)row * ldc + col] = v;
      }
    }
  }
}

// ---------------- M measure: block per (bh), XOR-swizzled float4 K in LDS ----------------
__global__ __launch_bounds__(512) void m2_kernel(const float* __restrict__ QK,
                                                 const int* __restrict__ idx,
                                                 float* __restrict__ Mout) {
  int bh = blockIdx.x;
  int bv = bh >> 3, head = bh & 7;
  int tid = threadIdx.x;
  __shared__ float Ks[512 * 64];
  const float* base = QK + (size_t)bv * (SEQL * QKS);
  for (int c = tid; c < 512 * 16; c += 512) {
    int l = c >> 4, db = c & 15;
    float4 v = *(const float4*)(base + (size_t)l * QKS + 512 + head * 64 + db * 4);
    *(float4*)(Ks + l * 64 + ((db ^ (l & 15)) << 2)) = v;
  }
  float q[64];
  const float* qp = base + (size_t)tid * QKS + head * 64;
  #pragma unroll
  for (int d4 = 0; d4 < 64; d4 += 4) {
    float4 qv = *(const float4*)(qp + d4);
    q[d4 + 0] = qv.x; q[d4 + 1] = qv.y; q[d4 + 2] = qv.z; q[d4 + 3] = qv.w;
  }
  __syncthreads();
  const int* ip = idx + tid * NSAMP;
  float mx = -INFINITY, sm = 0.f;
  for (int u = 0; u < NSAMP; ++u) {
    int kidx = ip[u];
    const float* kr = Ks + kidx * 64;
    int x = kidx & 15;
    float s = 0.f;
    #pragma unroll
    for (int db = 0; db < 16; ++db) {
      float4 kv = *(const float4*)(kr + ((db ^ x) << 2));
      s += q[db * 4 + 0] * kv.x + q[db * 4 + 1] * kv.y
         + q[db * 4 + 2] * kv.z + q[db * 4 + 3] * kv.w;
    }
    mx = fmaxf(mx, s);
    sm += s;
  }
  Mout[(size_t)bh * SEQL + tid] = mx - sm * (1.0f / 512.0f);
}

// ---------------- top-k (k=35) ----------------
__global__ __launch_bounds__(256) void topk_kernel(const float* __restrict__ Mv,
                                                   int* __restrict__ top) {
  int bh = blockIdx.x;
  int tid = threadIdx.x;
  __shared__ float vals[512];
  __shared__ float rv[256];
  __shared__ int ri[256];
  vals[tid]       = Mv[(size_t)bh * SEQL + tid];
  vals[tid + 256] = Mv[(size_t)bh * SEQL + tid + 256];
  __syncthreads();
  for (int t = 0; t < NSAMP; ++t) {
    float v0 = vals[tid], v1 = vals[tid + 256];
    float bvv; int bii;
    if (v0 >= v1) { bvv = v0; bii = tid; } else { bvv = v1; bii = tid + 256; }
    rv[tid] = bvv; ri[tid] = bii;
    __syncthreads();
    for (int s = 128; s > 0; s >>= 1) {
      if (tid < s) {
        float ov = rv[tid + s]; int oi = ri[tid + s];
        if (ov > rv[tid] || (ov == rv[tid] && oi < ri[tid])) { rv[tid] = ov; ri[tid] = oi; }
      }
      __syncthreads();
    }
    if (tid == 0) { top[bh * NSAMP + t] = ri[0]; vals[ri[0]] = -INFINITY; }
    __syncthreads();
  }
}

// ---------------- mean of V (bf16 V, coalesced: block per bv) ----------------
__global__ __launch_bounds__(256) void vmean_kernel(const unsigned short* __restrict__ Vb,
                                                    float* __restrict__ vmean) {
  int bv = blockIdx.x;
  int t = threadIdx.x;
  const unsigned short* vb = Vb + (size_t)bv * (SEQL * DMOD) + t * 2;
  float s0 = 0.f, s1 = 0.f;
  #pragma unroll 4
  for (int l = 0; l < SEQL; ++l) {
    unsigned u = *(const unsigned*)(vb + (size_t)l * DMOD);
    s0 += b2f((unsigned short)(u & 0xffffu));
    s1 += b2f((unsigned short)(u >> 16));
  }
  vmean[bv * DMOD + t * 2]     = s0 * (1.0f / 512.0f);
  vmean[bv * DMOD + t * 2 + 1] = s1 * (1.0f / 512.0f);
}

// ---------------- ctx = broadcast vmean (bf16 out, vectorized) ----------------
__global__ void ctx_fill_kernel(const float* __restrict__ vmean,
                                unsigned short* __restrict__ ctxb) {
  size_t i = (size_t)blockIdx.x * 256 + threadIdx.x;
  if (i >= (size_t)(SBIG / 4)) return;
  size_t e = i * 4;
  int dm = (int)(e & 511);
  int bv = (int)(e >> 18);
  float4 vm = *(const float4*)(vmean + bv * DMOD + dm);
  ushort4 o;
  o.x = f2b(vm.x); o.y = f2b(vm.y); o.z = f2b(vm.z); o.w = f2b(vm.w);
  *(ushort4*)(ctxb + e) = o;
}

// ---------------- MFMA attention for selected queries: block per (bh) ----------------
__global__ __launch_bounds__(256) void attn2_kernel(const float* __restrict__ QK,
                                                    const unsigned short* __restrict__ Vb,
                                                    const int* __restrict__ top,
                                                    unsigned short* __restrict__ ctxb) {
  __shared__ __align__(16) unsigned short KV[512 * 64];
  __shared__ __align__(16) unsigned short P[48 * 512];
  __shared__ __align__(16) unsigned short Qs[48 * 64];
  __shared__ int topi[NSAMP];
  int bh = blockIdx.x;
  int bv = bh >> 3, head = bh & 7;
  int tid = threadIdx.x;
  int wv = tid >> 6, lane = tid & 63;
  int r16 = lane & 15, kq = lane >> 4;
  const float* base = QK + (size_t)bv * (SEQL * QKS);
  const unsigned short* vbase = Vb + (size_t)bv * (SEQL * DMOD) + head * 64;

  if (tid < NSAMP) topi[tid] = top[bh * NSAMP + tid];
  __syncthreads();

  for (int c = tid; c < NSAMP * 16; c += 256) {
    int u = c >> 4, dq = c & 15;
    float4 q4 = *(const float4*)(base + (size_t)topi[u] * QKS + head * 64 + dq * 4);
    ushort4 o;
    o.x = f2b(q4.x * 0.125f); o.y = f2b(q4.y * 0.125f);
    o.z = f2b(q4.z * 0.125f); o.w = f2b(q4.w * 0.125f);
    int byte = ((u << 7) | (dq << 3)) ^ ((u & 7) << 4);
    *(ushort4*)((char*)Qs + byte) = o;
  }
  for (int c = tid; c < 512 * 16; c += 256) {
    int l = c >> 4, dq = c & 15;
    float4 k4 = *(const float4*)(base + (size_t)l * QKS + 512 + head * 64 + dq * 4);
    ushort4 o;
    o.x = f2b(k4.x); o.y = f2b(k4.y); o.z = f2b(k4.z); o.w = f2b(k4.w);
    int byte = ((l << 7) | (dq << 3)) ^ ((l & 7) << 4);
    *(ushort4*)((char*)KV + byte) = o;
  }
  __syncthreads();

  // QK^T: scores[48][512]
  {
    f32x4 acc[3][8];
    #pragma unroll
    for (int m = 0; m < 3; ++m)
      #pragma unroll
      for (int j = 0; j < 8; ++j) acc[m][j] = (f32x4){0.f, 0.f, 0.f, 0.f};
    bf16x8 afr[3][2];
    #pragma unroll
    for (int m = 0; m < 3; ++m)
      #pragma unroll
      for (int ks = 0; ks < 2; ++ks) {
        int row = m * 16 + r16;
        int addr = ((row << 7) | (ks << 6) | (kq << 4)) ^ ((row & 7) << 4);
        afr[m][ks] = *(const bf16x8*)((const char*)Qs + addr);
      }
    #pragma unroll
    for (int j = 0; j < 8; ++j) {
      int nrow = (wv * 8 + j) * 16 + r16;
      #pragma unroll
      for (int ks = 0; ks < 2; ++ks) {
        int addr = ((nrow << 7) | (ks << 6) | (kq << 4)) ^ ((nrow & 7) << 4);
        bf16x8 bfr = *(const bf16x8*)((const char*)KV + addr);
        #pragma unroll
        for (int m = 0; m < 3; ++m)
          acc[m][j] = __builtin_amdgcn_mfma_f32_16x16x32_bf16(afr[m][ks], bfr, acc[m][j], 0, 0, 0);
      }
    }
    #pragma unroll
    for (int m = 0; m < 3; ++m)
      #pragma unroll
      for (int j = 0; j < 8; ++j) {
        int l = (wv * 8 + j) * 16 + r16;
        #pragma unroll
        for (int r = 0; r < 4; ++r) {
          int u = m * 16 + kq * 4 + r;
          int byte = ((u << 10) | (l << 1)) ^ ((u & 7) << 4);
          *(unsigned short*)((char*)P + byte) = f2b(acc[m][j][r]);
        }
      }
  }
  __syncthreads();

  // stage V^T into KV region (K dead) from bf16 V
  for (int c = tid; c < 512 * 8; c += 256) {
    int l = c >> 3, dq = c & 7;
    bf16x8 v8 = *(const bf16x8*)(vbase + (size_t)l * DMOD + dq * 8);
    #pragma unroll
    for (int j = 0; j < 8; ++j) {
      int d = dq * 8 + j;
      int byte = ((d << 10) | (l << 1)) ^ ((d & 7) << 4);
      *(unsigned short*)((char*)KV + byte) = (unsigned short)v8[j];
    }
  }
  // softmax on P rows
  for (int u = wv; u < NSAMP; u += 4) {
    int byte = ((u << 10) | (lane << 4)) ^ ((u & 7) << 4);
    bf16x8 sv = *(const bf16x8*)((const char*)P + byte);
    float s[8];
    #pragma unroll
    for (int j = 0; j < 8; ++j) s[j] = b2f((unsigned short)sv[j]);
    float mx = s[0];
    #pragma unroll
    for (int j = 1; j < 8; ++j) mx = fmaxf(mx, s[j]);
    #pragma unroll
    for (int off = 32; off > 0; off >>= 1) mx = fmaxf(mx, __shfl_xor(mx, off));
    float e[8], sm = 0.f;
    #pragma unroll
    for (int j = 0; j < 8; ++j) { e[j] = __expf(s[j] - mx); sm += e[j]; }
    #pragma unroll
    for (int off = 32; off > 0; off >>= 1) sm += __shfl_xor(sm, off);
    float inv = 1.0f / sm;
    bf16x8 pv;
    #pragma unroll
    for (int j = 0; j < 8; ++j) pv[j] = (short)f2b(e[j] * inv);
    *(bf16x8*)((char*)P + byte) = pv;
  }
  __syncthreads();

  // PV: ctx[48][64] = P @ V
  {
    f32x4 acc2[3];
    #pragma unroll
    for (int m = 0; m < 3; ++m) acc2[m] = (f32x4){0.f, 0.f, 0.f, 0.f};
    for (int kst = 0; kst < 16; ++kst) {
      int vrow = wv * 16 + r16;
      int baddr = ((vrow << 10) | (kst << 6) | (kq << 4)) ^ ((vrow & 7) << 4);
      bf16x8 bfr = *(const bf16x8*)((const char*)KV + baddr);
      #pragma unroll
      for (int m = 0; m < 3; ++m) {
        int prow = m * 16 + r16;
        int aaddr = ((prow << 10) | (kst << 6) | (kq << 4)) ^ ((prow & 7) << 4);
        bf16x8 afr2 = *(const bf16x8*)((const char*)P + aaddr);
        acc2[m] = __builtin_amdgcn_mfma_f32_16x16x32_bf16(afr2, bfr, acc2[m], 0, 0, 0);
      }
    }
    int d = wv * 16 + r16;
    #pragma unroll
    for (int m = 0; m < 3; ++m)
      #pragma unroll
      for (int r = 0; r < 4; ++r) {
        int u = m * 16 + kq * 4 + r;
        if (u < NSAMP) {
          size_t off = (size_t)bv * (SEQL * DMOD) + (size_t)topi[u] * DMOD + head * 64 + d;
          ctxb[off] = f2b(acc2[m][r]);
        }
      }
  }
}

// ---------------- residual add + layernorm (vectorized: 2 rows/block) ----------------
// BMODE: 0 none, 2 bf16 residual. OUT: 0 none, 1 bf16 mirror, 3 h3 triple (stride 1536)
template<int BMODE, int OUT>
__global__ __launch_bounds__(256) void add_ln(const float* __restrict__ a,
                                              const unsigned short* __restrict__ b,
                                              const float* __restrict__ g,
                                              const float* __restrict__ be,
                                              float* __restrict__ out,
                                              unsigned short* __restrict__ outb,
                                              unsigned short* __restrict__ outh3) {
  int row = blockIdx.x * 2 + (threadIdx.x >> 7);
  int t = threadIdx.x & 127;
  int wave = threadIdx.x >> 6;
  int lane = threadIdx.x & 63;
  size_t base = (size_t)row * DMOD + t * 4;
  float4 x = *(const float4*)(a + base);
  if (BMODE == 2) {
    ushort4 r4 = *(const ushort4*)(b + base);
    x.x += b2f(r4.x); x.y += b2f(r4.y); x.z += b2f(r4.z); x.w += b2f(r4.w);
  }
  float s1 = x.x + x.y + x.z + x.w;
  float s2 = x.x * x.x + x.y * x.y + x.z * x.z + x.w * x.w;
  #pragma unroll
  for (int off = 32; off > 0; off >>= 1) {
    s1 += __shfl_xor(s1, off);
    s2 += __shfl_xor(s2, off);
  }
  __shared__ float sh[8];
  if (lane == 0) { sh[wave * 2] = s1; sh[wave * 2 + 1] = s2; }
  __syncthreads();
  int mate = wave ^ 1;
  s1 += sh[mate * 2];
  s2 += sh[mate * 2 + 1];
  float mu = s1 * (1.0f / 512.0f);
  float var = s2 * (1.0f / 512.0f) - mu * mu;
  float rstd = rsqrtf(var + 1e-5f);
  float4 gg = *(const float4*)(g + t * 4);
  float4 bb = *(const float4*)(be + t * 4);
  float4 o;
  o.x = (x.x - mu) * rstd * gg.x + bb.x;
  o.y = (x.y - mu) * rstd * gg.y + bb.y;
  o.z = (x.z - mu) * rstd * gg.z + bb.z;
  o.w = (x.w - mu) * rstd * gg.w + bb.w;
  *(float4*)(out + base) = o;
  if (OUT == 1) {
    ushort4 ob;
    ob.x = f2b(o.x); ob.y = f2b(o.y); ob.z = f2b(o.z); ob.w = f2b(o.w);
    *(ushort4*)(outb + base) = ob;
  }
  if (OUT == 3) {
    ushort4 hi4, lo4;
    hi4.x = f2b(o.x); lo4.x = f2b(o.x - b2f(hi4.x));
    hi4.y = f2b(o.y); lo4.y = f2b(o.y - b2f(hi4.y));
    hi4.z = f2b(o.z); lo4.z = f2b(o.z - b2f(hi4.z));
    hi4.w = f2b(o.w); lo4.w = f2b(o.w - b2f(hi4.w));
    size_t base3 = (size_t)row * K3 + t * 4;
    *(ushort4*)(outh3 + base3)        = hi4;
    *(ushort4*)(outh3 + base3 + 512)  = hi4;
    *(ushort4*)(outh3 + base3 + 1024) = lo4;
  }
}

// ---------------- head via MFMA: partial[blk*4+w][2688], K-chunk 512/block ----------------
__global__ __launch_bounds__(256) void head_partial_mfma(const unsigned short* __restrict__ hbf,
                                                         const float* __restrict__ Wh,
                                                         float* __restrict__ partial) {
  __shared__ __align__(16) unsigned short Hs[32 * 512];
  __shared__ __align__(16) unsigned short Ws[96 * 512];
  int blk = blockIdx.x;
  int k0 = blk * 512;
  int tid = threadIdx.x;
  int wv = tid >> 6, lane = tid & 63;
  int r16 = lane & 15, kq = lane >> 4;

  for (int c = tid; c < 32 * 64; c += 256) {
    int row = c >> 6, col8 = c & 63;
    int src = row < 28 ? row : 0;
    bf16x8 v = *(const bf16x8*)(hbf + (size_t)src * 262144 + k0 + col8 * 8);
    int byte = ((row << 10) | (col8 << 4)) ^ ((row & 7) << 4);
    *(bf16x8*)((char*)Hs + byte) = v;
  }
  for (int c = tid; c < 96 * 64; c += 256) {
    int row = c >> 6, col8 = c & 63;
    const float* src = Wh + (size_t)row * 262144 + k0 + col8 * 8;
    float4 va = *(const float4*)(src);
    float4 vb = *(const float4*)(src + 4);
    bf16x8 o8;
    o8[0] = (short)f2b(va.x); o8[1] = (short)f2b(va.y);
    o8[2] = (short)f2b(va.z); o8[3] = (short)f2b(va.w);
    o8[4] = (short)f2b(vb.x); o8[5] = (short)f2b(vb.y);
    o8[6] = (short)f2b(vb.z); o8[7] = (short)f2b(vb.w);
    int byte = ((row << 10) | (col8 << 4)) ^ ((row & 7) << 4);
    *(bf16x8*)((char*)Ws + byte) = o8;
  }
  __syncthreads();

  f32x4 acc[2][6];
  #pragma unroll
  for (int mt = 0; mt < 2; ++mt)
    #pragma unroll
    for (int nt = 0; nt < 6; ++nt) acc[mt][nt] = (f32x4){0.f, 0.f, 0.f, 0.f};

  #pragma unroll
  for (int kk = 0; kk < 4; ++kk) {
    int kfrag = wv * 4 + kk;
    bf16x8 afr[2];
    #pragma unroll
    for (int mt = 0; mt < 2; ++mt) {
      int row = mt * 16 + r16;
      int byte = ((row << 10) | (kfrag << 6) | (kq << 4)) ^ ((row & 7) << 4);
      afr[mt] = *(const bf16x8*)((const char*)Hs + byte);
    }
    #pragma unroll
    for (int nt = 0; nt < 6; ++nt) {
      int row = nt * 16 + r16;
      int byte = ((row << 10) | (kfrag << 6) | (kq << 4)) ^ ((row & 7) << 4);
      bf16x8 bfr = *(const bf16x8*)((const char*)Ws + byte);
      #pragma unroll
      for (int mt = 0; mt < 2; ++mt)
        acc[mt][nt] = __builtin_amdgcn_mfma_f32_16x16x32_bf16(afr[mt], bfr, acc[mt][nt], 0, 0, 0);
    }
  }
  size_t prow = (size_t)(blk * 4 + wv) * 2688;
  #pragma unroll
  for (int mt = 0; mt < 2; ++mt)
    #pragma unroll
    for (int nt = 0; nt < 6; ++nt)
      #pragma unroll
      for (int r = 0; r < 4; ++r) {
        int m = mt * 16 + kq * 4 + r;
        int n = nt * 16 + r16;
        if (m < 28) partial[prow + m * 96 + n] = acc[mt][nt][r];
      }
}

__global__ __launch_bounds__(256) void head_reduce(const float* __restrict__ partial,
                                                   const float* __restrict__ bh_,
                                                   float* __restrict__ out) {
  int o = blockIdx.x;
  int tid = threadIdx.x;
  float s = 0.f;
  for (int b = tid; b < 2048; b += 256) s += partial[(size_t)b * 2688 + o];
  __shared__ float red[256];
  red[tid] = s;
  __syncthreads();
  for (int st = 128; st > 0; st >>= 1) {
    if (tid < st) red[tid] += red[tid + st];
    __syncthreads();
  }
  if (tid == 0) {
    int m = o / 96, p = o % 96;
    int b = m / NVARS, v = m % NVARS;
    out[(size_t)b * (NPRED * NVARS) + (size_t)p * NVARS + v] = red[0] + bh_[p];
  }
}

extern "C" void kernel_launch(void* const* d_in, const int* in_sizes, int n_in,
                              void* d_out, int out_size, void* d_ws, size_t ws_size,
                              hipStream_t stream) {
  const float* x_enc = (const float*)d_in[0];
  const float* w_emb = (const float*)d_in[1];
  const float* b_emb = (const float*)d_in[2];
  const float* w_pos = (const float*)d_in[3];
  const float* Wq = (const float*)d_in[4];
  const float* bq = (const float*)d_in[5];
  const float* Wk = (const float*)d_in[6];
  const float* bk = (const float*)d_in[7];
  const float* Wv = (const float*)d_in[8];
  const float* bv_ = (const float*)d_in[9];
  const float* Wo = (const float*)d_in[10];
  const float* bo = (const float*)d_in[11];
  const float* W1 = (const float*)d_in[12];
  const float* b1 = (const float*)d_in[13];
  const float* W2 = (const float*)d_in[14];
  const float* b2 = (const float*)d_in[15];
  const float* g1 = (const float*)d_in[16];
  const float* be1 = (const float*)d_in[17];
  const float* g2 = (const float*)d_in[18];
  const float* be2 = (const float*)d_in[19];
  const float* gF = (const float*)d_in[20];
  const float* bF = (const float*)d_in[21];
  const float* Wh = (const float*)d_in[22];
  const float* bh_ = (const float*)d_in[23];
  float* out = (float*)d_out;

  const size_t S = (size_t)SBIG;
  const size_t SB = S * 4;                    // 29,360,128 B
  char* ws = (char*)d_ws;
  float* h    = (float*)(ws);                 // [0, SB)
  float* QKb  = (float*)(ws + SB);            // [SB, 3SB): [14336][1024] fp32 (56MB)
  unsigned short* Vb   = (unsigned short*)(ws + 3 * SB);            // 14.7 MB
  unsigned short* Ob_b = (unsigned short*)(ws + 3 * SB + SB / 2);   // 14.7 MB
  // weight scratch [4SB, 4SB+9MB)
  unsigned short* Wqk3 = (unsigned short*)(ws + 4 * SB);                    // 3 MB
  unsigned short* Wv_b = (unsigned short*)(ws + 4 * SB + 0x300000);         // 0.5 MB
  unsigned short* Wo_b = (unsigned short*)(ws + 4 * SB + 0x380000);         // 0.5 MB
  unsigned short* W1_b = (unsigned short*)(ws + 4 * SB + 0x400000);         // 2 MB
  unsigned short* W2_b = (unsigned short*)(ws + 4 * SB + 0x600000);         // 2 MB
  float* bias_qk       = (float*)(ws + 4 * SB + 0x800000);                  // 4 KB
  // h3 [14336][1536] bf16 = 44 MB at [4SB+9MB, 4SB+53MB) (< 6SB)
  unsigned short* h3 = (unsigned short*)(ws + 4 * SB + 0x900000);
  // aliases inside h3 region (h3 dead after QK+V gemms):
  unsigned short* CTXb = h3;                                        // 14.7 MB
  unsigned short* h_bf = (unsigned short*)((char*)h3 + 0x1000000);  // 14.7 MB
  unsigned short* FFNb = (unsigned short*)QKb;   // after attn consumed QK (2SB)
  float* partial = QKb;                          // head phase (22 MB)
  int*   idx = (int*)(ws + 6 * SB);                        // 70KB
  float* Mv  = (float*)(ws + 6 * SB + 0x20000);            // 448KB
  int*   top = (int*)(ws + 6 * SB + 0xA0000);              // 31KB
  float* vmean = (float*)(ws + 6 * SB + 0xB0000);          // 56KB
  if (ws_size < 6 * SB + 0xC0000) return;

  dim3 b256(256);
  int gVec = (int)(S / 4 / 256);   // 7168

  embed_kernel<<<gVec, b256, 0, stream>>>(x_enc, w_emb, b_emb, w_pos, h, h3);

  for (int l = 0; l < 2; ++l) {
    const float* Wql = Wq + (size_t)l * DMOD * DMOD;
    const float* Wkl = Wk + (size_t)l * DMOD * DMOD;
    const float* Wvl = Wv + (size_t)l * DMOD * DMOD;
    const float* Wol = Wo + (size_t)l * DMOD * DMOD;
    const float* W1l = W1 + (size_t)l * DFFN * DMOD;
    const float* W2l = W2 + (size_t)l * DMOD * DFFN;

    prep_weights<<<4100, b256, 0, stream>>>(Wql, Wkl, Wvl, Wol, W1l, W2l,
                                            bq + l * DMOD, bk + l * DMOD,
                                            Wqk3, Wv_b, Wo_b, W1_b, W2_b, bias_qk);

    // QK projection: single GEMM over K'=1536 == exact hh+hl+lh (fp32-grade)
    dim3 gqk(QKS / 128, NROWS / 128);
    gemm_mfma<0, 0><<<gqk, b256, 0, stream>>>(h3, K3, Wqk3, K3, bias_qk,
                                              QKb, (unsigned short*)0,
                                              NROWS, QKS, K3, QKS);
    // V projection (bf16): A = hi copy within h3 (lda = 1536)
    dim3 gv(DMOD / 128, NROWS / 128);
    gemm_mfma<0, 1><<<gv, b256, 0, stream>>>(h3, K3, Wv_b, DMOD, bv_ + l * DMOD,
                                             (float*)0, Vb, NROWS, DMOD, DMOD, DMOD);

    make_idx_kernel<<<(SEQL * NSAMP + 255) / 256, b256, 0, stream>>>(l, idx);
    m2_kernel<<<NBH, dim3(512), 0, stream>>>(QKb, idx, Mv);
    topk_kernel<<<NBH, b256, 0, stream>>>(Mv, top);
    vmean_kernel<<<NBV, b256, 0, stream>>>(Vb, vmean);
    ctx_fill_kernel<<<gVec, b256, 0, stream>>>(vmean, CTXb);
    attn2_kernel<<<NBH, b256, 0, stream>>>(QKb, Vb, top, CTXb);

    dim3 go(DMOD / 128, NROWS / 128);
    gemm_mfma<0, 1><<<go, b256, 0, stream>>>(CTXb, DMOD, Wo_b, DMOD, bo + l * DMOD,
                                             (float*)0, Ob_b, NROWS, DMOD, DMOD, DMOD);
    add_ln<2, 1><<<NROWS / 2, b256, 0, stream>>>(h, Ob_b, g1 + l * DMOD, be1 + l * DMOD,
                                                 h, h_bf, (unsigned short*)0);

    dim3 gf1(DFFN / 128, NROWS / 128);
    gemm_mfma<1, 1><<<gf1, b256, 0, stream>>>(h_bf, DMOD, W1_b, DMOD, b1 + l * DFFN,
                                              (float*)0, FFNb, NROWS, DFFN, DMOD, DFFN);
    dim3 gf2(DMOD / 128, NROWS / 128);
    gemm_mfma<0, 1><<<gf2, b256, 0, stream>>>(FFNb, DFFN, W2_b, DFFN, b2 + l * DMOD,
                                              (float*)0, Ob_b, NROWS, DMOD, DFFN, DMOD);
    if (l == 0) {
      add_ln<2, 3><<<NROWS / 2, b256, 0, stream>>>(h, Ob_b, g2 + l * DMOD, be2 + l * DMOD,
                                                   h, (unsigned short*)0, h3);
    } else {
      add_ln<2, 0><<<NROWS / 2, b256, 0, stream>>>(h, Ob_b, g2 + l * DMOD, be2 + l * DMOD,
                                                   h, (unsigned short*)0, (unsigned short*)0);
    }
  }

  add_ln<0, 1><<<NROWS / 2, b256, 0, stream>>>(h, (const unsigned short*)0, gF, bF,
                                               h, h_bf, (unsigned short*)0);
  head_partial_mfma<<<512, b256, 0, stream>>>(h_bf, Wh, partial);
  head_reduce<<<NBV * NPRED, b256, 0, stream>>>(partial, bh_, out);
}

// Round 12
// 755.898 us; speedup vs baseline: 1.3498x; 1.0632x over previous
//
#include <hip/hip_runtime.h>
#include <math.h>

#define SEQL 512
#define DMOD 512
#define NHEAD 8
#define DHEAD 64
#define DFFN 2048
#define NBATCH 4
#define NVARS 7
#define NBV 28          // NBATCH*NVARS
#define NBH 224         // NBV*NHEAD
#define NROWS 14336     // NBV*SEQL
#define NSAMP 35        // U_part = u = 35
#define NPRED 96
#define SBIG 7340032    // NBV*SEQL*DMOD floats
#define QKS 1024        // fused QK row stride

typedef short bf16x8 __attribute__((ext_vector_type(8)));
typedef float f32x4 __attribute__((ext_vector_type(4)));

#define GLDS(gptr, lptr) \
  __builtin_amdgcn_global_load_lds((const __attribute__((address_space(1))) void*)(gptr), \
                                   (__attribute__((address_space(3))) void*)(lptr), 16, 0, 0)

__device__ inline unsigned short f2b(float f) {
  unsigned u = __builtin_bit_cast(unsigned, f);
  unsigned r = (u + 0x7FFFu + ((u >> 16) & 1u)) >> 16;
  return (unsigned short)r;
}
__device__ inline float b2f(unsigned short h) {
  return __builtin_bit_cast(float, (unsigned)h << 16);
}

// ---------------- threefry2x32 (matches jax._src.prng) ----------------
__device__ inline void threefry2x32(unsigned k0, unsigned k1,
                                    unsigned x0, unsigned x1,
                                    unsigned &o0, unsigned &o1) {
  unsigned ks2 = k0 ^ k1 ^ 0x1BD11BDAu;
  unsigned ks[3] = {k0, k1, ks2};
  x0 += k0; x1 += k1;
  const unsigned rot[2][4] = {{13u,15u,26u,6u},{17u,29u,16u,24u}};
  #pragma unroll
  for (int i = 0; i < 5; ++i) {
    #pragma unroll
    for (int j = 0; j < 4; ++j) {
      unsigned r = rot[i & 1][j];
      x0 += x1;
      x1 = (x1 << r) | (x1 >> (32u - r));
      x1 ^= x0;
    }
    x0 += ks[(i + 1) % 3];
    x1 += ks[(i + 2) % 3] + (unsigned)(i + 1);
  }
  o0 = x0; o1 = x1;
}

__global__ void make_idx_kernel(int layer, int* idx) {
  int i = blockIdx.x * 256 + threadIdx.x;
  if (i >= SEQL * NSAMP) return;
  unsigned kl0, kl1, o0, o1;
  threefry2x32(0u, 42u, 0u, (unsigned)layer, kl0, kl1);
  threefry2x32(kl0, kl1, (unsigned)i, (unsigned)(SEQL * NSAMP + i), o0, o1);
  idx[i] = (int)(o1 & 511u);
}

// ---------------- embedding (vectorized, fused hi/lo split) ----------------
__global__ void embed_kernel(const float* __restrict__ x_enc,
                             const float* __restrict__ w_emb,
                             const float* __restrict__ b_emb,
                             const float* __restrict__ w_pos,
                             float* __restrict__ h,
                             unsigned short* __restrict__ h_hi,
                             unsigned short* __restrict__ h_lo) {
  size_t i = (size_t)blockIdx.x * 256 + threadIdx.x;
  if (i >= (size_t)(SBIG / 4)) return;
  size_t e = i * 4;
  int dm = (int)(e & 511);
  int l  = (int)((e >> 9) & 511);
  int bv = (int)(e >> 18);
  int b = bv / NVARS, v = bv % NVARS;
  float xs = x_enc[((size_t)b * SEQL + l) * NVARS + v];
  float4 we = *(const float4*)(w_emb + dm);
  float4 bb = *(const float4*)(b_emb + dm);
  float4 wp = *(const float4*)(w_pos + (size_t)l * DMOD + dm);
  float4 val;
  val.x = xs * we.x + bb.x + wp.x;
  val.y = xs * we.y + bb.y + wp.y;
  val.z = xs * we.z + bb.z + wp.z;
  val.w = xs * we.w + bb.w + wp.w;
  *(float4*)(h + e) = val;
  ushort4 hi4, lo4;
  hi4.x = f2b(val.x); lo4.x = f2b(val.x - b2f(hi4.x));
  hi4.y = f2b(val.y); lo4.y = f2b(val.y - b2f(hi4.y));
  hi4.z = f2b(val.z); lo4.z = f2b(val.z - b2f(hi4.z));
  hi4.w = f2b(val.w); lo4.w = f2b(val.w - b2f(hi4.w));
  *(ushort4*)(h_hi + e) = hi4;
  *(ushort4*)(h_lo + e) = lo4;
}

// ---------------- fused per-layer weight prep (one dispatch) ----------------
__global__ void prep_weights(const float* __restrict__ Wq, const float* __restrict__ Wk,
                             const float* __restrict__ Wv, const float* __restrict__ Wo,
                             const float* __restrict__ W1, const float* __restrict__ W2,
                             unsigned short* __restrict__ Wqk_hi, unsigned short* __restrict__ Wqk_lo,
                             unsigned short* __restrict__ Wv_b, unsigned short* __restrict__ Wo_b,
                             unsigned short* __restrict__ W1_b, unsigned short* __restrict__ W2_b) {
  const int Q4 = 65536;   // 262144/4
  int g = blockIdx.x * 256 + threadIdx.x;
  if (g < 2 * Q4) {
    const float* src = g < Q4 ? Wq : Wk;
    unsigned short* hi = Wqk_hi + (g < Q4 ? 0 : DMOD * DMOD);
    unsigned short* lo = Wqk_lo + (g < Q4 ? 0 : DMOD * DMOD);
    int off = (g < Q4 ? g : g - Q4) * 4;
    float4 v = *(const float4*)(src + off);
    ushort4 h4, l4;
    h4.x = f2b(v.x); l4.x = f2b(v.x - b2f(h4.x));
    h4.y = f2b(v.y); l4.y = f2b(v.y - b2f(h4.y));
    h4.z = f2b(v.z); l4.z = f2b(v.z - b2f(h4.z));
    h4.w = f2b(v.w); l4.w = f2b(v.w - b2f(h4.w));
    *(ushort4*)(hi + off) = h4;
    *(ushort4*)(lo + off) = l4;
    return;
  }
  const float* src;
  unsigned short* dst;
  int off;
  if (g < 3 * Q4)      { src = Wv; dst = Wv_b; off = (g - 2 * Q4) * 4; }
  else if (g < 4 * Q4) { src = Wo; dst = Wo_b; off = (g - 3 * Q4) * 4; }
  else if (g < 4 * Q4 + 262144) { src = W1; dst = W1_b; off = (g - 4 * Q4) * 4; }
  else                 { src = W2; dst = W2_b; off = (g - 4 * Q4 - 262144) * 4; }
  float4 v = *(const float4*)(src + off);
  ushort4 o;
  o.x = f2b(v.x); o.y = f2b(v.y); o.z = f2b(v.z); o.w = f2b(v.w);
  *(ushort4*)(dst + off) = o;
}

// ---------------- split-bf16 MFMA GEMM (3-pass hi/lo): C = A@W^T + [bq|bk] ----------------
// staging via global_load_lds w=16, linear LDS dest + pre-swizzled global source
__global__ __launch_bounds__(256) void gemm_mfma3(const unsigned short* __restrict__ Ah,
                                                  const unsigned short* __restrict__ Al,
                                                  const unsigned short* __restrict__ Bh,
                                                  const unsigned short* __restrict__ Bl,
                                                  const float* __restrict__ bq,
                                                  const float* __restrict__ bk,
                                                  float* __restrict__ C,
                                                  int M, int N, int K, int ldc) {
  __shared__ __align__(16) unsigned short AsH[128 * 64];
  __shared__ __align__(16) unsigned short AsL[128 * 64];
  __shared__ __align__(16) unsigned short BsH[128 * 64];
  __shared__ __align__(16) unsigned short BsL[128 * 64];
  int nwg = gridDim.x * gridDim.y;
  int flat = blockIdx.y * gridDim.x + blockIdx.x;
  int swz = (flat & 7) * (nwg >> 3) + (flat >> 3);
  int bxs = swz % gridDim.x, bys = swz / gridDim.x;
  int bm = bys * 128, bn = bxs * 128;
  int tid = threadIdx.x;
  int wave = tid >> 6, lane = tid & 63;
  int wr = wave >> 1, wc = wave & 1;
  int r16 = lane & 15, kq = lane >> 4;

  f32x4 acc[4][4];
  #pragma unroll
  for (int i = 0; i < 4; ++i)
    #pragma unroll
    for (int j = 0; j < 4; ++j) acc[i][j] = (f32x4){0.f, 0.f, 0.f, 0.f};

  for (int kt = 0; kt < K; kt += 64) {
    __syncthreads();
    #pragma unroll
    for (int i = 0; i < 4; ++i) {
      int c = i * 256 + tid;
      int row = c >> 3, kb = c & 7;
      int kbs = kb ^ (row & 7);             // pre-swizzled source
      size_t offA = (size_t)(bm + row) * K + kt + kbs * 8;
      size_t offB = (size_t)(bn + row) * K + kt + kbs * 8;
      int ldst = (i * 256 + (tid & 192)) << 4;   // wave-uniform linear dest
      GLDS(Ah + offA, (char*)AsH + ldst);
      GLDS(Al + offA, (char*)AsL + ldst);
      GLDS(Bh + offB, (char*)BsH + ldst);
      GLDS(Bl + offB, (char*)BsL + ldst);
    }
    __syncthreads();
    #pragma unroll
    for (int ks = 0; ks < 2; ++ks) {
      bf16x8 ah[4], al[4], bh[4], bl[4];
      #pragma unroll
      for (int mi = 0; mi < 4; ++mi) {
        int row = wr * 64 + mi * 16 + r16;
        int addr = ((row << 7) | (ks << 6) | (kq << 4)) ^ ((row & 7) << 4);
        ah[mi] = *(const bf16x8*)((const char*)AsH + addr);
        al[mi] = *(const bf16x8*)((const char*)AsL + addr);
      }
      #pragma unroll
      for (int ni = 0; ni < 4; ++ni) {
        int row = wc * 64 + ni * 16 + r16;
        int addr = ((row << 7) | (ks << 6) | (kq << 4)) ^ ((row & 7) << 4);
        bh[ni] = *(const bf16x8*)((const char*)BsH + addr);
        bl[ni] = *(const bf16x8*)((const char*)BsL + addr);
      }
      #pragma unroll
      for (int mi = 0; mi < 4; ++mi)
        #pragma unroll
        for (int ni = 0; ni < 4; ++ni) {
          acc[mi][ni] = __builtin_amdgcn_mfma_f32_16x16x32_bf16(ah[mi], bh[ni], acc[mi][ni], 0, 0, 0);
          acc[mi][ni] = __builtin_amdgcn_mfma_f32_16x16x32_bf16(ah[mi], bl[ni], acc[mi][ni], 0, 0, 0);
          acc[mi][ni] = __builtin_amdgcn_mfma_f32_16x16x32_bf16(al[mi], bh[ni], acc[mi][ni], 0, 0, 0);
        }
    }
  }
  int crow0 = bm + wr * 64 + (lane >> 4) * 4;
  int ccol0 = bn + wc * 64 + (lane & 15);
  #pragma unroll
  for (int mi = 0; mi < 4; ++mi) {
    #pragma unroll
    for (int ni = 0; ni < 4; ++ni) {
      int col = ccol0 + ni * 16;
      float bvv = col < 512 ? bq[col] : bk[col - 512];
      #pragma unroll
      for (int r = 0; r < 4; ++r) {
        int row = crow0 + mi * 16 + r;
        C[(size_t)row * ldc + col] = acc[mi][ni][r] + bvv;
      }
    }
  }
}

// ---------------- bf16 MFMA GEMM, 2-phase double-buffered LDS ----------------
template<int ACT, int OUTBF>
__global__ __launch_bounds__(256) void gemm_mfma(const unsigned short* __restrict__ A,
                                                 const unsigned short* __restrict__ W,
                                                 const float* __restrict__ bias,
                                                 float* __restrict__ Cf,
                                                 unsigned short* __restrict__ Cb,
                                                 int M, int N, int K) {
  __shared__ __align__(16) unsigned short As[2][128 * 64];   // 16 KB x2
  __shared__ __align__(16) unsigned short Bs[2][128 * 64];   // 16 KB x2
  int nwg = gridDim.x * gridDim.y;
  int flat = blockIdx.y * gridDim.x + blockIdx.x;
  int swz = (flat & 7) * (nwg >> 3) + (flat >> 3);
  int bxs = swz % gridDim.x, bys = swz / gridDim.x;
  int bm = bys * 128, bn = bxs * 128;
  int tid = threadIdx.x;
  int wave = tid >> 6, lane = tid & 63;
  int wr = wave >> 1, wc = wave & 1;
  int r16 = lane & 15, kq = lane >> 4;

  f32x4 acc[4][4];
  #pragma unroll
  for (int i = 0; i < 4; ++i)
    #pragma unroll
    for (int j = 0; j < 4; ++j) acc[i][j] = (f32x4){0.f, 0.f, 0.f, 0.f};

#define STAGE_MM(buf, ktv) \
  { \
    for (int i_ = 0; i_ < 4; ++i_) { \
      int c_ = i_ * 256 + tid; \
      int row_ = c_ >> 3, kb_ = c_ & 7; \
      int kbs_ = kb_ ^ (row_ & 7); \
      size_t offA_ = (size_t)(bm + row_) * K + (ktv) + kbs_ * 8; \
      size_t offB_ = (size_t)(bn + row_) * K + (ktv) + kbs_ * 8; \
      int ldst_ = (i_ * 256 + (tid & 192)) << 4; \
      GLDS(A + offA_, (char*)As[buf] + ldst_); \
      GLDS(W + offB_, (char*)Bs[buf] + ldst_); \
    } \
  }

  int nkt = K >> 6;
  STAGE_MM(0, 0);
  __syncthreads();                 // compiler drains vmcnt before barrier
  for (int t = 0; t < nkt; ++t) {
    int cur = t & 1;
    if (t + 1 < nkt) STAGE_MM(cur ^ 1, (t + 1) << 6);
    const char* Ab = (const char*)As[cur];
    const char* Bb = (const char*)Bs[cur];
    #pragma unroll
    for (int ks = 0; ks < 2; ++ks) {
      bf16x8 afr[4], bfr[4];
      #pragma unroll
      for (int mi = 0; mi < 4; ++mi) {
        int row = wr * 64 + mi * 16 + r16;
        int addr = ((row << 7) | (ks << 6) | (kq << 4)) ^ ((row & 7) << 4);
        afr[mi] = *(const bf16x8*)(Ab + addr);
      }
      #pragma unroll
      for (int ni = 0; ni < 4; ++ni) {
        int row = wc * 64 + ni * 16 + r16;
        int addr = ((row << 7) | (ks << 6) | (kq << 4)) ^ ((row & 7) << 4);
        bfr[ni] = *(const bf16x8*)(Bb + addr);
      }
      #pragma unroll
      for (int mi = 0; mi < 4; ++mi)
        #pragma unroll
        for (int ni = 0; ni < 4; ++ni)
          acc[mi][ni] = __builtin_amdgcn_mfma_f32_16x16x32_bf16(afr[mi], bfr[ni], acc[mi][ni], 0, 0, 0);
    }
    __syncthreads();               // drains the in-flight next-buf GLDS too
  }
#undef STAGE_MM

  int crow0 = bm + wr * 64 + (lane >> 4) * 4;
  int ccol0 = bn + wc * 64 + (lane & 15);
  #pragma unroll
  for (int mi = 0; mi < 4; ++mi) {
    #pragma unroll
    for (int ni = 0; ni < 4; ++ni) {
      int col = ccol0 + ni * 16;
      float bvv = bias[col];
      #pragma unroll
      for (int r = 0; r < 4; ++r) {
        int row = crow0 + mi * 16 + r;
        float v = acc[mi][ni][r] + bvv;
        if (ACT) {
          // gelu(tanh approx) = x * sigmoid(2*0.79788456(x+0.044715x^3))
          float x = v;
          float u = x * __builtin_fmaf(0.044715f * x, x, 1.0f);
          float tme = __expf(-1.5957691216057308f * u);
          v = x * __builtin_amdgcn_rcpf(1.0f + tme);
        }
        if (OUTBF) Cb[(size_t)row * N + col] = f2b(v);
        else       Cf[(size_t)row * N + col] = v;
      }
    }
  }
}

// ---------------- M measure: block per (bh), XOR-swizzled float4 K in LDS ----------------
__global__ __launch_bounds__(512) void m2_kernel(const float* __restrict__ QK,
                                                 const int* __restrict__ idx,
                                                 float* __restrict__ Mout) {
  int bh = blockIdx.x;
  int bv = bh >> 3, head = bh & 7;
  int tid = threadIdx.x;                 // 0..511, one q-row each
  __shared__ float Ks[512 * 64];         // 128 KB, word(l,db) = l*64 + ((db^(l&15))<<2)
  const float* base = QK + (size_t)bv * (SEQL * QKS);
  for (int c = tid; c < 512 * 16; c += 512) {
    int l = c >> 4, db = c & 15;
    float4 v = *(const float4*)(base + (size_t)l * QKS + 512 + head * 64 + db * 4);
    *(float4*)(Ks + l * 64 + ((db ^ (l & 15)) << 2)) = v;
  }
  float q[64];
  const float* qp = base + (size_t)tid * QKS + head * 64;
  #pragma unroll
  for (int d4 = 0; d4 < 64; d4 += 4) {
    float4 qv = *(const float4*)(qp + d4);
    q[d4 + 0] = qv.x; q[d4 + 1] = qv.y; q[d4 + 2] = qv.z; q[d4 + 3] = qv.w;
  }
  __syncthreads();
  const int* ip = idx + tid * NSAMP;
  float mx = -INFINITY, sm = 0.f;
  for (int u = 0; u < NSAMP; ++u) {
    int kidx = ip[u];
    const float* kr = Ks + kidx * 64;
    int x = kidx & 15;
    float s = 0.f;
    #pragma unroll
    for (int db = 0; db < 16; ++db) {
      float4 kv = *(const float4*)(kr + ((db ^ x) << 2));
      s += q[db * 4 + 0] * kv.x + q[db * 4 + 1] * kv.y
         + q[db * 4 + 2] * kv.z + q[db * 4 + 3] * kv.w;
    }
    mx = fmaxf(mx, s);
    sm += s;
  }
  Mout[(size_t)bh * SEQL + tid] = mx - sm * (1.0f / 512.0f);
}

// ---------------- top-k (k=35) ----------------
__global__ __launch_bounds__(256) void topk_kernel(const float* __restrict__ Mv,
                                                   int* __restrict__ top) {
  int bh = blockIdx.x;
  int tid = threadIdx.x;
  __shared__ float vals[512];
  __shared__ float rv[256];
  __shared__ int ri[256];
  vals[tid]       = Mv[(size_t)bh * SEQL + tid];
  vals[tid + 256] = Mv[(size_t)bh * SEQL + tid + 256];
  __syncthreads();
  for (int t = 0; t < NSAMP; ++t) {
    float v0 = vals[tid], v1 = vals[tid + 256];
    float bvv; int bii;
    if (v0 >= v1) { bvv = v0; bii = tid; } else { bvv = v1; bii = tid + 256; }
    rv[tid] = bvv; ri[tid] = bii;
    __syncthreads();
    for (int s = 128; s > 0; s >>= 1) {
      if (tid < s) {
        float ov = rv[tid + s]; int oi = ri[tid + s];
        if (ov > rv[tid] || (ov == rv[tid] && oi < ri[tid])) { rv[tid] = ov; ri[tid] = oi; }
      }
      __syncthreads();
    }
    if (tid == 0) { top[bh * NSAMP + t] = ri[0]; vals[ri[0]] = -INFINITY; }
    __syncthreads();
  }
}

// ---------------- mean of V (bf16 V, coalesced: block per bv) ----------------
__global__ __launch_bounds__(256) void vmean_kernel(const unsigned short* __restrict__ Vb,
                                                    float* __restrict__ vmean) {
  int bv = blockIdx.x;                 // 0..27
  int t = threadIdx.x;                 // cols 2t, 2t+1
  const unsigned short* vb = Vb + (size_t)bv * (SEQL * DMOD) + t * 2;
  float s0 = 0.f, s1 = 0.f;
  #pragma unroll 4
  for (int l = 0; l < SEQL; ++l) {
    unsigned u = *(const unsigned*)(vb + (size_t)l * DMOD);
    s0 += b2f((unsigned short)(u & 0xffffu));
    s1 += b2f((unsigned short)(u >> 16));
  }
  vmean[bv * DMOD + t * 2]     = s0 * (1.0f / 512.0f);
  vmean[bv * DMOD + t * 2 + 1] = s1 * (1.0f / 512.0f);
}

// ---------------- ctx = broadcast vmean (bf16 out, vectorized) ----------------
__global__ void ctx_fill_kernel(const float* __restrict__ vmean,
                                unsigned short* __restrict__ ctxb) {
  size_t i = (size_t)blockIdx.x * 256 + threadIdx.x;
  if (i >= (size_t)(SBIG / 4)) return;
  size_t e = i * 4;
  int dm = (int)(e & 511);
  int bv = (int)(e >> 18);
  float4 vm = *(const float4*)(vmean + bv * DMOD + dm);
  ushort4 o;
  o.x = f2b(vm.x); o.y = f2b(vm.y); o.z = f2b(vm.z); o.w = f2b(vm.w);
  *(ushort4*)(ctxb + e) = o;
}

// ---------------- MFMA attention for selected queries: block per (bh) ----------------
__global__ __launch_bounds__(256) void attn2_kernel(const float* __restrict__ QK,
                                                    const unsigned short* __restrict__ Vb,
                                                    const int* __restrict__ top,
                                                    unsigned short* __restrict__ ctxb) {
  __shared__ __align__(16) unsigned short KV[512 * 64];
  __shared__ __align__(16) unsigned short P[48 * 512];
  __shared__ __align__(16) unsigned short Qs[48 * 64];
  __shared__ int topi[NSAMP];
  int bh = blockIdx.x;
  int bv = bh >> 3, head = bh & 7;
  int tid = threadIdx.x;
  int wv = tid >> 6, lane = tid & 63;
  int r16 = lane & 15, kq = lane >> 4;
  const float* base = QK + (size_t)bv * (SEQL * QKS);
  const unsigned short* vbase = Vb + (size_t)bv * (SEQL * DMOD) + head * 64;

  if (tid < NSAMP) topi[tid] = top[bh * NSAMP + tid];
  __syncthreads();

  for (int c = tid; c < NSAMP * 16; c += 256) {
    int u = c >> 4, dq = c & 15;
    float4 q4 = *(const float4*)(base + (size_t)topi[u] * QKS + head * 64 + dq * 4);
    ushort4 o;
    o.x = f2b(q4.x * 0.125f); o.y = f2b(q4.y * 0.125f);
    o.z = f2b(q4.z * 0.125f); o.w = f2b(q4.w * 0.125f);
    int byte = ((u << 7) | (dq << 3)) ^ ((u & 7) << 4);
    *(ushort4*)((char*)Qs + byte) = o;
  }
  for (int c = tid; c < 512 * 16; c += 256) {
    int l = c >> 4, dq = c & 15;
    float4 k4 = *(const float4*)(base + (size_t)l * QKS + 512 + head * 64 + dq * 4);
    ushort4 o;
    o.x = f2b(k4.x); o.y = f2b(k4.y); o.z = f2b(k4.z); o.w = f2b(k4.w);
    int byte = ((l << 7) | (dq << 3)) ^ ((l & 7) << 4);
    *(ushort4*)((char*)KV + byte) = o;
  }
  __syncthreads();

  // QK^T: scores[48][512]
  {
    f32x4 acc[3][8];
    #pragma unroll
    for (int m = 0; m < 3; ++m)
      #pragma unroll
      for (int j = 0; j < 8; ++j) acc[m][j] = (f32x4){0.f, 0.f, 0.f, 0.f};
    bf16x8 afr[3][2];
    #pragma unroll
    for (int m = 0; m < 3; ++m)
      #pragma unroll
      for (int ks = 0; ks < 2; ++ks) {
        int row = m * 16 + r16;
        int addr = ((row << 7) | (ks << 6) | (kq << 4)) ^ ((row & 7) << 4);
        afr[m][ks] = *(const bf16x8*)((const char*)Qs + addr);
      }
    #pragma unroll
    for (int j = 0; j < 8; ++j) {
      int nrow = (wv * 8 + j) * 16 + r16;
      #pragma unroll
      for (int ks = 0; ks < 2; ++ks) {
        int addr = ((nrow << 7) | (ks << 6) | (kq << 4)) ^ ((nrow & 7) << 4);
        bf16x8 bfr = *(const bf16x8*)((const char*)KV + addr);
        #pragma unroll
        for (int m = 0; m < 3; ++m)
          acc[m][j] = __builtin_amdgcn_mfma_f32_16x16x32_bf16(afr[m][ks], bfr, acc[m][j], 0, 0, 0);
      }
    }
    #pragma unroll
    for (int m = 0; m < 3; ++m)
      #pragma unroll
      for (int j = 0; j < 8; ++j) {
        int l = (wv * 8 + j) * 16 + r16;
        #pragma unroll
        for (int r = 0; r < 4; ++r) {
          int u = m * 16 + kq * 4 + r;
          int byte = ((u << 10) | (l << 1)) ^ ((u & 7) << 4);
          *(unsigned short*)((char*)P + byte) = f2b(acc[m][j][r]);
        }
      }
  }
  __syncthreads();

  // stage V^T into KV region (K dead) from bf16 V
  for (int c = tid; c < 512 * 8; c += 256) {
    int l = c >> 3, dq = c & 7;
    bf16x8 v8 = *(const bf16x8*)(vbase + (size_t)l * DMOD + dq * 8);
    #pragma unroll
    for (int j = 0; j < 8; ++j) {
      int d = dq * 8 + j;
      int byte = ((d << 10) | (l << 1)) ^ ((d & 7) << 4);
      *(unsigned short*)((char*)KV + byte) = (unsigned short)v8[j];
    }
  }
  // softmax on P rows
  for (int u = wv; u < NSAMP; u += 4) {
    int byte = ((u << 10) | (lane << 4)) ^ ((u & 7) << 4);
    bf16x8 sv = *(const bf16x8*)((const char*)P + byte);
    float s[8];
    #pragma unroll
    for (int j = 0; j < 8; ++j) s[j] = b2f((unsigned short)sv[j]);
    float mx = s[0];
    #pragma unroll
    for (int j = 1; j < 8; ++j) mx = fmaxf(mx, s[j]);
    #pragma unroll
    for (int off = 32; off > 0; off >>= 1) mx = fmaxf(mx, __shfl_xor(mx, off));
    float e[8], sm = 0.f;
    #pragma unroll
    for (int j = 0; j < 8; ++j) { e[j] = __expf(s[j] - mx); sm += e[j]; }
    #pragma unroll
    for (int off = 32; off > 0; off >>= 1) sm += __shfl_xor(sm, off);
    float inv = 1.0f / sm;
    bf16x8 pv;
    #pragma unroll
    for (int j = 0; j < 8; ++j) pv[j] = (short)f2b(e[j] * inv);
    *(bf16x8*)((char*)P + byte) = pv;
  }
  __syncthreads();

  // PV: ctx[48][64] = P @ V
  {
    f32x4 acc2[3];
    #pragma unroll
    for (int m = 0; m < 3; ++m) acc2[m] = (f32x4){0.f, 0.f, 0.f, 0.f};
    for (int kst = 0; kst < 16; ++kst) {
      int vrow = wv * 16 + r16;
      int baddr = ((vrow << 10) | (kst << 6) | (kq << 4)) ^ ((vrow & 7) << 4);
      bf16x8 bfr = *(const bf16x8*)((const char*)KV + baddr);
      #pragma unroll
      for (int m = 0; m < 3; ++m) {
        int prow = m * 16 + r16;
        int aaddr = ((prow << 10) | (kst << 6) | (kq << 4)) ^ ((prow & 7) << 4);
        bf16x8 afr2 = *(const bf16x8*)((const char*)P + aaddr);
        acc2[m] = __builtin_amdgcn_mfma_f32_16x16x32_bf16(afr2, bfr, acc2[m], 0, 0, 0);
      }
    }
    int d = wv * 16 + r16;
    #pragma unroll
    for (int m = 0; m < 3; ++m)
      #pragma unroll
      for (int r = 0; r < 4; ++r) {
        int u = m * 16 + kq * 4 + r;
        if (u < NSAMP) {
          size_t off = (size_t)bv * (SEQL * DMOD) + (size_t)topi[u] * DMOD + head * 64 + d;
          ctxb[off] = f2b(acc2[m][r]);
        }
      }
  }
}

// ---------------- residual add + layernorm (vectorized: 2 rows/block) ----------------
template<int BMODE, int OUT>
__global__ __launch_bounds__(256) void add_ln(const float* __restrict__ a,
                                              const unsigned short* __restrict__ b,
                                              const float* __restrict__ g,
                                              const float* __restrict__ be,
                                              float* __restrict__ out,
                                              unsigned short* __restrict__ outb,
                                              unsigned short* __restrict__ outh,
                                              unsigned short* __restrict__ outl) {
  int row = blockIdx.x * 2 + (threadIdx.x >> 7);
  int t = threadIdx.x & 127;
  int wave = threadIdx.x >> 6;
  int lane = threadIdx.x & 63;
  size_t base = (size_t)row * DMOD + t * 4;
  float4 x = *(const float4*)(a + base);
  if (BMODE == 2) {
    ushort4 r4 = *(const ushort4*)(b + base);
    x.x += b2f(r4.x); x.y += b2f(r4.y); x.z += b2f(r4.z); x.w += b2f(r4.w);
  }
  float s1 = x.x + x.y + x.z + x.w;
  float s2 = x.x * x.x + x.y * x.y + x.z * x.z + x.w * x.w;
  #pragma unroll
  for (int off = 32; off > 0; off >>= 1) {
    s1 += __shfl_xor(s1, off);
    s2 += __shfl_xor(s2, off);
  }
  __shared__ float sh[8];
  if (lane == 0) { sh[wave * 2] = s1; sh[wave * 2 + 1] = s2; }
  __syncthreads();
  int mate = wave ^ 1;
  s1 += sh[mate * 2];
  s2 += sh[mate * 2 + 1];
  float mu = s1 * (1.0f / 512.0f);
  float var = s2 * (1.0f / 512.0f) - mu * mu;
  float rstd = rsqrtf(var + 1e-5f);
  float4 gg = *(const float4*)(g + t * 4);
  float4 bb = *(const float4*)(be + t * 4);
  float4 o;
  o.x = (x.x - mu) * rstd * gg.x + bb.x;
  o.y = (x.y - mu) * rstd * gg.y + bb.y;
  o.z = (x.z - mu) * rstd * gg.z + bb.z;
  o.w = (x.w - mu) * rstd * gg.w + bb.w;
  *(float4*)(out + base) = o;
  if (OUT == 1) {
    ushort4 ob;
    ob.x = f2b(o.x); ob.y = f2b(o.y); ob.z = f2b(o.z); ob.w = f2b(o.w);
    *(ushort4*)(outb + base) = ob;
  }
  if (OUT == 2) {
    ushort4 hi4, lo4;
    hi4.x = f2b(o.x); lo4.x = f2b(o.x - b2f(hi4.x));
    hi4.y = f2b(o.y); lo4.y = f2b(o.y - b2f(hi4.y));
    hi4.z = f2b(o.z); lo4.z = f2b(o.z - b2f(hi4.z));
    hi4.w = f2b(o.w); lo4.w = f2b(o.w - b2f(hi4.w));
    *(ushort4*)(outh + base) = hi4;
    *(ushort4*)(outl + base) = lo4;
  }
}

// ---------------- head via MFMA: partial[blk*4+w][2688], K-chunk 512/block ----------------
__global__ __launch_bounds__(256) void head_partial_mfma(const unsigned short* __restrict__ hbf,
                                                         const float* __restrict__ Wh,
                                                         float* __restrict__ partial) {
  __shared__ __align__(16) unsigned short Hs[32 * 512];   // 32 KB
  __shared__ __align__(16) unsigned short Ws[96 * 512];   // 96 KB
  int blk = blockIdx.x;            // 0..511
  int k0 = blk * 512;
  int tid = threadIdx.x;
  int wv = tid >> 6, lane = tid & 63;
  int r16 = lane & 15, kq = lane >> 4;

  for (int c = tid; c < 32 * 64; c += 256) {
    int row = c >> 6, col8 = c & 63;
    int src = row < 28 ? row : 0;
    bf16x8 v = *(const bf16x8*)(hbf + (size_t)src * 262144 + k0 + col8 * 8);
    int byte = ((row << 10) | (col8 << 4)) ^ ((row & 7) << 4);
    *(bf16x8*)((char*)Hs + byte) = v;
  }
  for (int c = tid; c < 96 * 64; c += 256) {
    int row = c >> 6, col8 = c & 63;
    const float* src = Wh + (size_t)row * 262144 + k0 + col8 * 8;
    float4 va = *(const float4*)(src);
    float4 vb = *(const float4*)(src + 4);
    bf16x8 o8;
    o8[0] = (short)f2b(va.x); o8[1] = (short)f2b(va.y);
    o8[2] = (short)f2b(va.z); o8[3] = (short)f2b(va.w);
    o8[4] = (short)f2b(vb.x); o8[5] = (short)f2b(vb.y);
    o8[6] = (short)f2b(vb.z); o8[7] = (short)f2b(vb.w);
    int byte = ((row << 10) | (col8 << 4)) ^ ((row & 7) << 4);
    *(bf16x8*)((char*)Ws + byte) = o8;
  }
  __syncthreads();

  f32x4 acc[2][6];
  #pragma unroll
  for (int mt = 0; mt < 2; ++mt)
    #pragma unroll
    for (int nt = 0; nt < 6; ++nt) acc[mt][nt] = (f32x4){0.f, 0.f, 0.f, 0.f};

  #pragma unroll
  for (int kk = 0; kk < 4; ++kk) {
    int kfrag = wv * 4 + kk;     // k = kfrag*32 + kq*8
    bf16x8 afr[2];
    #pragma unroll
    for (int mt = 0; mt < 2; ++mt) {
      int row = mt * 16 + r16;
      int byte = ((row << 10) | (kfrag << 6) | (kq << 4)) ^ ((row & 7) << 4);
      afr[mt] = *(const bf16x8*)((const char*)Hs + byte);
    }
    #pragma unroll
    for (int nt = 0; nt < 6; ++nt) {
      int row = nt * 16 + r16;
      int byte = ((row << 10) | (kfrag << 6) | (kq << 4)) ^ ((row & 7) << 4);
      bf16x8 bfr = *(const bf16x8*)((const char*)Ws + byte);
      #pragma unroll
      for (int mt = 0; mt < 2; ++mt)
        acc[mt][nt] = __builtin_amdgcn_mfma_f32_16x16x32_bf16(afr[mt], bfr, acc[mt][nt], 0, 0, 0);
    }
  }
  size_t prow = (size_t)(blk * 4 + wv) * 2688;
  #pragma unroll
  for (int mt = 0; mt < 2; ++mt)
    #pragma unroll
    for (int nt = 0; nt < 6; ++nt)
      #pragma unroll
      for (int r = 0; r < 4; ++r) {
        int m = mt * 16 + kq * 4 + r;
        int n = nt * 16 + r16;
        if (m < 28) partial[prow + m * 96 + n] = acc[mt][nt][r];
      }
}

__global__ __launch_bounds__(256) void head_reduce(const float* __restrict__ partial,
                                                   const float* __restrict__ bh_,
                                                   float* __restrict__ out) {
  int o = blockIdx.x;              // 0..2687 = m*96+p
  int tid = threadIdx.x;
  float s = 0.f;
  for (int b = tid; b < 2048; b += 256) s += partial[(size_t)b * 2688 + o];
  __shared__ float red[256];
  red[tid] = s;
  __syncthreads();
  for (int st = 128; st > 0; st >>= 1) {
    if (tid < st) red[tid] += red[tid + st];
    __syncthreads();
  }
  if (tid == 0) {
    int m = o / 96, p = o % 96;
    int b = m / NVARS, v = m % NVARS;
    out[(size_t)b * (NPRED * NVARS) + (size_t)p * NVARS + v] = red[0] + bh_[p];
  }
}

extern "C" void kernel_launch(void* const* d_in, const int* in_sizes, int n_in,
                              void* d_out, int out_size, void* d_ws, size_t ws_size,
                              hipStream_t stream) {
  const float* x_enc = (const float*)d_in[0];
  const float* w_emb = (const float*)d_in[1];
  const float* b_emb = (const float*)d_in[2];
  const float* w_pos = (const float*)d_in[3];
  const float* Wq = (const float*)d_in[4];
  const float* bq = (const float*)d_in[5];
  const float* Wk = (const float*)d_in[6];
  const float* bk = (const float*)d_in[7];
  const float* Wv = (const float*)d_in[8];
  const float* bv_ = (const float*)d_in[9];
  const float* Wo = (const float*)d_in[10];
  const float* bo = (const float*)d_in[11];
  const float* W1 = (const float*)d_in[12];
  const float* b1 = (const float*)d_in[13];
  const float* W2 = (const float*)d_in[14];
  const float* b2 = (const float*)d_in[15];
  const float* g1 = (const float*)d_in[16];
  const float* be1 = (const float*)d_in[17];
  const float* g2 = (const float*)d_in[18];
  const float* be2 = (const float*)d_in[19];
  const float* gF = (const float*)d_in[20];
  const float* bF = (const float*)d_in[21];
  const float* Wh = (const float*)d_in[22];
  const float* bh_ = (const float*)d_in[23];
  float* out = (float*)d_out;

  const size_t S = (size_t)SBIG;
  const size_t SB = S * 4;                    // 29,360,128 B
  char* ws = (char*)d_ws;
  float* h    = (float*)(ws);                 // [0, SB)
  float* QKb  = (float*)(ws + SB);            // [SB, 3SB): [14336][1024] fp32
  unsigned short* Vb   = (unsigned short*)(ws + 3 * SB);            // 14.7 MB
  unsigned short* Ob_b = (unsigned short*)(ws + 3 * SB + SB / 2);   // 14.7 MB
  // weight scratch region [4SB, 5SB)
  unsigned short* Wqk_hi = (unsigned short*)(ws + 4 * SB);                  // 1 MB
  unsigned short* Wqk_lo = (unsigned short*)(ws + 4 * SB + 0x100000);       // 1 MB
  unsigned short* Wv_b = (unsigned short*)(ws + 4 * SB + 0x200000);         // 0.5 MB
  unsigned short* Wo_b = (unsigned short*)(ws + 4 * SB + 0x280000);         // 0.5 MB
  unsigned short* W1_b = (unsigned short*)(ws + 4 * SB + 0x300000);         // 2 MB
  unsigned short* W2_b = (unsigned short*)(ws + 4 * SB + 0x500000);         // 2 MB
  unsigned short* h_hi = (unsigned short*)(ws + 5 * SB);           // SB/2
  unsigned short* h_lo = (unsigned short*)(ws + 5 * SB + SB / 2);  // SB/2
  // phase aliases:
  unsigned short* CTXb = h_hi;                 // after QK+V gemms consumed h_hi
  unsigned short* h_bf = h_lo;                 // after QK gemm consumed h_lo
  unsigned short* FFNb = (unsigned short*)QKb; // after attn consumed QK
  float* partial = QKb;                        // head phase (22 MB <= 2SB)
  int*   idx = (int*)(ws + 6 * SB);                        // 70KB
  float* Mv  = (float*)(ws + 6 * SB + 0x20000);            // 448KB
  int*   top = (int*)(ws + 6 * SB + 0xA0000);              // 31KB
  float* vmean = (float*)(ws + 6 * SB + 0xB0000);          // 56KB
  if (ws_size < 6 * SB + 0xC0000) return;

  dim3 b256(256);
  int gVec = (int)(S / 4 / 256);   // 7168

  embed_kernel<<<gVec, b256, 0, stream>>>(x_enc, w_emb, b_emb, w_pos, h, h_hi, h_lo);

  for (int l = 0; l < 2; ++l) {
    const float* Wql = Wq + (size_t)l * DMOD * DMOD;
    const float* Wkl = Wk + (size_t)l * DMOD * DMOD;
    const float* Wvl = Wv + (size_t)l * DMOD * DMOD;
    const float* Wol = Wo + (size_t)l * DMOD * DMOD;
    const float* W1l = W1 + (size_t)l * DFFN * DMOD;
    const float* W2l = W2 + (size_t)l * DMOD * DFFN;

    prep_weights<<<3072, b256, 0, stream>>>(Wql, Wkl, Wvl, Wol, W1l, W2l,
                                            Wqk_hi, Wqk_lo, Wv_b, Wo_b, W1_b, W2_b);

    dim3 gqk(QKS / 128, NROWS / 128);
    gemm_mfma3<<<gqk, b256, 0, stream>>>(h_hi, h_lo, Wqk_hi, Wqk_lo,
                                         bq + l * DMOD, bk + l * DMOD,
                                         QKb, NROWS, QKS, DMOD, QKS);
    dim3 gv(DMOD / 128, NROWS / 128);
    gemm_mfma<0, 1><<<gv, b256, 0, stream>>>(h_hi, Wv_b, bv_ + l * DMOD,
                                             (float*)0, Vb, NROWS, DMOD, DMOD);

    make_idx_kernel<<<(SEQL * NSAMP + 255) / 256, b256, 0, stream>>>(l, idx);
    m2_kernel<<<NBH, dim3(512), 0, stream>>>(QKb, idx, Mv);
    topk_kernel<<<NBH, b256, 0, stream>>>(Mv, top);
    vmean_kernel<<<NBV, b256, 0, stream>>>(Vb, vmean);
    ctx_fill_kernel<<<gVec, b256, 0, stream>>>(vmean, CTXb);
    attn2_kernel<<<NBH, b256, 0, stream>>>(QKb, Vb, top, CTXb);

    dim3 go(DMOD / 128, NROWS / 128);
    gemm_mfma<0, 1><<<go, b256, 0, stream>>>(CTXb, Wo_b, bo + l * DMOD,
                                             (float*)0, Ob_b, NROWS, DMOD, DMOD);
    add_ln<2, 1><<<NROWS / 2, b256, 0, stream>>>(h, Ob_b, g1 + l * DMOD, be1 + l * DMOD,
                                                 h, h_bf, (unsigned short*)0, (unsigned short*)0);

    dim3 gf1(DFFN / 128, NROWS / 128);
    gemm_mfma<1, 1><<<gf1, b256, 0, stream>>>(h_bf, W1_b, b1 + l * DFFN,
                                              (float*)0, FFNb, NROWS, DFFN, DMOD);
    dim3 gf2(DMOD / 128, NROWS / 128);
    gemm_mfma<0, 1><<<gf2, b256, 0, stream>>>(FFNb, W2_b, b2 + l * DMOD,
                                              (float*)0, Ob_b, NROWS, DMOD, DFFN);
    if (l == 0) {
      add_ln<2, 2><<<NROWS / 2, b256, 0, stream>>>(h, Ob_b, g2 + l * DMOD, be2 + l * DMOD,
                                                   h, (unsigned short*)0, h_hi, h_lo);
    } else {
      add_ln<2, 0><<<NROWS / 2, b256, 0, stream>>>(h, Ob_b, g2 + l * DMOD, be2 + l * DMOD,
                                                   h, (unsigned short*)0, (unsigned short*)0, (unsigned short*)0);
    }
  }

  add_ln<0, 1><<<NROWS / 2, b256, 0, stream>>>(h, (const unsigned short*)0, gF, bF,
                                               h, h_bf, (unsigned short*)0, (unsigned short*)0);
  head_partial_mfma<<<512, b256, 0, stream>>>(h_bf, Wh, partial);
  head_reduce<<<NBV * NPRED, b256, 0, stream>>>(partial, bh_, out);
}

// Round 13
// 752.511 us; speedup vs baseline: 1.3558x; 1.0045x over previous
//
#include <hip/hip_runtime.h>
#include <math.h>

#define SEQL 512
#define DMOD 512
#define NHEAD 8
#define DHEAD 64
#define DFFN 2048
#define NBATCH 4
#define NVARS 7
#define NBV 28          // NBATCH*NVARS
#define NBH 224         // NBV*NHEAD
#define NROWS 14336     // NBV*SEQL
#define NSAMP 35        // U_part = u = 35
#define NPRED 96
#define SBIG 7340032    // NBV*SEQL*DMOD floats
#define QKS 1024        // fused QK row stride

typedef short bf16x8 __attribute__((ext_vector_type(8)));
typedef float f32x4 __attribute__((ext_vector_type(4)));

#define GLDS(gptr, lptr) \
  __builtin_amdgcn_global_load_lds((const __attribute__((address_space(1))) void*)(gptr), \
                                   (__attribute__((address_space(3))) void*)(lptr), 16, 0, 0)

__device__ inline unsigned short f2b(float f) {
  unsigned u = __builtin_bit_cast(unsigned, f);
  unsigned r = (u + 0x7FFFu + ((u >> 16) & 1u)) >> 16;
  return (unsigned short)r;
}
__device__ inline float b2f(unsigned short h) {
  return __builtin_bit_cast(float, (unsigned)h << 16);
}

// ---------------- threefry2x32 (matches jax._src.prng) ----------------
__device__ inline void threefry2x32(unsigned k0, unsigned k1,
                                    unsigned x0, unsigned x1,
                                    unsigned &o0, unsigned &o1) {
  unsigned ks2 = k0 ^ k1 ^ 0x1BD11BDAu;
  unsigned ks[3] = {k0, k1, ks2};
  x0 += k0; x1 += k1;
  const unsigned rot[2][4] = {{13u,15u,26u,6u},{17u,29u,16u,24u}};
  #pragma unroll
  for (int i = 0; i < 5; ++i) {
    #pragma unroll
    for (int j = 0; j < 4; ++j) {
      unsigned r = rot[i & 1][j];
      x0 += x1;
      x1 = (x1 << r) | (x1 >> (32u - r));
      x1 ^= x0;
    }
    x0 += ks[(i + 1) % 3];
    x1 += ks[(i + 2) % 3] + (unsigned)(i + 1);
  }
  o0 = x0; o1 = x1;
}

__global__ void make_idx_kernel(int layer, int* idx) {
  int i = blockIdx.x * 256 + threadIdx.x;
  if (i >= SEQL * NSAMP) return;
  unsigned kl0, kl1, o0, o1;
  threefry2x32(0u, 42u, 0u, (unsigned)layer, kl0, kl1);
  threefry2x32(kl0, kl1, (unsigned)i, (unsigned)(SEQL * NSAMP + i), o0, o1);
  idx[i] = (int)(o1 & 511u);
}

// ---------------- embedding (vectorized, fused hi/lo split) ----------------
__global__ void embed_kernel(const float* __restrict__ x_enc,
                             const float* __restrict__ w_emb,
                             const float* __restrict__ b_emb,
                             const float* __restrict__ w_pos,
                             float* __restrict__ h,
                             unsigned short* __restrict__ h_hi,
                             unsigned short* __restrict__ h_lo) {
  size_t i = (size_t)blockIdx.x * 256 + threadIdx.x;
  if (i >= (size_t)(SBIG / 4)) return;
  size_t e = i * 4;
  int dm = (int)(e & 511);
  int l  = (int)((e >> 9) & 511);
  int bv = (int)(e >> 18);
  int b = bv / NVARS, v = bv % NVARS;
  float xs = x_enc[((size_t)b * SEQL + l) * NVARS + v];
  float4 we = *(const float4*)(w_emb + dm);
  float4 bb = *(const float4*)(b_emb + dm);
  float4 wp = *(const float4*)(w_pos + (size_t)l * DMOD + dm);
  float4 val;
  val.x = xs * we.x + bb.x + wp.x;
  val.y = xs * we.y + bb.y + wp.y;
  val.z = xs * we.z + bb.z + wp.z;
  val.w = xs * we.w + bb.w + wp.w;
  *(float4*)(h + e) = val;
  ushort4 hi4, lo4;
  hi4.x = f2b(val.x); lo4.x = f2b(val.x - b2f(hi4.x));
  hi4.y = f2b(val.y); lo4.y = f2b(val.y - b2f(hi4.y));
  hi4.z = f2b(val.z); lo4.z = f2b(val.z - b2f(hi4.z));
  hi4.w = f2b(val.w); lo4.w = f2b(val.w - b2f(hi4.w));
  *(ushort4*)(h_hi + e) = hi4;
  *(ushort4*)(h_lo + e) = lo4;
}

// ---------------- fused per-layer weight prep (one dispatch) ----------------
__global__ void prep_weights(const float* __restrict__ Wq, const float* __restrict__ Wk,
                             const float* __restrict__ Wv, const float* __restrict__ Wo,
                             const float* __restrict__ W1, const float* __restrict__ W2,
                             unsigned short* __restrict__ Wqk_hi, unsigned short* __restrict__ Wqk_lo,
                             unsigned short* __restrict__ Wv_b, unsigned short* __restrict__ Wo_b,
                             unsigned short* __restrict__ W1_b, unsigned short* __restrict__ W2_b) {
  const int Q4 = 65536;   // 262144/4
  int g = blockIdx.x * 256 + threadIdx.x;
  if (g < 2 * Q4) {
    const float* src = g < Q4 ? Wq : Wk;
    unsigned short* hi = Wqk_hi + (g < Q4 ? 0 : DMOD * DMOD);
    unsigned short* lo = Wqk_lo + (g < Q4 ? 0 : DMOD * DMOD);
    int off = (g < Q4 ? g : g - Q4) * 4;
    float4 v = *(const float4*)(src + off);
    ushort4 h4, l4;
    h4.x = f2b(v.x); l4.x = f2b(v.x - b2f(h4.x));
    h4.y = f2b(v.y); l4.y = f2b(v.y - b2f(h4.y));
    h4.z = f2b(v.z); l4.z = f2b(v.z - b2f(h4.z));
    h4.w = f2b(v.w); l4.w = f2b(v.w - b2f(h4.w));
    *(ushort4*)(hi + off) = h4;
    *(ushort4*)(lo + off) = l4;
    return;
  }
  const float* src;
  unsigned short* dst;
  int off;
  if (g < 3 * Q4)      { src = Wv; dst = Wv_b; off = (g - 2 * Q4) * 4; }
  else if (g < 4 * Q4) { src = Wo; dst = Wo_b; off = (g - 3 * Q4) * 4; }
  else if (g < 4 * Q4 + 262144) { src = W1; dst = W1_b; off = (g - 4 * Q4) * 4; }
  else                 { src = W2; dst = W2_b; off = (g - 4 * Q4 - 262144) * 4; }
  float4 v = *(const float4*)(src + off);
  ushort4 o;
  o.x = f2b(v.x); o.y = f2b(v.y); o.z = f2b(v.z); o.w = f2b(v.w);
  *(ushort4*)(dst + off) = o;
}

// ---------------- split-bf16 MFMA GEMM (3-pass hi/lo): C = A@W^T + [bq|bk] ----------------
__global__ __launch_bounds__(256) void gemm_mfma3(const unsigned short* __restrict__ Ah,
                                                  const unsigned short* __restrict__ Al,
                                                  const unsigned short* __restrict__ Bh,
                                                  const unsigned short* __restrict__ Bl,
                                                  const float* __restrict__ bq,
                                                  const float* __restrict__ bk,
                                                  float* __restrict__ C,
                                                  int M, int N, int K, int ldc) {
  __shared__ __align__(16) unsigned short AsH[128 * 64];
  __shared__ __align__(16) unsigned short AsL[128 * 64];
  __shared__ __align__(16) unsigned short BsH[128 * 64];
  __shared__ __align__(16) unsigned short BsL[128 * 64];
  int nwg = gridDim.x * gridDim.y;
  int flat = blockIdx.y * gridDim.x + blockIdx.x;
  int swz = (flat & 7) * (nwg >> 3) + (flat >> 3);
  int bxs = swz % gridDim.x, bys = swz / gridDim.x;
  int bm = bys * 128, bn = bxs * 128;
  int tid = threadIdx.x;
  int wave = tid >> 6, lane = tid & 63;
  int wr = wave >> 1, wc = wave & 1;
  int r16 = lane & 15, kq = lane >> 4;

  f32x4 acc[4][4];
  #pragma unroll
  for (int i = 0; i < 4; ++i)
    #pragma unroll
    for (int j = 0; j < 4; ++j) acc[i][j] = (f32x4){0.f, 0.f, 0.f, 0.f};

  for (int kt = 0; kt < K; kt += 64) {
    __syncthreads();
    #pragma unroll
    for (int i = 0; i < 4; ++i) {
      int c = i * 256 + tid;
      int row = c >> 3, kb = c & 7;
      int kbs = kb ^ (row & 7);             // pre-swizzled source
      size_t offA = (size_t)(bm + row) * K + kt + kbs * 8;
      size_t offB = (size_t)(bn + row) * K + kt + kbs * 8;
      int ldst = (i * 256 + (tid & 192)) << 4;   // wave-uniform linear dest
      GLDS(Ah + offA, (char*)AsH + ldst);
      GLDS(Al + offA, (char*)AsL + ldst);
      GLDS(Bh + offB, (char*)BsH + ldst);
      GLDS(Bl + offB, (char*)BsL + ldst);
    }
    __syncthreads();
    #pragma unroll
    for (int ks = 0; ks < 2; ++ks) {
      bf16x8 ah[4], al[4], bh[4], bl[4];
      #pragma unroll
      for (int mi = 0; mi < 4; ++mi) {
        int row = wr * 64 + mi * 16 + r16;
        int addr = ((row << 7) | (ks << 6) | (kq << 4)) ^ ((row & 7) << 4);
        ah[mi] = *(const bf16x8*)((const char*)AsH + addr);
        al[mi] = *(const bf16x8*)((const char*)AsL + addr);
      }
      #pragma unroll
      for (int ni = 0; ni < 4; ++ni) {
        int row = wc * 64 + ni * 16 + r16;
        int addr = ((row << 7) | (ks << 6) | (kq << 4)) ^ ((row & 7) << 4);
        bh[ni] = *(const bf16x8*)((const char*)BsH + addr);
        bl[ni] = *(const bf16x8*)((const char*)BsL + addr);
      }
      #pragma unroll
      for (int mi = 0; mi < 4; ++mi)
        #pragma unroll
        for (int ni = 0; ni < 4; ++ni) {
          acc[mi][ni] = __builtin_amdgcn_mfma_f32_16x16x32_bf16(ah[mi], bh[ni], acc[mi][ni], 0, 0, 0);
          acc[mi][ni] = __builtin_amdgcn_mfma_f32_16x16x32_bf16(ah[mi], bl[ni], acc[mi][ni], 0, 0, 0);
          acc[mi][ni] = __builtin_amdgcn_mfma_f32_16x16x32_bf16(al[mi], bh[ni], acc[mi][ni], 0, 0, 0);
        }
    }
  }
  int crow0 = bm + wr * 64 + (lane >> 4) * 4;
  int ccol0 = bn + wc * 64 + (lane & 15);
  #pragma unroll
  for (int mi = 0; mi < 4; ++mi) {
    #pragma unroll
    for (int ni = 0; ni < 4; ++ni) {
      int col = ccol0 + ni * 16;
      float bvv = col < 512 ? bq[col] : bk[col - 512];
      #pragma unroll
      for (int r = 0; r < 4; ++r) {
        int row = crow0 + mi * 16 + r;
        C[(size_t)row * ldc + col] = acc[mi][ni][r] + bvv;
      }
    }
  }
}

// ---------------- bf16 MFMA GEMM, 2-phase double-buffered LDS ----------------
template<int ACT, int OUTBF>
__global__ __launch_bounds__(256) void gemm_mfma(const unsigned short* __restrict__ A,
                                                 const unsigned short* __restrict__ W,
                                                 const float* __restrict__ bias,
                                                 float* __restrict__ Cf,
                                                 unsigned short* __restrict__ Cb,
                                                 int M, int N, int K) {
  __shared__ __align__(16) unsigned short As[2][128 * 64];   // 16 KB x2
  __shared__ __align__(16) unsigned short Bs[2][128 * 64];   // 16 KB x2
  int nwg = gridDim.x * gridDim.y;
  int flat = blockIdx.y * gridDim.x + blockIdx.x;
  int swz = (flat & 7) * (nwg >> 3) + (flat >> 3);
  int bxs = swz % gridDim.x, bys = swz / gridDim.x;
  int bm = bys * 128, bn = bxs * 128;
  int tid = threadIdx.x;
  int wave = tid >> 6, lane = tid & 63;
  int wr = wave >> 1, wc = wave & 1;
  int r16 = lane & 15, kq = lane >> 4;

  f32x4 acc[4][4];
  #pragma unroll
  for (int i = 0; i < 4; ++i)
    #pragma unroll
    for (int j = 0; j < 4; ++j) acc[i][j] = (f32x4){0.f, 0.f, 0.f, 0.f};

#define STAGE_MM(buf, ktv) \
  { \
    for (int i_ = 0; i_ < 4; ++i_) { \
      int c_ = i_ * 256 + tid; \
      int row_ = c_ >> 3, kb_ = c_ & 7; \
      int kbs_ = kb_ ^ (row_ & 7); \
      size_t offA_ = (size_t)(bm + row_) * K + (ktv) + kbs_ * 8; \
      size_t offB_ = (size_t)(bn + row_) * K + (ktv) + kbs_ * 8; \
      int ldst_ = (i_ * 256 + (tid & 192)) << 4; \
      GLDS(A + offA_, (char*)As[buf] + ldst_); \
      GLDS(W + offB_, (char*)Bs[buf] + ldst_); \
    } \
  }

  int nkt = K >> 6;
  STAGE_MM(0, 0);
  __syncthreads();                 // compiler drains vmcnt before barrier
  for (int t = 0; t < nkt; ++t) {
    int cur = t & 1;
    if (t + 1 < nkt) STAGE_MM(cur ^ 1, (t + 1) << 6);
    const char* Ab = (const char*)As[cur];
    const char* Bb = (const char*)Bs[cur];
    #pragma unroll
    for (int ks = 0; ks < 2; ++ks) {
      bf16x8 afr[4], bfr[4];
      #pragma unroll
      for (int mi = 0; mi < 4; ++mi) {
        int row = wr * 64 + mi * 16 + r16;
        int addr = ((row << 7) | (ks << 6) | (kq << 4)) ^ ((row & 7) << 4);
        afr[mi] = *(const bf16x8*)(Ab + addr);
      }
      #pragma unroll
      for (int ni = 0; ni < 4; ++ni) {
        int row = wc * 64 + ni * 16 + r16;
        int addr = ((row << 7) | (ks << 6) | (kq << 4)) ^ ((row & 7) << 4);
        bfr[ni] = *(const bf16x8*)(Bb + addr);
      }
      #pragma unroll
      for (int mi = 0; mi < 4; ++mi)
        #pragma unroll
        for (int ni = 0; ni < 4; ++ni)
          acc[mi][ni] = __builtin_amdgcn_mfma_f32_16x16x32_bf16(afr[mi], bfr[ni], acc[mi][ni], 0, 0, 0);
    }
    __syncthreads();               // drains the in-flight next-buf GLDS too
  }
#undef STAGE_MM

  int crow0 = bm + wr * 64 + (lane >> 4) * 4;
  int ccol0 = bn + wc * 64 + (lane & 15);
  #pragma unroll
  for (int mi = 0; mi < 4; ++mi) {
    #pragma unroll
    for (int ni = 0; ni < 4; ++ni) {
      int col = ccol0 + ni * 16;
      float bvv = bias[col];
      #pragma unroll
      for (int r = 0; r < 4; ++r) {
        int row = crow0 + mi * 16 + r;
        float v = acc[mi][ni][r] + bvv;
        if (ACT) {
          // gelu(tanh approx) = x * sigmoid(2*0.79788456(x+0.044715x^3))
          float x = v;
          float u = x * __builtin_fmaf(0.044715f * x, x, 1.0f);
          float tme = __expf(-1.5957691216057308f * u);
          v = x * __builtin_amdgcn_rcpf(1.0f + tme);
        }
        if (OUTBF) Cb[(size_t)row * N + col] = f2b(v);
        else       Cf[(size_t)row * N + col] = v;
      }
    }
  }
}

// ---------------- M measure + top-k fused: block per (bh) ----------------
__global__ __launch_bounds__(512) void m2_topk_kernel(const float* __restrict__ QK,
                                                      const int* __restrict__ idx,
                                                      int* __restrict__ top) {
  int bh = blockIdx.x;
  int bv = bh >> 3, head = bh & 7;
  int tid = threadIdx.x;                 // 0..511, one q-row each
  __shared__ float Ks[512 * 64];         // 128 KB, word(l,db) = l*64 + ((db^(l&15))<<2)
  const float* base = QK + (size_t)bv * (SEQL * QKS);
  for (int c = tid; c < 512 * 16; c += 512) {
    int l = c >> 4, db = c & 15;
    float4 v = *(const float4*)(base + (size_t)l * QKS + 512 + head * 64 + db * 4);
    *(float4*)(Ks + l * 64 + ((db ^ (l & 15)) << 2)) = v;
  }
  float q[64];
  const float* qp = base + (size_t)tid * QKS + head * 64;
  #pragma unroll
  for (int d4 = 0; d4 < 64; d4 += 4) {
    float4 qv = *(const float4*)(qp + d4);
    q[d4 + 0] = qv.x; q[d4 + 1] = qv.y; q[d4 + 2] = qv.z; q[d4 + 3] = qv.w;
  }
  __syncthreads();
  const int* ip = idx + tid * NSAMP;
  float mx = -INFINITY, sm = 0.f;
  for (int u = 0; u < NSAMP; ++u) {
    int kidx = ip[u];
    const float* kr = Ks + kidx * 64;
    int x = kidx & 15;
    float s = 0.f;
    #pragma unroll
    for (int db = 0; db < 16; ++db) {
      float4 kv = *(const float4*)(kr + ((db ^ x) << 2));
      s += q[db * 4 + 0] * kv.x + q[db * 4 + 1] * kv.y
         + q[db * 4 + 2] * kv.z + q[db * 4 + 3] * kv.w;
    }
    mx = fmaxf(mx, s);
    sm += s;
  }
  float Mval = mx - sm * (1.0f / 512.0f);
  __syncthreads();                       // all Ks reads done; reuse LDS
  float* vals = Ks;                      // [512]
  float* rv   = Ks + 512;                // [512]
  int*   ri   = (int*)(Ks + 1024);       // [512]
  vals[tid] = Mval;
  __syncthreads();
  for (int t = 0; t < NSAMP; ++t) {
    rv[tid] = vals[tid];
    ri[tid] = tid;
    __syncthreads();
    for (int s = 256; s > 0; s >>= 1) {
      if (tid < s) {
        float ov = rv[tid + s]; int oi = ri[tid + s];
        if (ov > rv[tid] || (ov == rv[tid] && oi < ri[tid])) { rv[tid] = ov; ri[tid] = oi; }
      }
      __syncthreads();
    }
    if (tid == 0) { top[bh * NSAMP + t] = ri[0]; vals[ri[0]] = -INFINITY; }
    __syncthreads();
  }
}

// ---------------- mean of V partials: block per (bv, rowgroup of 64) ----------------
__global__ __launch_bounds__(256) void vmean_part_kernel(const unsigned short* __restrict__ Vb,
                                                         float* __restrict__ part) {
  int blk = blockIdx.x;                // 0..223 = bv*8+g
  int bv = blk >> 3, grp = blk & 7;
  int t = threadIdx.x;                 // cols 2t, 2t+1
  const unsigned short* vb = Vb + (size_t)bv * (SEQL * DMOD) + (size_t)grp * 64 * DMOD + t * 2;
  float s0 = 0.f, s1 = 0.f;
  #pragma unroll 4
  for (int l = 0; l < 64; ++l) {
    unsigned u = *(const unsigned*)(vb + (size_t)l * DMOD);
    s0 += b2f((unsigned short)(u & 0xffffu));
    s1 += b2f((unsigned short)(u >> 16));
  }
  part[(size_t)blk * DMOD + t * 2]     = s0;
  part[(size_t)blk * DMOD + t * 2 + 1] = s1;
}

// ---------------- ctx = broadcast vmean (sums 8 partials, bf16 out) ----------------
__global__ void ctx_fill_kernel(const float* __restrict__ part,
                                unsigned short* __restrict__ ctxb) {
  size_t i = (size_t)blockIdx.x * 256 + threadIdx.x;
  if (i >= (size_t)(SBIG / 4)) return;
  size_t e = i * 4;
  int dm = (int)(e & 511);
  int bv = (int)(e >> 18);
  float4 vm = {0.f, 0.f, 0.f, 0.f};
  #pragma unroll
  for (int g = 0; g < 8; ++g) {
    float4 p = *(const float4*)(part + (size_t)(bv * 8 + g) * DMOD + dm);
    vm.x += p.x; vm.y += p.y; vm.z += p.z; vm.w += p.w;
  }
  const float inv = 1.0f / 512.0f;
  ushort4 o;
  o.x = f2b(vm.x * inv); o.y = f2b(vm.y * inv);
  o.z = f2b(vm.z * inv); o.w = f2b(vm.w * inv);
  *(ushort4*)(ctxb + e) = o;
}

// ---------------- MFMA attention for selected queries: block per (bh) ----------------
__global__ __launch_bounds__(256) void attn2_kernel(const float* __restrict__ QK,
                                                    const unsigned short* __restrict__ Vb,
                                                    const int* __restrict__ top,
                                                    unsigned short* __restrict__ ctxb) {
  __shared__ __align__(16) unsigned short KV[512 * 64];
  __shared__ __align__(16) unsigned short P[48 * 512];
  __shared__ __align__(16) unsigned short Qs[48 * 64];
  __shared__ int topi[NSAMP];
  int bh = blockIdx.x;
  int bv = bh >> 3, head = bh & 7;
  int tid = threadIdx.x;
  int wv = tid >> 6, lane = tid & 63;
  int r16 = lane & 15, kq = lane >> 4;
  const float* base = QK + (size_t)bv * (SEQL * QKS);
  const unsigned short* vbase = Vb + (size_t)bv * (SEQL * DMOD) + head * 64;

  if (tid < NSAMP) topi[tid] = top[bh * NSAMP + tid];
  __syncthreads();

  for (int c = tid; c < NSAMP * 16; c += 256) {
    int u = c >> 4, dq = c & 15;
    float4 q4 = *(const float4*)(base + (size_t)topi[u] * QKS + head * 64 + dq * 4);
    ushort4 o;
    o.x = f2b(q4.x * 0.125f); o.y = f2b(q4.y * 0.125f);
    o.z = f2b(q4.z * 0.125f); o.w = f2b(q4.w * 0.125f);
    int byte = ((u << 7) | (dq << 3)) ^ ((u & 7) << 4);
    *(ushort4*)((char*)Qs + byte) = o;
  }
  for (int c = tid; c < 512 * 16; c += 256) {
    int l = c >> 4, dq = c & 15;
    float4 k4 = *(const float4*)(base + (size_t)l * QKS + 512 + head * 64 + dq * 4);
    ushort4 o;
    o.x = f2b(k4.x); o.y = f2b(k4.y); o.z = f2b(k4.z); o.w = f2b(k4.w);
    int byte = ((l << 7) | (dq << 3)) ^ ((l & 7) << 4);
    *(ushort4*)((char*)KV + byte) = o;
  }
  __syncthreads();

  // QK^T: scores[48][512]
  {
    f32x4 acc[3][8];
    #pragma unroll
    for (int m = 0; m < 3; ++m)
      #pragma unroll
      for (int j = 0; j < 8; ++j) acc[m][j] = (f32x4){0.f, 0.f, 0.f, 0.f};
    bf16x8 afr[3][2];
    #pragma unroll
    for (int m = 0; m < 3; ++m)
      #pragma unroll
      for (int ks = 0; ks < 2; ++ks) {
        int row = m * 16 + r16;
        int addr = ((row << 7) | (ks << 6) | (kq << 4)) ^ ((row & 7) << 4);
        afr[m][ks] = *(const bf16x8*)((const char*)Qs + addr);
      }
    #pragma unroll
    for (int j = 0; j < 8; ++j) {
      int nrow = (wv * 8 + j) * 16 + r16;
      #pragma unroll
      for (int ks = 0; ks < 2; ++ks) {
        int addr = ((nrow << 7) | (ks << 6) | (kq << 4)) ^ ((nrow & 7) << 4);
        bf16x8 bfr = *(const bf16x8*)((const char*)KV + addr);
        #pragma unroll
        for (int m = 0; m < 3; ++m)
          acc[m][j] = __builtin_amdgcn_mfma_f32_16x16x32_bf16(afr[m][ks], bfr, acc[m][j], 0, 0, 0);
      }
    }
    #pragma unroll
    for (int m = 0; m < 3; ++m)
      #pragma unroll
      for (int j = 0; j < 8; ++j) {
        int l = (wv * 8 + j) * 16 + r16;
        #pragma unroll
        for (int r = 0; r < 4; ++r) {
          int u = m * 16 + kq * 4 + r;
          int byte = ((u << 10) | (l << 1)) ^ ((u & 7) << 4);
          *(unsigned short*)((char*)P + byte) = f2b(acc[m][j][r]);
        }
      }
  }
  __syncthreads();

  // stage V^T into KV region (K dead) from bf16 V
  for (int c = tid; c < 512 * 8; c += 256) {
    int l = c >> 3, dq = c & 7;
    bf16x8 v8 = *(const bf16x8*)(vbase + (size_t)l * DMOD + dq * 8);
    #pragma unroll
    for (int j = 0; j < 8; ++j) {
      int d = dq * 8 + j;
      int byte = ((d << 10) | (l << 1)) ^ ((d & 7) << 4);
      *(unsigned short*)((char*)KV + byte) = (unsigned short)v8[j];
    }
  }
  // softmax on P rows
  for (int u = wv; u < NSAMP; u += 4) {
    int byte = ((u << 10) | (lane << 4)) ^ ((u & 7) << 4);
    bf16x8 sv = *(const bf16x8*)((const char*)P + byte);
    float s[8];
    #pragma unroll
    for (int j = 0; j < 8; ++j) s[j] = b2f((unsigned short)sv[j]);
    float mx = s[0];
    #pragma unroll
    for (int j = 1; j < 8; ++j) mx = fmaxf(mx, s[j]);
    #pragma unroll
    for (int off = 32; off > 0; off >>= 1) mx = fmaxf(mx, __shfl_xor(mx, off));
    float e[8], sm = 0.f;
    #pragma unroll
    for (int j = 0; j < 8; ++j) { e[j] = __expf(s[j] - mx); sm += e[j]; }
    #pragma unroll
    for (int off = 32; off > 0; off >>= 1) sm += __shfl_xor(sm, off);
    float inv = 1.0f / sm;
    bf16x8 pv;
    #pragma unroll
    for (int j = 0; j < 8; ++j) pv[j] = (short)f2b(e[j] * inv);
    *(bf16x8*)((char*)P + byte) = pv;
  }
  __syncthreads();

  // PV: ctx[48][64] = P @ V
  {
    f32x4 acc2[3];
    #pragma unroll
    for (int m = 0; m < 3; ++m) acc2[m] = (f32x4){0.f, 0.f, 0.f, 0.f};
    for (int kst = 0; kst < 16; ++kst) {
      int vrow = wv * 16 + r16;
      int baddr = ((vrow << 10) | (kst << 6) | (kq << 4)) ^ ((vrow & 7) << 4);
      bf16x8 bfr = *(const bf16x8*)((const char*)KV + baddr);
      #pragma unroll
      for (int m = 0; m < 3; ++m) {
        int prow = m * 16 + r16;
        int aaddr = ((prow << 10) | (kst << 6) | (kq << 4)) ^ ((prow & 7) << 4);
        bf16x8 afr2 = *(const bf16x8*)((const char*)P + aaddr);
        acc2[m] = __builtin_amdgcn_mfma_f32_16x16x32_bf16(afr2, bfr, acc2[m], 0, 0, 0);
      }
    }
    int d = wv * 16 + r16;
    #pragma unroll
    for (int m = 0; m < 3; ++m)
      #pragma unroll
      for (int r = 0; r < 4; ++r) {
        int u = m * 16 + kq * 4 + r;
        if (u < NSAMP) {
          size_t off = (size_t)bv * (SEQL * DMOD) + (size_t)topi[u] * DMOD + head * 64 + d;
          ctxb[off] = f2b(acc2[m][r]);
        }
      }
  }
}

// ---------------- residual add + layernorm (vectorized: 2 rows/block) ----------------
template<int BMODE, int OUT>
__global__ __launch_bounds__(256) void add_ln(const float* __restrict__ a,
                                              const unsigned short* __restrict__ b,
                                              const float* __restrict__ g,
                                              const float* __restrict__ be,
                                              float* __restrict__ out,
                                              unsigned short* __restrict__ outb,
                                              unsigned short* __restrict__ outh,
                                              unsigned short* __restrict__ outl) {
  int row = blockIdx.x * 2 + (threadIdx.x >> 7);
  int t = threadIdx.x & 127;
  int wave = threadIdx.x >> 6;
  int lane = threadIdx.x & 63;
  size_t base = (size_t)row * DMOD + t * 4;
  float4 x = *(const float4*)(a + base);
  if (BMODE == 2) {
    ushort4 r4 = *(const ushort4*)(b + base);
    x.x += b2f(r4.x); x.y += b2f(r4.y); x.z += b2f(r4.z); x.w += b2f(r4.w);
  }
  float s1 = x.x + x.y + x.z + x.w;
  float s2 = x.x * x.x + x.y * x.y + x.z * x.z + x.w * x.w;
  #pragma unroll
  for (int off = 32; off > 0; off >>= 1) {
    s1 += __shfl_xor(s1, off);
    s2 += __shfl_xor(s2, off);
  }
  __shared__ float sh[8];
  if (lane == 0) { sh[wave * 2] = s1; sh[wave * 2 + 1] = s2; }
  __syncthreads();
  int mate = wave ^ 1;
  s1 += sh[mate * 2];
  s2 += sh[mate * 2 + 1];
  float mu = s1 * (1.0f / 512.0f);
  float var = s2 * (1.0f / 512.0f) - mu * mu;
  float rstd = rsqrtf(var + 1e-5f);
  float4 gg = *(const float4*)(g + t * 4);
  float4 bb = *(const float4*)(be + t * 4);
  float4 o;
  o.x = (x.x - mu) * rstd * gg.x + bb.x;
  o.y = (x.y - mu) * rstd * gg.y + bb.y;
  o.z = (x.z - mu) * rstd * gg.z + bb.z;
  o.w = (x.w - mu) * rstd * gg.w + bb.w;
  *(float4*)(out + base) = o;
  if (OUT == 1) {
    ushort4 ob;
    ob.x = f2b(o.x); ob.y = f2b(o.y); ob.z = f2b(o.z); ob.w = f2b(o.w);
    *(ushort4*)(outb + base) = ob;
  }
  if (OUT == 2) {
    ushort4 hi4, lo4;
    hi4.x = f2b(o.x); lo4.x = f2b(o.x - b2f(hi4.x));
    hi4.y = f2b(o.y); lo4.y = f2b(o.y - b2f(hi4.y));
    hi4.z = f2b(o.z); lo4.z = f2b(o.z - b2f(hi4.z));
    hi4.w = f2b(o.w); lo4.w = f2b(o.w - b2f(hi4.w));
    *(ushort4*)(outh + base) = hi4;
    *(ushort4*)(outl + base) = lo4;
  }
}

// ---------------- head via MFMA: partial[blk*4+w][2688], K-chunk 512/block ----------------
__global__ __launch_bounds__(256) void head_partial_mfma(const unsigned short* __restrict__ hbf,
                                                         const float* __restrict__ Wh,
                                                         float* __restrict__ partial) {
  __shared__ __align__(16) unsigned short Hs[32 * 512];   // 32 KB
  __shared__ __align__(16) unsigned short Ws[96 * 512];   // 96 KB
  int blk = blockIdx.x;            // 0..511
  int k0 = blk * 512;
  int tid = threadIdx.x;
  int wv = tid >> 6, lane = tid & 63;
  int r16 = lane & 15, kq = lane >> 4;

  for (int c = tid; c < 32 * 64; c += 256) {
    int row = c >> 6, col8 = c & 63;
    int src = row < 28 ? row : 0;
    bf16x8 v = *(const bf16x8*)(hbf + (size_t)src * 262144 + k0 + col8 * 8);
    int byte = ((row << 10) | (col8 << 4)) ^ ((row & 7) << 4);
    *(bf16x8*)((char*)Hs + byte) = v;
  }
  for (int c = tid; c < 96 * 64; c += 256) {
    int row = c >> 6, col8 = c & 63;
    const float* src = Wh + (size_t)row * 262144 + k0 + col8 * 8;
    float4 va = *(const float4*)(src);
    float4 vb = *(const float4*)(src + 4);
    bf16x8 o8;
    o8[0] = (short)f2b(va.x); o8[1] = (short)f2b(va.y);
    o8[2] = (short)f2b(va.z); o8[3] = (short)f2b(va.w);
    o8[4] = (short)f2b(vb.x); o8[5] = (short)f2b(vb.y);
    o8[6] = (short)f2b(vb.z); o8[7] = (short)f2b(vb.w);
    int byte = ((row << 10) | (col8 << 4)) ^ ((row & 7) << 4);
    *(bf16x8*)((char*)Ws + byte) = o8;
  }
  __syncthreads();

  f32x4 acc[2][6];
  #pragma unroll
  for (int mt = 0; mt < 2; ++mt)
    #pragma unroll
    for (int nt = 0; nt < 6; ++nt) acc[mt][nt] = (f32x4){0.f, 0.f, 0.f, 0.f};

  #pragma unroll
  for (int kk = 0; kk < 4; ++kk) {
    int kfrag = wv * 4 + kk;     // k = kfrag*32 + kq*8
    bf16x8 afr[2];
    #pragma unroll
    for (int mt = 0; mt < 2; ++mt) {
      int row = mt * 16 + r16;
      int byte = ((row << 10) | (kfrag << 6) | (kq << 4)) ^ ((row & 7) << 4);
      afr[mt] = *(const bf16x8*)((const char*)Hs + byte);
    }
    #pragma unroll
    for (int nt = 0; nt < 6; ++nt) {
      int row = nt * 16 + r16;
      int byte = ((row << 10) | (kfrag << 6) | (kq << 4)) ^ ((row & 7) << 4);
      bf16x8 bfr = *(const bf16x8*)((const char*)Ws + byte);
      #pragma unroll
      for (int mt = 0; mt < 2; ++mt)
        acc[mt][nt] = __builtin_amdgcn_mfma_f32_16x16x32_bf16(afr[mt], bfr, acc[mt][nt], 0, 0, 0);
    }
  }
  size_t prow = (size_t)(blk * 4 + wv) * 2688;
  #pragma unroll
  for (int mt = 0; mt < 2; ++mt)
    #pragma unroll
    for (int nt = 0; nt < 6; ++nt)
      #pragma unroll
      for (int r = 0; r < 4; ++r) {
        int m = mt * 16 + kq * 4 + r;
        int n = nt * 16 + r16;
        if (m < 28) partial[prow + m * 96 + n] = acc[mt][nt][r];
      }
}

// ---------------- head reduce (coalesced: 32 consecutive columns per 32 lanes) ----------------
__global__ __launch_bounds__(256) void head_reduce(const float* __restrict__ partial,
                                                   const float* __restrict__ bh_,
                                                   float* __restrict__ out) {
  int blk = blockIdx.x;            // 0..83, columns blk*32..blk*32+31
  int o0 = blk * 32;
  int oo = threadIdx.x & 31;
  int rp = threadIdx.x >> 5;       // 0..7
  float s = 0.f;
  for (int r = rp; r < 2048; r += 8)
    s += partial[(size_t)r * 2688 + o0 + oo];
  __shared__ float red[256];
  red[threadIdx.x] = s;
  __syncthreads();
  if (rp == 0) {
    float tot = 0.f;
    #pragma unroll
    for (int k = 0; k < 8; ++k) tot += red[k * 32 + oo];
    int o = o0 + oo;
    int m = o / 96, p = o % 96;
    int b = m / NVARS, v = m % NVARS;
    out[(size_t)b * (NPRED * NVARS) + (size_t)p * NVARS + v] = tot + bh_[p];
  }
}

extern "C" void kernel_launch(void* const* d_in, const int* in_sizes, int n_in,
                              void* d_out, int out_size, void* d_ws, size_t ws_size,
                              hipStream_t stream) {
  const float* x_enc = (const float*)d_in[0];
  const float* w_emb = (const float*)d_in[1];
  const float* b_emb = (const float*)d_in[2];
  const float* w_pos = (const float*)d_in[3];
  const float* Wq = (const float*)d_in[4];
  const float* bq = (const float*)d_in[5];
  const float* Wk = (const float*)d_in[6];
  const float* bk = (const float*)d_in[7];
  const float* Wv = (const float*)d_in[8];
  const float* bv_ = (const float*)d_in[9];
  const float* Wo = (const float*)d_in[10];
  const float* bo = (const float*)d_in[11];
  const float* W1 = (const float*)d_in[12];
  const float* b1 = (const float*)d_in[13];
  const float* W2 = (const float*)d_in[14];
  const float* b2 = (const float*)d_in[15];
  const float* g1 = (const float*)d_in[16];
  const float* be1 = (const float*)d_in[17];
  const float* g2 = (const float*)d_in[18];
  const float* be2 = (const float*)d_in[19];
  const float* gF = (const float*)d_in[20];
  const float* bF = (const float*)d_in[21];
  const float* Wh = (const float*)d_in[22];
  const float* bh_ = (const float*)d_in[23];
  float* out = (float*)d_out;

  const size_t S = (size_t)SBIG;
  const size_t SB = S * 4;                    // 29,360,128 B
  char* ws = (char*)d_ws;
  float* h    = (float*)(ws);                 // [0, SB)
  float* QKb  = (float*)(ws + SB);            // [SB, 3SB): [14336][1024] fp32
  unsigned short* Vb   = (unsigned short*)(ws + 3 * SB);            // 14.7 MB
  unsigned short* Ob_b = (unsigned short*)(ws + 3 * SB + SB / 2);   // 14.7 MB
  // weight scratch region [4SB, 5SB)
  unsigned short* Wqk_hi = (unsigned short*)(ws + 4 * SB);                  // 1 MB
  unsigned short* Wqk_lo = (unsigned short*)(ws + 4 * SB + 0x100000);       // 1 MB
  unsigned short* Wv_b = (unsigned short*)(ws + 4 * SB + 0x200000);         // 0.5 MB
  unsigned short* Wo_b = (unsigned short*)(ws + 4 * SB + 0x280000);         // 0.5 MB
  unsigned short* W1_b = (unsigned short*)(ws + 4 * SB + 0x300000);         // 2 MB
  unsigned short* W2_b = (unsigned short*)(ws + 4 * SB + 0x500000);         // 2 MB
  unsigned short* h_hi = (unsigned short*)(ws + 5 * SB);           // SB/2
  unsigned short* h_lo = (unsigned short*)(ws + 5 * SB + SB / 2);  // SB/2
  // phase aliases:
  unsigned short* CTXb = h_hi;                 // after QK+V gemms consumed h_hi
  unsigned short* h_bf = h_lo;                 // after QK gemm consumed h_lo
  unsigned short* FFNb = (unsigned short*)QKb; // after attn consumed QK
  float* partial = QKb;                        // head phase (22 MB <= 2SB)
  int*   idx = (int*)(ws + 6 * SB);                        // 70KB
  float* vpart = (float*)(ws + 6 * SB + 0x20000);          // 448KB (224*512 f)
  int*   top = (int*)(ws + 6 * SB + 0xA0000);              // 31KB
  if (ws_size < 6 * SB + 0xC0000) return;

  dim3 b256(256);
  int gVec = (int)(S / 4 / 256);   // 7168

  embed_kernel<<<gVec, b256, 0, stream>>>(x_enc, w_emb, b_emb, w_pos, h, h_hi, h_lo);

  for (int l = 0; l < 2; ++l) {
    const float* Wql = Wq + (size_t)l * DMOD * DMOD;
    const float* Wkl = Wk + (size_t)l * DMOD * DMOD;
    const float* Wvl = Wv + (size_t)l * DMOD * DMOD;
    const float* Wol = Wo + (size_t)l * DMOD * DMOD;
    const float* W1l = W1 + (size_t)l * DFFN * DMOD;
    const float* W2l = W2 + (size_t)l * DMOD * DFFN;

    prep_weights<<<3072, b256, 0, stream>>>(Wql, Wkl, Wvl, Wol, W1l, W2l,
                                            Wqk_hi, Wqk_lo, Wv_b, Wo_b, W1_b, W2_b);

    dim3 gqk(QKS / 128, NROWS / 128);
    gemm_mfma3<<<gqk, b256, 0, stream>>>(h_hi, h_lo, Wqk_hi, Wqk_lo,
                                         bq + l * DMOD, bk + l * DMOD,
                                         QKb, NROWS, QKS, DMOD, QKS);
    dim3 gv(DMOD / 128, NROWS / 128);
    gemm_mfma<0, 1><<<gv, b256, 0, stream>>>(h_hi, Wv_b, bv_ + l * DMOD,
                                             (float*)0, Vb, NROWS, DMOD, DMOD);

    make_idx_kernel<<<(SEQL * NSAMP + 255) / 256, b256, 0, stream>>>(l, idx);
    m2_topk_kernel<<<NBH, dim3(512), 0, stream>>>(QKb, idx, top);
    vmean_part_kernel<<<NBV * 8, b256, 0, stream>>>(Vb, vpart);
    ctx_fill_kernel<<<gVec, b256, 0, stream>>>(vpart, CTXb);
    attn2_kernel<<<NBH, b256, 0, stream>>>(QKb, Vb, top, CTXb);

    dim3 go(DMOD / 128, NROWS / 128);
    gemm_mfma<0, 1><<<go, b256, 0, stream>>>(CTXb, Wo_b, bo + l * DMOD,
                                             (float*)0, Ob_b, NROWS, DMOD, DMOD);
    add_ln<2, 1><<<NROWS / 2, b256, 0, stream>>>(h, Ob_b, g1 + l * DMOD, be1 + l * DMOD,
                                                 h, h_bf, (unsigned short*)0, (unsigned short*)0);

    dim3 gf1(DFFN / 128, NROWS / 128);
    gemm_mfma<1, 1><<<gf1, b256, 0, stream>>>(h_bf, W1_b, b1 + l * DFFN,
                                              (float*)0, FFNb, NROWS, DFFN, DMOD);
    dim3 gf2(DMOD / 128, NROWS / 128);
    gemm_mfma<0, 1><<<gf2, b256, 0, stream>>>(FFNb, W2_b, b2 + l * DMOD,
                                              (float*)0, Ob_b, NROWS, DMOD, DFFN);
    if (l == 0) {
      add_ln<2, 2><<<NROWS / 2, b256, 0, stream>>>(h, Ob_b, g2 + l * DMOD, be2 + l * DMOD,
                                                   h, (unsigned short*)0, h_hi, h_lo);
    } else {
      add_ln<2, 0><<<NROWS / 2, b256, 0, stream>>>(h, Ob_b, g2 + l * DMOD, be2 + l * DMOD,
                                                   h, (unsigned short*)0, (unsigned short*)0, (unsigned short*)0);
    }
  }

  add_ln<0, 1><<<NROWS / 2, b256, 0, stream>>>(h, (const unsigned short*)0, gF, bF,
                                               h, h_bf, (unsigned short*)0, (unsigned short*)0);
  head_partial_mfma<<<512, b256, 0, stream>>>(h_bf, Wh, partial);
  head_reduce<<<84, b256, 0, stream>>>(partial, bh_, out);
}

// Round 14
// 731.843 us; speedup vs baseline: 1.3941x; 1.0282x over previous
//
#include <hip/hip_runtime.h>
#include <math.h>

#define SEQL 512
#define DMOD 512
#define NHEAD 8
#define DHEAD 64
#define DFFN 2048
#define NBATCH 4
#define NVARS 7
#define NBV 28          // NBATCH*NVARS
#define NBH 224         // NBV*NHEAD
#define NROWS 14336     // NBV*SEQL
#define NSAMP 35        // U_part = u = 35
#define NPRED 96
#define SBIG 7340032    // NBV*SEQL*DMOD floats
#define QKS 1024        // fused QK row stride

typedef short bf16x8 __attribute__((ext_vector_type(8)));
typedef float f32x4 __attribute__((ext_vector_type(4)));

#define GLDS(gptr, lptr) \
  __builtin_amdgcn_global_load_lds((const __attribute__((address_space(1))) void*)(gptr), \
                                   (__attribute__((address_space(3))) void*)(lptr), 16, 0, 0)

__device__ inline unsigned short f2b(float f) {
  unsigned u = __builtin_bit_cast(unsigned, f);
  unsigned r = (u + 0x7FFFu + ((u >> 16) & 1u)) >> 16;
  return (unsigned short)r;
}
__device__ inline float b2f(unsigned short h) {
  return __builtin_bit_cast(float, (unsigned)h << 16);
}

// ---------------- threefry2x32 (matches jax._src.prng) ----------------
__device__ inline void threefry2x32(unsigned k0, unsigned k1,
                                    unsigned x0, unsigned x1,
                                    unsigned &o0, unsigned &o1) {
  unsigned ks2 = k0 ^ k1 ^ 0x1BD11BDAu;
  unsigned ks[3] = {k0, k1, ks2};
  x0 += k0; x1 += k1;
  const unsigned rot[2][4] = {{13u,15u,26u,6u},{17u,29u,16u,24u}};
  #pragma unroll
  for (int i = 0; i < 5; ++i) {
    #pragma unroll
    for (int j = 0; j < 4; ++j) {
      unsigned r = rot[i & 1][j];
      x0 += x1;
      x1 = (x1 << r) | (x1 >> (32u - r));
      x1 ^= x0;
    }
    x0 += ks[(i + 1) % 3];
    x1 += ks[(i + 2) % 3] + (unsigned)(i + 1);
  }
  o0 = x0; o1 = x1;
}

// writes TRANSPOSED layout idx_t[u*512 + q]
__global__ void make_idx_kernel(int layer, int* idx_t) {
  int i = blockIdx.x * 256 + threadIdx.x;
  if (i >= SEQL * NSAMP) return;
  unsigned kl0, kl1, o0, o1;
  threefry2x32(0u, 42u, 0u, (unsigned)layer, kl0, kl1);
  threefry2x32(kl0, kl1, (unsigned)i, (unsigned)(SEQL * NSAMP + i), o0, o1);
  int q = i / NSAMP, u = i % NSAMP;
  idx_t[u * SEQL + q] = (int)(o1 & 511u);
}

// ---------------- embedding (vectorized, fused hi/lo split) ----------------
__global__ void embed_kernel(const float* __restrict__ x_enc,
                             const float* __restrict__ w_emb,
                             const float* __restrict__ b_emb,
                             const float* __restrict__ w_pos,
                             float* __restrict__ h,
                             unsigned short* __restrict__ h_hi,
                             unsigned short* __restrict__ h_lo) {
  size_t i = (size_t)blockIdx.x * 256 + threadIdx.x;
  if (i >= (size_t)(SBIG / 4)) return;
  size_t e = i * 4;
  int dm = (int)(e & 511);
  int l  = (int)((e >> 9) & 511);
  int bv = (int)(e >> 18);
  int b = bv / NVARS, v = bv % NVARS;
  float xs = x_enc[((size_t)b * SEQL + l) * NVARS + v];
  float4 we = *(const float4*)(w_emb + dm);
  float4 bb = *(const float4*)(b_emb + dm);
  float4 wp = *(const float4*)(w_pos + (size_t)l * DMOD + dm);
  float4 val;
  val.x = xs * we.x + bb.x + wp.x;
  val.y = xs * we.y + bb.y + wp.y;
  val.z = xs * we.z + bb.z + wp.z;
  val.w = xs * we.w + bb.w + wp.w;
  *(float4*)(h + e) = val;
  ushort4 hi4, lo4;
  hi4.x = f2b(val.x); lo4.x = f2b(val.x - b2f(hi4.x));
  hi4.y = f2b(val.y); lo4.y = f2b(val.y - b2f(hi4.y));
  hi4.z = f2b(val.z); lo4.z = f2b(val.z - b2f(hi4.z));
  hi4.w = f2b(val.w); lo4.w = f2b(val.w - b2f(hi4.w));
  *(ushort4*)(h_hi + e) = hi4;
  *(ushort4*)(h_lo + e) = lo4;
}

// ---------------- fused per-layer weight prep (one dispatch) ----------------
__global__ void prep_weights(const float* __restrict__ Wq, const float* __restrict__ Wk,
                             const float* __restrict__ Wv, const float* __restrict__ Wo,
                             const float* __restrict__ W1, const float* __restrict__ W2,
                             unsigned short* __restrict__ Wqk_hi, unsigned short* __restrict__ Wqk_lo,
                             unsigned short* __restrict__ Wv_b, unsigned short* __restrict__ Wo_b,
                             unsigned short* __restrict__ W1_b, unsigned short* __restrict__ W2_b) {
  const int Q4 = 65536;   // 262144/4
  int g = blockIdx.x * 256 + threadIdx.x;
  if (g < 2 * Q4) {
    const float* src = g < Q4 ? Wq : Wk;
    unsigned short* hi = Wqk_hi + (g < Q4 ? 0 : DMOD * DMOD);
    unsigned short* lo = Wqk_lo + (g < Q4 ? 0 : DMOD * DMOD);
    int off = (g < Q4 ? g : g - Q4) * 4;
    float4 v = *(const float4*)(src + off);
    ushort4 h4, l4;
    h4.x = f2b(v.x); l4.x = f2b(v.x - b2f(h4.x));
    h4.y = f2b(v.y); l4.y = f2b(v.y - b2f(h4.y));
    h4.z = f2b(v.z); l4.z = f2b(v.z - b2f(h4.z));
    h4.w = f2b(v.w); l4.w = f2b(v.w - b2f(h4.w));
    *(ushort4*)(hi + off) = h4;
    *(ushort4*)(lo + off) = l4;
    return;
  }
  const float* src;
  unsigned short* dst;
  int off;
  if (g < 3 * Q4)      { src = Wv; dst = Wv_b; off = (g - 2 * Q4) * 4; }
  else if (g < 4 * Q4) { src = Wo; dst = Wo_b; off = (g - 3 * Q4) * 4; }
  else if (g < 4 * Q4 + 262144) { src = W1; dst = W1_b; off = (g - 4 * Q4) * 4; }
  else                 { src = W2; dst = W2_b; off = (g - 4 * Q4 - 262144) * 4; }
  float4 v = *(const float4*)(src + off);
  ushort4 o;
  o.x = f2b(v.x); o.y = f2b(v.y); o.z = f2b(v.z); o.w = f2b(v.w);
  *(ushort4*)(dst + off) = o;
}

// ---------------- split-bf16 MFMA GEMM (3-pass hi/lo): C = A@W^T + [bq|bk] ----------------
__global__ __launch_bounds__(256) void gemm_mfma3(const unsigned short* __restrict__ Ah,
                                                  const unsigned short* __restrict__ Al,
                                                  const unsigned short* __restrict__ Bh,
                                                  const unsigned short* __restrict__ Bl,
                                                  const float* __restrict__ bq,
                                                  const float* __restrict__ bk,
                                                  float* __restrict__ C,
                                                  int M, int N, int K, int ldc) {
  __shared__ __align__(16) unsigned short AsH[128 * 64];
  __shared__ __align__(16) unsigned short AsL[128 * 64];
  __shared__ __align__(16) unsigned short BsH[128 * 64];
  __shared__ __align__(16) unsigned short BsL[128 * 64];
  int nwg = gridDim.x * gridDim.y;
  int flat = blockIdx.y * gridDim.x + blockIdx.x;
  int swz = (flat & 7) * (nwg >> 3) + (flat >> 3);
  int bxs = swz % gridDim.x, bys = swz / gridDim.x;
  int bm = bys * 128, bn = bxs * 128;
  int tid = threadIdx.x;
  int wave = tid >> 6, lane = tid & 63;
  int wr = wave >> 1, wc = wave & 1;
  int r16 = lane & 15, kq = lane >> 4;

  f32x4 acc[4][4];
  #pragma unroll
  for (int i = 0; i < 4; ++i)
    #pragma unroll
    for (int j = 0; j < 4; ++j) acc[i][j] = (f32x4){0.f, 0.f, 0.f, 0.f};

  for (int kt = 0; kt < K; kt += 64) {
    __syncthreads();
    #pragma unroll
    for (int i = 0; i < 4; ++i) {
      int c = i * 256 + tid;
      int row = c >> 3, kb = c & 7;
      int kbs = kb ^ (row & 7);             // pre-swizzled source
      size_t offA = (size_t)(bm + row) * K + kt + kbs * 8;
      size_t offB = (size_t)(bn + row) * K + kt + kbs * 8;
      int ldst = (i * 256 + (tid & 192)) << 4;   // wave-uniform linear dest
      GLDS(Ah + offA, (char*)AsH + ldst);
      GLDS(Al + offA, (char*)AsL + ldst);
      GLDS(Bh + offB, (char*)BsH + ldst);
      GLDS(Bl + offB, (char*)BsL + ldst);
    }
    __syncthreads();
    #pragma unroll
    for (int ks = 0; ks < 2; ++ks) {
      bf16x8 ah[4], al[4], bh[4], bl[4];
      #pragma unroll
      for (int mi = 0; mi < 4; ++mi) {
        int row = wr * 64 + mi * 16 + r16;
        int addr = ((row << 7) | (ks << 6) | (kq << 4)) ^ ((row & 7) << 4);
        ah[mi] = *(const bf16x8*)((const char*)AsH + addr);
        al[mi] = *(const bf16x8*)((const char*)AsL + addr);
      }
      #pragma unroll
      for (int ni = 0; ni < 4; ++ni) {
        int row = wc * 64 + ni * 16 + r16;
        int addr = ((row << 7) | (ks << 6) | (kq << 4)) ^ ((row & 7) << 4);
        bh[ni] = *(const bf16x8*)((const char*)BsH + addr);
        bl[ni] = *(const bf16x8*)((const char*)BsL + addr);
      }
      #pragma unroll
      for (int mi = 0; mi < 4; ++mi)
        #pragma unroll
        for (int ni = 0; ni < 4; ++ni) {
          acc[mi][ni] = __builtin_amdgcn_mfma_f32_16x16x32_bf16(ah[mi], bh[ni], acc[mi][ni], 0, 0, 0);
          acc[mi][ni] = __builtin_amdgcn_mfma_f32_16x16x32_bf16(ah[mi], bl[ni], acc[mi][ni], 0, 0, 0);
          acc[mi][ni] = __builtin_amdgcn_mfma_f32_16x16x32_bf16(al[mi], bh[ni], acc[mi][ni], 0, 0, 0);
        }
    }
  }
  int crow0 = bm + wr * 64 + (lane >> 4) * 4;
  int ccol0 = bn + wc * 64 + (lane & 15);
  #pragma unroll
  for (int mi = 0; mi < 4; ++mi) {
    #pragma unroll
    for (int ni = 0; ni < 4; ++ni) {
      int col = ccol0 + ni * 16;
      float bvv = col < 512 ? bq[col] : bk[col - 512];
      #pragma unroll
      for (int r = 0; r < 4; ++r) {
        int row = crow0 + mi * 16 + r;
        C[(size_t)row * ldc + col] = acc[mi][ni][r] + bvv;
      }
    }
  }
}

// ---------------- bf16 MFMA GEMM, 2-phase double-buffered LDS ----------------
template<int ACT, int OUTBF>
__global__ __launch_bounds__(256) void gemm_mfma(const unsigned short* __restrict__ A,
                                                 const unsigned short* __restrict__ W,
                                                 const float* __restrict__ bias,
                                                 float* __restrict__ Cf,
                                                 unsigned short* __restrict__ Cb,
                                                 int M, int N, int K) {
  __shared__ __align__(16) unsigned short As[2][128 * 64];   // 16 KB x2
  __shared__ __align__(16) unsigned short Bs[2][128 * 64];   // 16 KB x2
  int nwg = gridDim.x * gridDim.y;
  int flat = blockIdx.y * gridDim.x + blockIdx.x;
  int swz = (flat & 7) * (nwg >> 3) + (flat >> 3);
  int bxs = swz % gridDim.x, bys = swz / gridDim.x;
  int bm = bys * 128, bn = bxs * 128;
  int tid = threadIdx.x;
  int wave = tid >> 6, lane = tid & 63;
  int wr = wave >> 1, wc = wave & 1;
  int r16 = lane & 15, kq = lane >> 4;

  f32x4 acc[4][4];
  #pragma unroll
  for (int i = 0; i < 4; ++i)
    #pragma unroll
    for (int j = 0; j < 4; ++j) acc[i][j] = (f32x4){0.f, 0.f, 0.f, 0.f};

#define STAGE_MM(buf, ktv) \
  { \
    for (int i_ = 0; i_ < 4; ++i_) { \
      int c_ = i_ * 256 + tid; \
      int row_ = c_ >> 3, kb_ = c_ & 7; \
      int kbs_ = kb_ ^ (row_ & 7); \
      size_t offA_ = (size_t)(bm + row_) * K + (ktv) + kbs_ * 8; \
      size_t offB_ = (size_t)(bn + row_) * K + (ktv) + kbs_ * 8; \
      int ldst_ = (i_ * 256 + (tid & 192)) << 4; \
      GLDS(A + offA_, (char*)As[buf] + ldst_); \
      GLDS(W + offB_, (char*)Bs[buf] + ldst_); \
    } \
  }

  int nkt = K >> 6;
  STAGE_MM(0, 0);
  __syncthreads();                 // compiler drains vmcnt before barrier
  for (int t = 0; t < nkt; ++t) {
    int cur = t & 1;
    if (t + 1 < nkt) STAGE_MM(cur ^ 1, (t + 1) << 6);
    const char* Ab = (const char*)As[cur];
    const char* Bb = (const char*)Bs[cur];
    #pragma unroll
    for (int ks = 0; ks < 2; ++ks) {
      bf16x8 afr[4], bfr[4];
      #pragma unroll
      for (int mi = 0; mi < 4; ++mi) {
        int row = wr * 64 + mi * 16 + r16;
        int addr = ((row << 7) | (ks << 6) | (kq << 4)) ^ ((row & 7) << 4);
        afr[mi] = *(const bf16x8*)(Ab + addr);
      }
      #pragma unroll
      for (int ni = 0; ni < 4; ++ni) {
        int row = wc * 64 + ni * 16 + r16;
        int addr = ((row << 7) | (ks << 6) | (kq << 4)) ^ ((row & 7) << 4);
        bfr[ni] = *(const bf16x8*)(Bb + addr);
      }
      #pragma unroll
      for (int mi = 0; mi < 4; ++mi)
        #pragma unroll
        for (int ni = 0; ni < 4; ++ni)
          acc[mi][ni] = __builtin_amdgcn_mfma_f32_16x16x32_bf16(afr[mi], bfr[ni], acc[mi][ni], 0, 0, 0);
    }
    __syncthreads();               // drains the in-flight next-buf GLDS too
  }
#undef STAGE_MM

  int crow0 = bm + wr * 64 + (lane >> 4) * 4;
  int ccol0 = bn + wc * 64 + (lane & 15);
  #pragma unroll
  for (int mi = 0; mi < 4; ++mi) {
    #pragma unroll
    for (int ni = 0; ni < 4; ++ni) {
      int col = ccol0 + ni * 16;
      float bvv = bias[col];
      #pragma unroll
      for (int r = 0; r < 4; ++r) {
        int row = crow0 + mi * 16 + r;
        float v = acc[mi][ni][r] + bvv;
        if (ACT) {
          // gelu(tanh approx) = x * sigmoid(2*0.79788456(x+0.044715x^3))
          float x = v;
          float u = x * __builtin_fmaf(0.044715f * x, x, 1.0f);
          float tme = __expf(-1.5957691216057308f * u);
          v = x * __builtin_amdgcn_rcpf(1.0f + tme);
        }
        if (OUTBF) Cb[(size_t)row * N + col] = f2b(v);
        else       Cf[(size_t)row * N + col] = v;
      }
    }
  }
}

// ---------------- M measure + wave-parallel top-k fused: block per (bh) ----------------
__global__ __launch_bounds__(512) void m2_topk_kernel(const float* __restrict__ QK,
                                                      const int* __restrict__ idx_t,
                                                      int* __restrict__ top) {
  int bh = blockIdx.x;
  int bv = bh >> 3, head = bh & 7;
  int tid = threadIdx.x;                 // 0..511, one q-row each
  int lane = tid & 63, wv8 = tid >> 6;
  __shared__ float Ks[512 * 64];         // 128 KB, word(l,db) = l*64 + ((db^(l&15))<<2)
  const float* base = QK + (size_t)bv * (SEQL * QKS);
  for (int c = tid; c < 512 * 16; c += 512) {
    int l = c >> 4, db = c & 15;
    float4 v = *(const float4*)(base + (size_t)l * QKS + 512 + head * 64 + db * 4);
    *(float4*)(Ks + l * 64 + ((db ^ (l & 15)) << 2)) = v;
  }
  float q[64];
  const float* qp = base + (size_t)tid * QKS + head * 64;
  #pragma unroll
  for (int d4 = 0; d4 < 64; d4 += 4) {
    float4 qv = *(const float4*)(qp + d4);
    q[d4 + 0] = qv.x; q[d4 + 1] = qv.y; q[d4 + 2] = qv.z; q[d4 + 3] = qv.w;
  }
  __syncthreads();
  float mx = -INFINITY, sm = 0.f;
  for (int u = 0; u < NSAMP; ++u) {
    int kidx = idx_t[u * SEQL + tid];   // coalesced
    const float* kr = Ks + kidx * 64;
    int x = kidx & 15;
    float s = 0.f;
    #pragma unroll
    for (int db = 0; db < 16; ++db) {
      float4 kv = *(const float4*)(kr + ((db ^ x) << 2));
      s += q[db * 4 + 0] * kv.x + q[db * 4 + 1] * kv.y
         + q[db * 4 + 2] * kv.z + q[db * 4 + 3] * kv.w;
    }
    mx = fmaxf(mx, s);
    sm += s;
  }
  float Mval = mx - sm * (1.0f / 512.0f);
  __syncthreads();                       // all Ks reads done; reuse LDS
  float* vals = Ks;                      // [512]
  float* wred = Ks + 512;                // [8]
  int*   widx = (int*)(Ks + 520);        // [8]
  vals[tid] = Mval;
  __syncthreads();
  for (int t = 0; t < NSAMP; ++t) {
    float v = vals[tid];
    int ii = tid;
    #pragma unroll
    for (int off = 32; off > 0; off >>= 1) {
      float ov = __shfl_xor(v, off);
      int oi = __shfl_xor(ii, off);
      if (ov > v || (ov == v && oi < ii)) { v = ov; ii = oi; }
    }
    if (lane == 0) { wred[wv8] = v; widx[wv8] = ii; }
    __syncthreads();
    if (tid == 0) {
      float bvv = wred[0]; int bi = widx[0];
      #pragma unroll
      for (int w = 1; w < 8; ++w)
        if (wred[w] > bvv) { bvv = wred[w]; bi = widx[w]; }
      top[bh * NSAMP + t] = bi;
      vals[bi] = -INFINITY;
    }
    __syncthreads();
  }
}

// ---------------- mean of V partials: block per (bv, rowgroup of 64) ----------------
__global__ __launch_bounds__(256) void vmean_part_kernel(const unsigned short* __restrict__ Vb,
                                                         float* __restrict__ part) {
  int blk = blockIdx.x;                // 0..223 = bv*8+g
  int bv = blk >> 3, grp = blk & 7;
  int t = threadIdx.x;                 // cols 2t, 2t+1
  const unsigned short* vb = Vb + (size_t)bv * (SEQL * DMOD) + (size_t)grp * 64 * DMOD + t * 2;
  float s0 = 0.f, s1 = 0.f;
  #pragma unroll 4
  for (int l = 0; l < 64; ++l) {
    unsigned u = *(const unsigned*)(vb + (size_t)l * DMOD);
    s0 += b2f((unsigned short)(u & 0xffffu));
    s1 += b2f((unsigned short)(u >> 16));
  }
  part[(size_t)blk * DMOD + t * 2]     = s0;
  part[(size_t)blk * DMOD + t * 2 + 1] = s1;
}

// ---------------- ctx = broadcast vmean (sums 8 partials, bf16 out) ----------------
__global__ void ctx_fill_kernel(const float* __restrict__ part,
                                unsigned short* __restrict__ ctxb) {
  size_t i = (size_t)blockIdx.x * 256 + threadIdx.x;
  if (i >= (size_t)(SBIG / 4)) return;
  size_t e = i * 4;
  int dm = (int)(e & 511);
  int bv = (int)(e >> 18);
  float4 vm = {0.f, 0.f, 0.f, 0.f};
  #pragma unroll
  for (int g = 0; g < 8; ++g) {
    float4 p = *(const float4*)(part + (size_t)(bv * 8 + g) * DMOD + dm);
    vm.x += p.x; vm.y += p.y; vm.z += p.z; vm.w += p.w;
  }
  const float inv = 1.0f / 512.0f;
  ushort4 o;
  o.x = f2b(vm.x * inv); o.y = f2b(vm.y * inv);
  o.z = f2b(vm.z * inv); o.w = f2b(vm.w * inv);
  *(ushort4*)(ctxb + e) = o;
}

// ---------------- MFMA attention for selected queries: block per (bh) ----------------
__global__ __launch_bounds__(256) void attn2_kernel(const float* __restrict__ QK,
                                                    const unsigned short* __restrict__ Vb,
                                                    const int* __restrict__ top,
                                                    unsigned short* __restrict__ ctxb) {
  __shared__ __align__(16) unsigned short KV[512 * 64];
  __shared__ __align__(16) unsigned short P[48 * 512];
  __shared__ __align__(16) unsigned short Qs[48 * 64];
  __shared__ int topi[NSAMP];
  int bh = blockIdx.x;
  int bv = bh >> 3, head = bh & 7;
  int tid = threadIdx.x;
  int wv = tid >> 6, lane = tid & 63;
  int r16 = lane & 15, kq = lane >> 4;
  const float* base = QK + (size_t)bv * (SEQL * QKS);
  const unsigned short* vbase = Vb + (size_t)bv * (SEQL * DMOD) + head * 64;

  if (tid < NSAMP) topi[tid] = top[bh * NSAMP + tid];
  __syncthreads();

  for (int c = tid; c < NSAMP * 16; c += 256) {
    int u = c >> 4, dq = c & 15;
    float4 q4 = *(const float4*)(base + (size_t)topi[u] * QKS + head * 64 + dq * 4);
    ushort4 o;
    o.x = f2b(q4.x * 0.125f); o.y = f2b(q4.y * 0.125f);
    o.z = f2b(q4.z * 0.125f); o.w = f2b(q4.w * 0.125f);
    int byte = ((u << 7) | (dq << 3)) ^ ((u & 7) << 4);
    *(ushort4*)((char*)Qs + byte) = o;
  }
  for (int c = tid; c < 512 * 16; c += 256) {
    int l = c >> 4, dq = c & 15;
    float4 k4 = *(const float4*)(base + (size_t)l * QKS + 512 + head * 64 + dq * 4);
    ushort4 o;
    o.x = f2b(k4.x); o.y = f2b(k4.y); o.z = f2b(k4.z); o.w = f2b(k4.w);
    int byte = ((l << 7) | (dq << 3)) ^ ((l & 7) << 4);
    *(ushort4*)((char*)KV + byte) = o;
  }
  __syncthreads();

  // QK^T: scores[48][512]
  {
    f32x4 acc[3][8];
    #pragma unroll
    for (int m = 0; m < 3; ++m)
      #pragma unroll
      for (int j = 0; j < 8; ++j) acc[m][j] = (f32x4){0.f, 0.f, 0.f, 0.f};
    bf16x8 afr[3][2];
    #pragma unroll
    for (int m = 0; m < 3; ++m)
      #pragma unroll
      for (int ks = 0; ks < 2; ++ks) {
        int row = m * 16 + r16;
        int addr = ((row << 7) | (ks << 6) | (kq << 4)) ^ ((row & 7) << 4);
        afr[m][ks] = *(const bf16x8*)((const char*)Qs + addr);
      }
    #pragma unroll
    for (int j = 0; j < 8; ++j) {
      int nrow = (wv * 8 + j) * 16 + r16;
      #pragma unroll
      for (int ks = 0; ks < 2; ++ks) {
        int addr = ((nrow << 7) | (ks << 6) | (kq << 4)) ^ ((nrow & 7) << 4);
        bf16x8 bfr = *(const bf16x8*)((const char*)KV + addr);
        #pragma unroll
        for (int m = 0; m < 3; ++m)
          acc[m][j] = __builtin_amdgcn_mfma_f32_16x16x32_bf16(afr[m][ks], bfr, acc[m][j], 0, 0, 0);
      }
    }
    #pragma unroll
    for (int m = 0; m < 3; ++m)
      #pragma unroll
      for (int j = 0; j < 8; ++j) {
        int l = (wv * 8 + j) * 16 + r16;
        #pragma unroll
        for (int r = 0; r < 4; ++r) {
          int u = m * 16 + kq * 4 + r;
          int byte = ((u << 10) | (l << 1)) ^ ((u & 7) << 4);
          *(unsigned short*)((char*)P + byte) = f2b(acc[m][j][r]);
        }
      }
  }
  __syncthreads();

  // stage V^T into KV region (K dead) from bf16 V
  for (int c = tid; c < 512 * 8; c += 256) {
    int l = c >> 3, dq = c & 7;
    bf16x8 v8 = *(const bf16x8*)(vbase + (size_t)l * DMOD + dq * 8);
    #pragma unroll
    for (int j = 0; j < 8; ++j) {
      int d = dq * 8 + j;
      int byte = ((d << 10) | (l << 1)) ^ ((d & 7) << 4);
      *(unsigned short*)((char*)KV + byte) = (unsigned short)v8[j];
    }
  }
  // softmax on P rows
  for (int u = wv; u < NSAMP; u += 4) {
    int byte = ((u << 10) | (lane << 4)) ^ ((u & 7) << 4);
    bf16x8 sv = *(const bf16x8*)((const char*)P + byte);
    float s[8];
    #pragma unroll
    for (int j = 0; j < 8; ++j) s[j] = b2f((unsigned short)sv[j]);
    float mx = s[0];
    #pragma unroll
    for (int j = 1; j < 8; ++j) mx = fmaxf(mx, s[j]);
    #pragma unroll
    for (int off = 32; off > 0; off >>= 1) mx = fmaxf(mx, __shfl_xor(mx, off));
    float e[8], sm = 0.f;
    #pragma unroll
    for (int j = 0; j < 8; ++j) { e[j] = __expf(s[j] - mx); sm += e[j]; }
    #pragma unroll
    for (int off = 32; off > 0; off >>= 1) sm += __shfl_xor(sm, off);
    float inv = 1.0f / sm;
    bf16x8 pv;
    #pragma unroll
    for (int j = 0; j < 8; ++j) pv[j] = (short)f2b(e[j] * inv);
    *(bf16x8*)((char*)P + byte) = pv;
  }
  __syncthreads();

  // PV: ctx[48][64] = P @ V
  {
    f32x4 acc2[3];
    #pragma unroll
    for (int m = 0; m < 3; ++m) acc2[m] = (f32x4){0.f, 0.f, 0.f, 0.f};
    for (int kst = 0; kst < 16; ++kst) {
      int vrow = wv * 16 + r16;
      int baddr = ((vrow << 10) | (kst << 6) | (kq << 4)) ^ ((vrow & 7) << 4);
      bf16x8 bfr = *(const bf16x8*)((const char*)KV + baddr);
      #pragma unroll
      for (int m = 0; m < 3; ++m) {
        int prow = m * 16 + r16;
        int aaddr = ((prow << 10) | (kst << 6) | (kq << 4)) ^ ((prow & 7) << 4);
        bf16x8 afr2 = *(const bf16x8*)((const char*)P + aaddr);
        acc2[m] = __builtin_amdgcn_mfma_f32_16x16x32_bf16(afr2, bfr, acc2[m], 0, 0, 0);
      }
    }
    int d = wv * 16 + r16;
    #pragma unroll
    for (int m = 0; m < 3; ++m)
      #pragma unroll
      for (int r = 0; r < 4; ++r) {
        int u = m * 16 + kq * 4 + r;
        if (u < NSAMP) {
          size_t off = (size_t)bv * (SEQL * DMOD) + (size_t)topi[u] * DMOD + head * 64 + d;
          ctxb[off] = f2b(acc2[m][r]);
        }
      }
  }
}

// ---------------- residual add + layernorm (vectorized: 2 rows/block) ----------------
template<int BMODE, int OUT>
__global__ __launch_bounds__(256) void add_ln(const float* __restrict__ a,
                                              const unsigned short* __restrict__ b,
                                              const float* __restrict__ g,
                                              const float* __restrict__ be,
                                              float* __restrict__ out,
                                              unsigned short* __restrict__ outb,
                                              unsigned short* __restrict__ outh,
                                              unsigned short* __restrict__ outl) {
  int row = blockIdx.x * 2 + (threadIdx.x >> 7);
  int t = threadIdx.x & 127;
  int wave = threadIdx.x >> 6;
  int lane = threadIdx.x & 63;
  size_t base = (size_t)row * DMOD + t * 4;
  float4 x = *(const float4*)(a + base);
  if (BMODE == 2) {
    ushort4 r4 = *(const ushort4*)(b + base);
    x.x += b2f(r4.x); x.y += b2f(r4.y); x.z += b2f(r4.z); x.w += b2f(r4.w);
  }
  float s1 = x.x + x.y + x.z + x.w;
  float s2 = x.x * x.x + x.y * x.y + x.z * x.z + x.w * x.w;
  #pragma unroll
  for (int off = 32; off > 0; off >>= 1) {
    s1 += __shfl_xor(s1, off);
    s2 += __shfl_xor(s2, off);
  }
  __shared__ float sh[8];
  if (lane == 0) { sh[wave * 2] = s1; sh[wave * 2 + 1] = s2; }
  __syncthreads();
  int mate = wave ^ 1;
  s1 += sh[mate * 2];
  s2 += sh[mate * 2 + 1];
  float mu = s1 * (1.0f / 512.0f);
  float var = s2 * (1.0f / 512.0f) - mu * mu;
  float rstd = rsqrtf(var + 1e-5f);
  float4 gg = *(const float4*)(g + t * 4);
  float4 bb = *(const float4*)(be + t * 4);
  float4 o;
  o.x = (x.x - mu) * rstd * gg.x + bb.x;
  o.y = (x.y - mu) * rstd * gg.y + bb.y;
  o.z = (x.z - mu) * rstd * gg.z + bb.z;
  o.w = (x.w - mu) * rstd * gg.w + bb.w;
  *(float4*)(out + base) = o;
  if (OUT == 1) {
    ushort4 ob;
    ob.x = f2b(o.x); ob.y = f2b(o.y); ob.z = f2b(o.z); ob.w = f2b(o.w);
    *(ushort4*)(outb + base) = ob;
  }
  if (OUT == 2) {
    ushort4 hi4, lo4;
    hi4.x = f2b(o.x); lo4.x = f2b(o.x - b2f(hi4.x));
    hi4.y = f2b(o.y); lo4.y = f2b(o.y - b2f(hi4.y));
    hi4.z = f2b(o.z); lo4.z = f2b(o.z - b2f(hi4.z));
    hi4.w = f2b(o.w); lo4.w = f2b(o.w - b2f(hi4.w));
    *(ushort4*)(outh + base) = hi4;
    *(ushort4*)(outl + base) = lo4;
  }
}

// ---------------- head via MFMA: partial[blk*4+w][2688], K-chunk 512/block ----------------
__global__ __launch_bounds__(256) void head_partial_mfma(const unsigned short* __restrict__ hbf,
                                                         const float* __restrict__ Wh,
                                                         float* __restrict__ partial) {
  __shared__ __align__(16) unsigned short Hs[32 * 512];   // 32 KB
  __shared__ __align__(16) unsigned short Ws[96 * 512];   // 96 KB
  int blk = blockIdx.x;            // 0..511
  int k0 = blk * 512;
  int tid = threadIdx.x;
  int wv = tid >> 6, lane = tid & 63;
  int r16 = lane & 15, kq = lane >> 4;

  for (int c = tid; c < 32 * 64; c += 256) {
    int row = c >> 6, col8 = c & 63;
    int src = row < 28 ? row : 0;
    bf16x8 v = *(const bf16x8*)(hbf + (size_t)src * 262144 + k0 + col8 * 8);
    int byte = ((row << 10) | (col8 << 4)) ^ ((row & 7) << 4);
    *(bf16x8*)((char*)Hs + byte) = v;
  }
  for (int c = tid; c < 96 * 64; c += 256) {
    int row = c >> 6, col8 = c & 63;
    const float* src = Wh + (size_t)row * 262144 + k0 + col8 * 8;
    float4 va = *(const float4*)(src);
    float4 vb = *(const float4*)(src + 4);
    bf16x8 o8;
    o8[0] = (short)f2b(va.x); o8[1] = (short)f2b(va.y);
    o8[2] = (short)f2b(va.z); o8[3] = (short)f2b(va.w);
    o8[4] = (short)f2b(vb.x); o8[5] = (short)f2b(vb.y);
    o8[6] = (short)f2b(vb.z); o8[7] = (short)f2b(vb.w);
    int byte = ((row << 10) | (col8 << 4)) ^ ((row & 7) << 4);
    *(bf16x8*)((char*)Ws + byte) = o8;
  }
  __syncthreads();

  f32x4 acc[2][6];
  #pragma unroll
  for (int mt = 0; mt < 2; ++mt)
    #pragma unroll
    for (int nt = 0; nt < 6; ++nt) acc[mt][nt] = (f32x4){0.f, 0.f, 0.f, 0.f};

  #pragma unroll
  for (int kk = 0; kk < 4; ++kk) {
    int kfrag = wv * 4 + kk;     // k = kfrag*32 + kq*8
    bf16x8 afr[2];
    #pragma unroll
    for (int mt = 0; mt < 2; ++mt) {
      int row = mt * 16 + r16;
      int byte = ((row << 10) | (kfrag << 6) | (kq << 4)) ^ ((row & 7) << 4);
      afr[mt] = *(const bf16x8*)((const char*)Hs + byte);
    }
    #pragma unroll
    for (int nt = 0; nt < 6; ++nt) {
      int row = nt * 16 + r16;
      int byte = ((row << 10) | (kfrag << 6) | (kq << 4)) ^ ((row & 7) << 4);
      bf16x8 bfr = *(const bf16x8*)((const char*)Ws + byte);
      #pragma unroll
      for (int mt = 0; mt < 2; ++mt)
        acc[mt][nt] = __builtin_amdgcn_mfma_f32_16x16x32_bf16(afr[mt], bfr, acc[mt][nt], 0, 0, 0);
    }
  }
  size_t prow = (size_t)(blk * 4 + wv) * 2688;
  #pragma unroll
  for (int mt = 0; mt < 2; ++mt)
    #pragma unroll
    for (int nt = 0; nt < 6; ++nt)
      #pragma unroll
      for (int r = 0; r < 4; ++r) {
        int m = mt * 16 + kq * 4 + r;
        int n = nt * 16 + r16;
        if (m < 28) partial[prow + m * 96 + n] = acc[mt][nt][r];
      }
}

// ---------------- head reduce (coalesced: 32 consecutive columns per 32 lanes) ----------------
__global__ __launch_bounds__(256) void head_reduce(const float* __restrict__ partial,
                                                   const float* __restrict__ bh_,
                                                   float* __restrict__ out) {
  int blk = blockIdx.x;            // 0..83, columns blk*32..blk*32+31
  int o0 = blk * 32;
  int oo = threadIdx.x & 31;
  int rp = threadIdx.x >> 5;       // 0..7
  float s = 0.f;
  for (int r = rp; r < 2048; r += 8)
    s += partial[(size_t)r * 2688 + o0 + oo];
  __shared__ float red[256];
  red[threadIdx.x] = s;
  __syncthreads();
  if (rp == 0) {
    float tot = 0.f;
    #pragma unroll
    for (int k = 0; k < 8; ++k) tot += red[k * 32 + oo];
    int o = o0 + oo;
    int m = o / 96, p = o % 96;
    int b = m / NVARS, v = m % NVARS;
    out[(size_t)b * (NPRED * NVARS) + (size_t)p * NVARS + v] = tot + bh_[p];
  }
}

extern "C" void kernel_launch(void* const* d_in, const int* in_sizes, int n_in,
                              void* d_out, int out_size, void* d_ws, size_t ws_size,
                              hipStream_t stream) {
  const float* x_enc = (const float*)d_in[0];
  const float* w_emb = (const float*)d_in[1];
  const float* b_emb = (const float*)d_in[2];
  const float* w_pos = (const float*)d_in[3];
  const float* Wq = (const float*)d_in[4];
  const float* bq = (const float*)d_in[5];
  const float* Wk = (const float*)d_in[6];
  const float* bk = (const float*)d_in[7];
  const float* Wv = (const float*)d_in[8];
  const float* bv_ = (const float*)d_in[9];
  const float* Wo = (const float*)d_in[10];
  const float* bo = (const float*)d_in[11];
  const float* W1 = (const float*)d_in[12];
  const float* b1 = (const float*)d_in[13];
  const float* W2 = (const float*)d_in[14];
  const float* b2 = (const float*)d_in[15];
  const float* g1 = (const float*)d_in[16];
  const float* be1 = (const float*)d_in[17];
  const float* g2 = (const float*)d_in[18];
  const float* be2 = (const float*)d_in[19];
  const float* gF = (const float*)d_in[20];
  const float* bF = (const float*)d_in[21];
  const float* Wh = (const float*)d_in[22];
  const float* bh_ = (const float*)d_in[23];
  float* out = (float*)d_out;

  const size_t S = (size_t)SBIG;
  const size_t SB = S * 4;                    // 29,360,128 B
  char* ws = (char*)d_ws;
  float* h    = (float*)(ws);                 // [0, SB)
  float* QKb  = (float*)(ws + SB);            // [SB, 3SB): [14336][1024] fp32
  unsigned short* Vb   = (unsigned short*)(ws + 3 * SB);            // 14.7 MB
  unsigned short* Ob_b = (unsigned short*)(ws + 3 * SB + SB / 2);   // 14.7 MB
  // weight scratch region [4SB, 5SB)
  unsigned short* Wqk_hi = (unsigned short*)(ws + 4 * SB);                  // 1 MB
  unsigned short* Wqk_lo = (unsigned short*)(ws + 4 * SB + 0x100000);       // 1 MB
  unsigned short* Wv_b = (unsigned short*)(ws + 4 * SB + 0x200000);         // 0.5 MB
  unsigned short* Wo_b = (unsigned short*)(ws + 4 * SB + 0x280000);         // 0.5 MB
  unsigned short* W1_b = (unsigned short*)(ws + 4 * SB + 0x300000);         // 2 MB
  unsigned short* W2_b = (unsigned short*)(ws + 4 * SB + 0x500000);         // 2 MB
  unsigned short* h_hi = (unsigned short*)(ws + 5 * SB);           // SB/2
  unsigned short* h_lo = (unsigned short*)(ws + 5 * SB + SB / 2);  // SB/2
  // phase aliases:
  unsigned short* CTXb = h_hi;                 // after QK+V gemms consumed h_hi
  unsigned short* h_bf = h_lo;                 // after QK gemm consumed h_lo
  unsigned short* FFNb = (unsigned short*)QKb; // after attn consumed QK
  float* partial = QKb;                        // head phase (22 MB <= 2SB)
  int*   idx = (int*)(ws + 6 * SB);                        // 70KB (transposed)
  float* vpart = (float*)(ws + 6 * SB + 0x20000);          // 448KB (224*512 f)
  int*   top = (int*)(ws + 6 * SB + 0xA0000);              // 31KB
  if (ws_size < 6 * SB + 0xC0000) return;

  dim3 b256(256);
  int gVec = (int)(S / 4 / 256);   // 7168

  embed_kernel<<<gVec, b256, 0, stream>>>(x_enc, w_emb, b_emb, w_pos, h, h_hi, h_lo);

  for (int l = 0; l < 2; ++l) {
    const float* Wql = Wq + (size_t)l * DMOD * DMOD;
    const float* Wkl = Wk + (size_t)l * DMOD * DMOD;
    const float* Wvl = Wv + (size_t)l * DMOD * DMOD;
    const float* Wol = Wo + (size_t)l * DMOD * DMOD;
    const float* W1l = W1 + (size_t)l * DFFN * DMOD;
    const float* W2l = W2 + (size_t)l * DMOD * DFFN;

    prep_weights<<<3072, b256, 0, stream>>>(Wql, Wkl, Wvl, Wol, W1l, W2l,
                                            Wqk_hi, Wqk_lo, Wv_b, Wo_b, W1_b, W2_b);

    dim3 gqk(QKS / 128, NROWS / 128);
    gemm_mfma3<<<gqk, b256, 0, stream>>>(h_hi, h_lo, Wqk_hi, Wqk_lo,
                                         bq + l * DMOD, bk + l * DMOD,
                                         QKb, NROWS, QKS, DMOD, QKS);
    dim3 gv(DMOD / 128, NROWS / 128);
    gemm_mfma<0, 1><<<gv, b256, 0, stream>>>(h_hi, Wv_b, bv_ + l * DMOD,
                                             (float*)0, Vb, NROWS, DMOD, DMOD);

    make_idx_kernel<<<(SEQL * NSAMP + 255) / 256, b256, 0, stream>>>(l, idx);
    m2_topk_kernel<<<NBH, dim3(512), 0, stream>>>(QKb, idx, top);
    vmean_part_kernel<<<NBV * 8, b256, 0, stream>>>(Vb, vpart);
    ctx_fill_kernel<<<gVec, b256, 0, stream>>>(vpart, CTXb);
    attn2_kernel<<<NBH, b256, 0, stream>>>(QKb, Vb, top, CTXb);

    dim3 go(DMOD / 128, NROWS / 128);
    gemm_mfma<0, 1><<<go, b256, 0, stream>>>(CTXb, Wo_b, bo + l * DMOD,
                                             (float*)0, Ob_b, NROWS, DMOD, DMOD);
    add_ln<2, 1><<<NROWS / 2, b256, 0, stream>>>(h, Ob_b, g1 + l * DMOD, be1 + l * DMOD,
                                                 h, h_bf, (unsigned short*)0, (unsigned short*)0);

    dim3 gf1(DFFN / 128, NROWS / 128);
    gemm_mfma<1, 1><<<gf1, b256, 0, stream>>>(h_bf, W1_b, b1 + l * DFFN,
                                              (float*)0, FFNb, NROWS, DFFN, DMOD);
    dim3 gf2(DMOD / 128, NROWS / 128);
    gemm_mfma<0, 1><<<gf2, b256, 0, stream>>>(FFNb, W2_b, b2 + l * DMOD,
                                              (float*)0, Ob_b, NROWS, DMOD, DFFN);
    if (l == 0) {
      add_ln<2, 2><<<NROWS / 2, b256, 0, stream>>>(h, Ob_b, g2 + l * DMOD, be2 + l * DMOD,
                                                   h, (unsigned short*)0, h_hi, h_lo);
    } else {
      add_ln<2, 0><<<NROWS / 2, b256, 0, stream>>>(h, Ob_b, g2 + l * DMOD, be2 + l * DMOD,
                                                   h, (unsigned short*)0, (unsigned short*)0, (unsigned short*)0);
    }
  }

  add_ln<0, 1><<<NROWS / 2, b256, 0, stream>>>(h, (const unsigned short*)0, gF, bF,
                                               h, h_bf, (unsigned short*)0, (unsigned short*)0);
  head_partial_mfma<<<512, b256, 0, stream>>>(h_bf, Wh, partial);
  head_reduce<<<84, b256, 0, stream>>>(partial, bh_, out);
}

// Round 15
// 676.847 us; speedup vs baseline: 1.5074x; 1.0813x over previous
//
#include <hip/hip_runtime.h>
#include <math.h>

#define SEQL 512
#define DMOD 512
#define NHEAD 8
#define DHEAD 64
#define DFFN 2048
#define NBATCH 4
#define NVARS 7
#define NBV 28          // NBATCH*NVARS
#define NBH 224         // NBV*NHEAD
#define NROWS 14336     // NBV*SEQL
#define NSAMP 35        // U_part = u = 35
#define NPRED 96
#define SBIG 7340032    // NBV*SEQL*DMOD floats
#define QKS 1024        // fused QK row stride

typedef short bf16x8 __attribute__((ext_vector_type(8)));
typedef float f32x4 __attribute__((ext_vector_type(4)));

#define GLDS(gptr, lptr) \
  __builtin_amdgcn_global_load_lds((const __attribute__((address_space(1))) void*)(gptr), \
                                   (__attribute__((address_space(3))) void*)(lptr), 16, 0, 0)

__device__ inline unsigned short f2b(float f) {
  unsigned u = __builtin_bit_cast(unsigned, f);
  unsigned r = (u + 0x7FFFu + ((u >> 16) & 1u)) >> 16;
  return (unsigned short)r;
}
__device__ inline float b2f(unsigned short h) {
  return __builtin_bit_cast(float, (unsigned)h << 16);
}

// ---------------- threefry2x32 (matches jax._src.prng) ----------------
__device__ inline void threefry2x32(unsigned k0, unsigned k1,
                                    unsigned x0, unsigned x1,
                                    unsigned &o0, unsigned &o1) {
  unsigned ks2 = k0 ^ k1 ^ 0x1BD11BDAu;
  unsigned ks[3] = {k0, k1, ks2};
  x0 += k0; x1 += k1;
  const unsigned rot[2][4] = {{13u,15u,26u,6u},{17u,29u,16u,24u}};
  #pragma unroll
  for (int i = 0; i < 5; ++i) {
    #pragma unroll
    for (int j = 0; j < 4; ++j) {
      unsigned r = rot[i & 1][j];
      x0 += x1;
      x1 = (x1 << r) | (x1 >> (32u - r));
      x1 ^= x0;
    }
    x0 += ks[(i + 1) % 3];
    x1 += ks[(i + 2) % 3] + (unsigned)(i + 1);
  }
  o0 = x0; o1 = x1;
}

// writes TRANSPOSED layout idx_t[u*512 + q]
__global__ void make_idx_kernel(int layer, int* idx_t) {
  int i = blockIdx.x * 256 + threadIdx.x;
  if (i >= SEQL * NSAMP) return;
  unsigned kl0, kl1, o0, o1;
  threefry2x32(0u, 42u, 0u, (unsigned)layer, kl0, kl1);
  threefry2x32(kl0, kl1, (unsigned)i, (unsigned)(SEQL * NSAMP + i), o0, o1);
  int q = i / NSAMP, u = i % NSAMP;
  idx_t[u * SEQL + q] = (int)(o1 & 511u);
}

// ---------------- embedding (vectorized, fused hi/lo split) ----------------
__global__ void embed_kernel(const float* __restrict__ x_enc,
                             const float* __restrict__ w_emb,
                             const float* __restrict__ b_emb,
                             const float* __restrict__ w_pos,
                             float* __restrict__ h,
                             unsigned short* __restrict__ h_hi,
                             unsigned short* __restrict__ h_lo) {
  size_t i = (size_t)blockIdx.x * 256 + threadIdx.x;
  if (i >= (size_t)(SBIG / 4)) return;
  size_t e = i * 4;
  int dm = (int)(e & 511);
  int l  = (int)((e >> 9) & 511);
  int bv = (int)(e >> 18);
  int b = bv / NVARS, v = bv % NVARS;
  float xs = x_enc[((size_t)b * SEQL + l) * NVARS + v];
  float4 we = *(const float4*)(w_emb + dm);
  float4 bb = *(const float4*)(b_emb + dm);
  float4 wp = *(const float4*)(w_pos + (size_t)l * DMOD + dm);
  float4 val;
  val.x = xs * we.x + bb.x + wp.x;
  val.y = xs * we.y + bb.y + wp.y;
  val.z = xs * we.z + bb.z + wp.z;
  val.w = xs * we.w + bb.w + wp.w;
  *(float4*)(h + e) = val;
  ushort4 hi4, lo4;
  hi4.x = f2b(val.x); lo4.x = f2b(val.x - b2f(hi4.x));
  hi4.y = f2b(val.y); lo4.y = f2b(val.y - b2f(hi4.y));
  hi4.z = f2b(val.z); lo4.z = f2b(val.z - b2f(hi4.z));
  hi4.w = f2b(val.w); lo4.w = f2b(val.w - b2f(hi4.w));
  *(ushort4*)(h_hi + e) = hi4;
  *(ushort4*)(h_lo + e) = lo4;
}

// ---------------- fused per-layer weight prep (one dispatch) ----------------
__global__ void prep_weights(const float* __restrict__ Wq, const float* __restrict__ Wk,
                             const float* __restrict__ Wv, const float* __restrict__ Wo,
                             const float* __restrict__ W1, const float* __restrict__ W2,
                             unsigned short* __restrict__ Wqk_hi, unsigned short* __restrict__ Wqk_lo,
                             unsigned short* __restrict__ Wv_b, unsigned short* __restrict__ Wo_b,
                             unsigned short* __restrict__ W1_b, unsigned short* __restrict__ W2_b) {
  const int Q4 = 65536;   // 262144/4
  int g = blockIdx.x * 256 + threadIdx.x;
  if (g < 2 * Q4) {
    const float* src = g < Q4 ? Wq : Wk;
    unsigned short* hi = Wqk_hi + (g < Q4 ? 0 : DMOD * DMOD);
    unsigned short* lo = Wqk_lo + (g < Q4 ? 0 : DMOD * DMOD);
    int off = (g < Q4 ? g : g - Q4) * 4;
    float4 v = *(const float4*)(src + off);
    ushort4 h4, l4;
    h4.x = f2b(v.x); l4.x = f2b(v.x - b2f(h4.x));
    h4.y = f2b(v.y); l4.y = f2b(v.y - b2f(h4.y));
    h4.z = f2b(v.z); l4.z = f2b(v.z - b2f(h4.z));
    h4.w = f2b(v.w); l4.w = f2b(v.w - b2f(h4.w));
    *(ushort4*)(hi + off) = h4;
    *(ushort4*)(lo + off) = l4;
    return;
  }
  const float* src;
  unsigned short* dst;
  int off;
  if (g < 3 * Q4)      { src = Wv; dst = Wv_b; off = (g - 2 * Q4) * 4; }
  else if (g < 4 * Q4) { src = Wo; dst = Wo_b; off = (g - 3 * Q4) * 4; }
  else if (g < 4 * Q4 + 262144) { src = W1; dst = W1_b; off = (g - 4 * Q4) * 4; }
  else                 { src = W2; dst = W2_b; off = (g - 4 * Q4 - 262144) * 4; }
  float4 v = *(const float4*)(src + off);
  ushort4 o;
  o.x = f2b(v.x); o.y = f2b(v.y); o.z = f2b(v.z); o.w = f2b(v.w);
  *(ushort4*)(dst + off) = o;
}

// ---------------- split-bf16 MFMA GEMM (3-pass hi/lo): C = A@W^T + [bq|bk] ----------------
__global__ __launch_bounds__(256) void gemm_mfma3(const unsigned short* __restrict__ Ah,
                                                  const unsigned short* __restrict__ Al,
                                                  const unsigned short* __restrict__ Bh,
                                                  const unsigned short* __restrict__ Bl,
                                                  const float* __restrict__ bq,
                                                  const float* __restrict__ bk,
                                                  float* __restrict__ C,
                                                  int M, int N, int K, int ldc) {
  __shared__ __align__(16) unsigned short AsH[128 * 64];
  __shared__ __align__(16) unsigned short AsL[128 * 64];
  __shared__ __align__(16) unsigned short BsH[128 * 64];
  __shared__ __align__(16) unsigned short BsL[128 * 64];
  int nwg = gridDim.x * gridDim.y;
  int flat = blockIdx.y * gridDim.x + blockIdx.x;
  int swz = (flat & 7) * (nwg >> 3) + (flat >> 3);
  int bxs = swz % gridDim.x, bys = swz / gridDim.x;
  int bm = bys * 128, bn = bxs * 128;
  int tid = threadIdx.x;
  int wave = tid >> 6, lane = tid & 63;
  int wr = wave >> 1, wc = wave & 1;
  int r16 = lane & 15, kq = lane >> 4;

  f32x4 acc[4][4];
  #pragma unroll
  for (int i = 0; i < 4; ++i)
    #pragma unroll
    for (int j = 0; j < 4; ++j) acc[i][j] = (f32x4){0.f, 0.f, 0.f, 0.f};

  for (int kt = 0; kt < K; kt += 64) {
    __syncthreads();
    #pragma unroll
    for (int i = 0; i < 4; ++i) {
      int c = i * 256 + tid;
      int row = c >> 3, kb = c & 7;
      int kbs = kb ^ (row & 7);             // pre-swizzled source
      size_t offA = (size_t)(bm + row) * K + kt + kbs * 8;
      size_t offB = (size_t)(bn + row) * K + kt + kbs * 8;
      int ldst = (i * 256 + (tid & 192)) << 4;   // wave-uniform linear dest
      GLDS(Ah + offA, (char*)AsH + ldst);
      GLDS(Al + offA, (char*)AsL + ldst);
      GLDS(Bh + offB, (char*)BsH + ldst);
      GLDS(Bl + offB, (char*)BsL + ldst);
    }
    __syncthreads();
    #pragma unroll
    for (int ks = 0; ks < 2; ++ks) {
      bf16x8 ah[4], al[4], bh[4], bl[4];
      #pragma unroll
      for (int mi = 0; mi < 4; ++mi) {
        int row = wr * 64 + mi * 16 + r16;
        int addr = ((row << 7) | (ks << 6) | (kq << 4)) ^ ((row & 7) << 4);
        ah[mi] = *(const bf16x8*)((const char*)AsH + addr);
        al[mi] = *(const bf16x8*)((const char*)AsL + addr);
      }
      #pragma unroll
      for (int ni = 0; ni < 4; ++ni) {
        int row = wc * 64 + ni * 16 + r16;
        int addr = ((row << 7) | (ks << 6) | (kq << 4)) ^ ((row & 7) << 4);
        bh[ni] = *(const bf16x8*)((const char*)BsH + addr);
        bl[ni] = *(const bf16x8*)((const char*)BsL + addr);
      }
      #pragma unroll
      for (int mi = 0; mi < 4; ++mi)
        #pragma unroll
        for (int ni = 0; ni < 4; ++ni) {
          acc[mi][ni] = __builtin_amdgcn_mfma_f32_16x16x32_bf16(ah[mi], bh[ni], acc[mi][ni], 0, 0, 0);
          acc[mi][ni] = __builtin_amdgcn_mfma_f32_16x16x32_bf16(ah[mi], bl[ni], acc[mi][ni], 0, 0, 0);
          acc[mi][ni] = __builtin_amdgcn_mfma_f32_16x16x32_bf16(al[mi], bh[ni], acc[mi][ni], 0, 0, 0);
        }
    }
  }
  int crow0 = bm + wr * 64 + (lane >> 4) * 4;
  int ccol0 = bn + wc * 64 + (lane & 15);
  #pragma unroll
  for (int mi = 0; mi < 4; ++mi) {
    #pragma unroll
    for (int ni = 0; ni < 4; ++ni) {
      int col = ccol0 + ni * 16;
      float bvv = col < 512 ? bq[col] : bk[col - 512];
      #pragma unroll
      for (int r = 0; r < 4; ++r) {
        int row = crow0 + mi * 16 + r;
        C[(size_t)row * ldc + col] = acc[mi][ni][r] + bvv;
      }
    }
  }
}

// ---------------- bf16 MFMA GEMM, 2-phase double-buffered LDS ----------------
template<int ACT, int OUTBF>
__global__ __launch_bounds__(256) void gemm_mfma(const unsigned short* __restrict__ A,
                                                 const unsigned short* __restrict__ W,
                                                 const float* __restrict__ bias,
                                                 float* __restrict__ Cf,
                                                 unsigned short* __restrict__ Cb,
                                                 int M, int N, int K) {
  __shared__ __align__(16) unsigned short As[2][128 * 64];   // 16 KB x2
  __shared__ __align__(16) unsigned short Bs[2][128 * 64];   // 16 KB x2
  int nwg = gridDim.x * gridDim.y;
  int flat = blockIdx.y * gridDim.x + blockIdx.x;
  int swz = (flat & 7) * (nwg >> 3) + (flat >> 3);
  int bxs = swz % gridDim.x, bys = swz / gridDim.x;
  int bm = bys * 128, bn = bxs * 128;
  int tid = threadIdx.x;
  int wave = tid >> 6, lane = tid & 63;
  int wr = wave >> 1, wc = wave & 1;
  int r16 = lane & 15, kq = lane >> 4;

  f32x4 acc[4][4];
  #pragma unroll
  for (int i = 0; i < 4; ++i)
    #pragma unroll
    for (int j = 0; j < 4; ++j) acc[i][j] = (f32x4){0.f, 0.f, 0.f, 0.f};

#define STAGE_MM(buf, ktv) \
  { \
    for (int i_ = 0; i_ < 4; ++i_) { \
      int c_ = i_ * 256 + tid; \
      int row_ = c_ >> 3, kb_ = c_ & 7; \
      int kbs_ = kb_ ^ (row_ & 7); \
      size_t offA_ = (size_t)(bm + row_) * K + (ktv) + kbs_ * 8; \
      size_t offB_ = (size_t)(bn + row_) * K + (ktv) + kbs_ * 8; \
      int ldst_ = (i_ * 256 + (tid & 192)) << 4; \
      GLDS(A + offA_, (char*)As[buf] + ldst_); \
      GLDS(W + offB_, (char*)Bs[buf] + ldst_); \
    } \
  }

  int nkt = K >> 6;
  STAGE_MM(0, 0);
  __syncthreads();                 // compiler drains vmcnt before barrier
  for (int t = 0; t < nkt; ++t) {
    int cur = t & 1;
    if (t + 1 < nkt) STAGE_MM(cur ^ 1, (t + 1) << 6);
    const char* Ab = (const char*)As[cur];
    const char* Bb = (const char*)Bs[cur];
    #pragma unroll
    for (int ks = 0; ks < 2; ++ks) {
      bf16x8 afr[4], bfr[4];
      #pragma unroll
      for (int mi = 0; mi < 4; ++mi) {
        int row = wr * 64 + mi * 16 + r16;
        int addr = ((row << 7) | (ks << 6) | (kq << 4)) ^ ((row & 7) << 4);
        afr[mi] = *(const bf16x8*)(Ab + addr);
      }
      #pragma unroll
      for (int ni = 0; ni < 4; ++ni) {
        int row = wc * 64 + ni * 16 + r16;
        int addr = ((row << 7) | (ks << 6) | (kq << 4)) ^ ((row & 7) << 4);
        bfr[ni] = *(const bf16x8*)(Bb + addr);
      }
      #pragma unroll
      for (int mi = 0; mi < 4; ++mi)
        #pragma unroll
        for (int ni = 0; ni < 4; ++ni)
          acc[mi][ni] = __builtin_amdgcn_mfma_f32_16x16x32_bf16(afr[mi], bfr[ni], acc[mi][ni], 0, 0, 0);
    }
    __syncthreads();               // drains the in-flight next-buf GLDS too
  }
#undef STAGE_MM

  int crow0 = bm + wr * 64 + (lane >> 4) * 4;
  int ccol0 = bn + wc * 64 + (lane & 15);
  #pragma unroll
  for (int mi = 0; mi < 4; ++mi) {
    #pragma unroll
    for (int ni = 0; ni < 4; ++ni) {
      int col = ccol0 + ni * 16;
      float bvv = bias[col];
      #pragma unroll
      for (int r = 0; r < 4; ++r) {
        int row = crow0 + mi * 16 + r;
        float v = acc[mi][ni][r] + bvv;
        if (ACT) {
          // gelu(tanh approx) = x * sigmoid(2*0.79788456(x+0.044715x^3))
          float x = v;
          float u = x * __builtin_fmaf(0.044715f * x, x, 1.0f);
          float tme = __expf(-1.5957691216057308f * u);
          v = x * __builtin_amdgcn_rcpf(1.0f + tme);
        }
        if (OUTBF) Cb[(size_t)row * N + col] = f2b(v);
        else       Cf[(size_t)row * N + col] = v;
      }
    }
  }
}

// ---------------- M measure + wave-parallel top-k fused: block per (bh) ----------------
__global__ __launch_bounds__(512) void m2_topk_kernel(const float* __restrict__ QK,
                                                      const int* __restrict__ idx_t,
                                                      int* __restrict__ top) {
  int bh = blockIdx.x;
  int bv = bh >> 3, head = bh & 7;
  int tid = threadIdx.x;                 // 0..511, one q-row each
  int lane = tid & 63, wv8 = tid >> 6;
  __shared__ float Ks[512 * 64];         // 128 KB, word(l,db) = l*64 + ((db^(l&15))<<2)
  const float* base = QK + (size_t)bv * (SEQL * QKS);
  for (int c = tid; c < 512 * 16; c += 512) {
    int l = c >> 4, db = c & 15;
    float4 v = *(const float4*)(base + (size_t)l * QKS + 512 + head * 64 + db * 4);
    *(float4*)(Ks + l * 64 + ((db ^ (l & 15)) << 2)) = v;
  }
  float q[64];
  const float* qp = base + (size_t)tid * QKS + head * 64;
  #pragma unroll
  for (int d4 = 0; d4 < 64; d4 += 4) {
    float4 qv = *(const float4*)(qp + d4);
    q[d4 + 0] = qv.x; q[d4 + 1] = qv.y; q[d4 + 2] = qv.z; q[d4 + 3] = qv.w;
  }
  __syncthreads();
  float mx = -INFINITY, sm = 0.f;
  for (int u = 0; u < NSAMP; ++u) {
    int kidx = idx_t[u * SEQL + tid];   // coalesced
    const float* kr = Ks + kidx * 64;
    int x = kidx & 15;
    float s = 0.f;
    #pragma unroll
    for (int db = 0; db < 16; ++db) {
      float4 kv = *(const float4*)(kr + ((db ^ x) << 2));
      s += q[db * 4 + 0] * kv.x + q[db * 4 + 1] * kv.y
         + q[db * 4 + 2] * kv.z + q[db * 4 + 3] * kv.w;
    }
    mx = fmaxf(mx, s);
    sm += s;
  }
  float Mval = mx - sm * (1.0f / 512.0f);
  __syncthreads();                       // all Ks reads done; reuse LDS
  float* vals = Ks;                      // [512]
  float* wred = Ks + 512;                // [8]
  int*   widx = (int*)(Ks + 520);        // [8]
  vals[tid] = Mval;
  __syncthreads();
  for (int t = 0; t < NSAMP; ++t) {
    float v = vals[tid];
    int ii = tid;
    #pragma unroll
    for (int off = 32; off > 0; off >>= 1) {
      float ov = __shfl_xor(v, off);
      int oi = __shfl_xor(ii, off);
      if (ov > v || (ov == v && oi < ii)) { v = ov; ii = oi; }
    }
    if (lane == 0) { wred[wv8] = v; widx[wv8] = ii; }
    __syncthreads();
    if (tid == 0) {
      float bvv = wred[0]; int bi = widx[0];
      #pragma unroll
      for (int w = 1; w < 8; ++w)
        if (wred[w] > bvv) { bvv = wred[w]; bi = widx[w]; }
      top[bh * NSAMP + t] = bi;
      vals[bi] = -INFINITY;
    }
    __syncthreads();
  }
}

// ---------------- mean of V partials: block per (bv, rowgroup of 64) ----------------
__global__ __launch_bounds__(256) void vmean_part_kernel(const unsigned short* __restrict__ Vb,
                                                         float* __restrict__ part) {
  int blk = blockIdx.x;                // 0..223 = bv*8+g
  int bv = blk >> 3, grp = blk & 7;
  int t = threadIdx.x;                 // cols 2t, 2t+1
  const unsigned short* vb = Vb + (size_t)bv * (SEQL * DMOD) + (size_t)grp * 64 * DMOD + t * 2;
  float s0 = 0.f, s1 = 0.f;
  #pragma unroll 4
  for (int l = 0; l < 64; ++l) {
    unsigned u = *(const unsigned*)(vb + (size_t)l * DMOD);
    s0 += b2f((unsigned short)(u & 0xffffu));
    s1 += b2f((unsigned short)(u >> 16));
  }
  part[(size_t)blk * DMOD + t * 2]     = s0;
  part[(size_t)blk * DMOD + t * 2 + 1] = s1;
}

// ---------------- ctx = broadcast vmean (sums 8 partials, bf16 out) ----------------
__global__ void ctx_fill_kernel(const float* __restrict__ part,
                                unsigned short* __restrict__ ctxb) {
  size_t i = (size_t)blockIdx.x * 256 + threadIdx.x;
  if (i >= (size_t)(SBIG / 4)) return;
  size_t e = i * 4;
  int dm = (int)(e & 511);
  int bv = (int)(e >> 18);
  float4 vm = {0.f, 0.f, 0.f, 0.f};
  #pragma unroll
  for (int g = 0; g < 8; ++g) {
    float4 p = *(const float4*)(part + (size_t)(bv * 8 + g) * DMOD + dm);
    vm.x += p.x; vm.y += p.y; vm.z += p.z; vm.w += p.w;
  }
  const float inv = 1.0f / 512.0f;
  ushort4 o;
  o.x = f2b(vm.x * inv); o.y = f2b(vm.y * inv);
  o.z = f2b(vm.z * inv); o.w = f2b(vm.w * inv);
  *(ushort4*)(ctxb + e) = o;
}

// ---------------- MFMA attention for selected queries: block per (bh) ----------------
__global__ __launch_bounds__(256) void attn2_kernel(const float* __restrict__ QK,
                                                    const unsigned short* __restrict__ Vb,
                                                    const int* __restrict__ top,
                                                    unsigned short* __restrict__ ctxb) {
  __shared__ __align__(16) unsigned short KV[512 * 64];
  __shared__ __align__(16) unsigned short P[48 * 512];
  __shared__ __align__(16) unsigned short Qs[48 * 64];
  __shared__ int topi[NSAMP];
  int bh = blockIdx.x;
  int bv = bh >> 3, head = bh & 7;
  int tid = threadIdx.x;
  int wv = tid >> 6, lane = tid & 63;
  int r16 = lane & 15, kq = lane >> 4;
  const float* base = QK + (size_t)bv * (SEQL * QKS);
  const unsigned short* vbase = Vb + (size_t)bv * (SEQL * DMOD) + head * 64;

  if (tid < NSAMP) topi[tid] = top[bh * NSAMP + tid];
  __syncthreads();

  for (int c = tid; c < NSAMP * 16; c += 256) {
    int u = c >> 4, dq = c & 15;
    float4 q4 = *(const float4*)(base + (size_t)topi[u] * QKS + head * 64 + dq * 4);
    ushort4 o;
    o.x = f2b(q4.x * 0.125f); o.y = f2b(q4.y * 0.125f);
    o.z = f2b(q4.z * 0.125f); o.w = f2b(q4.w * 0.125f);
    int byte = ((u << 7) | (dq << 3)) ^ ((u & 7) << 4);
    *(ushort4*)((char*)Qs + byte) = o;
  }
  for (int c = tid; c < 512 * 16; c += 256) {
    int l = c >> 4, dq = c & 15;
    float4 k4 = *(const float4*)(base + (size_t)l * QKS + 512 + head * 64 + dq * 4);
    ushort4 o;
    o.x = f2b(k4.x); o.y = f2b(k4.y); o.z = f2b(k4.z); o.w = f2b(k4.w);
    int byte = ((l << 7) | (dq << 3)) ^ ((l & 7) << 4);
    *(ushort4*)((char*)KV + byte) = o;
  }
  __syncthreads();

  // QK^T: scores[48][512]
  {
    f32x4 acc[3][8];
    #pragma unroll
    for (int m = 0; m < 3; ++m)
      #pragma unroll
      for (int j = 0; j < 8; ++j) acc[m][j] = (f32x4){0.f, 0.f, 0.f, 0.f};
    bf16x8 afr[3][2];
    #pragma unroll
    for (int m = 0; m < 3; ++m)
      #pragma unroll
      for (int ks = 0; ks < 2; ++ks) {
        int row = m * 16 + r16;
        int addr = ((row << 7) | (ks << 6) | (kq << 4)) ^ ((row & 7) << 4);
        afr[m][ks] = *(const bf16x8*)((const char*)Qs + addr);
      }
    #pragma unroll
    for (int j = 0; j < 8; ++j) {
      int nrow = (wv * 8 + j) * 16 + r16;
      #pragma unroll
      for (int ks = 0; ks < 2; ++ks) {
        int addr = ((nrow << 7) | (ks << 6) | (kq << 4)) ^ ((nrow & 7) << 4);
        bf16x8 bfr = *(const bf16x8*)((const char*)KV + addr);
        #pragma unroll
        for (int m = 0; m < 3; ++m)
          acc[m][j] = __builtin_amdgcn_mfma_f32_16x16x32_bf16(afr[m][ks], bfr, acc[m][j], 0, 0, 0);
      }
    }
    #pragma unroll
    for (int m = 0; m < 3; ++m)
      #pragma unroll
      for (int j = 0; j < 8; ++j) {
        int l = (wv * 8 + j) * 16 + r16;
        #pragma unroll
        for (int r = 0; r < 4; ++r) {
          int u = m * 16 + kq * 4 + r;
          int byte = ((u << 10) | (l << 1)) ^ ((u & 7) << 4);
          *(unsigned short*)((char*)P + byte) = f2b(acc[m][j][r]);
        }
      }
  }
  __syncthreads();

  // stage V^T into KV region (K dead) from bf16 V
  for (int c = tid; c < 512 * 8; c += 256) {
    int l = c >> 3, dq = c & 7;
    bf16x8 v8 = *(const bf16x8*)(vbase + (size_t)l * DMOD + dq * 8);
    #pragma unroll
    for (int j = 0; j < 8; ++j) {
      int d = dq * 8 + j;
      int byte = ((d << 10) | (l << 1)) ^ ((d & 7) << 4);
      *(unsigned short*)((char*)KV + byte) = (unsigned short)v8[j];
    }
  }
  // softmax on P rows
  for (int u = wv; u < NSAMP; u += 4) {
    int byte = ((u << 10) | (lane << 4)) ^ ((u & 7) << 4);
    bf16x8 sv = *(const bf16x8*)((const char*)P + byte);
    float s[8];
    #pragma unroll
    for (int j = 0; j < 8; ++j) s[j] = b2f((unsigned short)sv[j]);
    float mx = s[0];
    #pragma unroll
    for (int j = 1; j < 8; ++j) mx = fmaxf(mx, s[j]);
    #pragma unroll
    for (int off = 32; off > 0; off >>= 1) mx = fmaxf(mx, __shfl_xor(mx, off));
    float e[8], sm = 0.f;
    #pragma unroll
    for (int j = 0; j < 8; ++j) { e[j] = __expf(s[j] - mx); sm += e[j]; }
    #pragma unroll
    for (int off = 32; off > 0; off >>= 1) sm += __shfl_xor(sm, off);
    float inv = 1.0f / sm;
    bf16x8 pv;
    #pragma unroll
    for (int j = 0; j < 8; ++j) pv[j] = (short)f2b(e[j] * inv);
    *(bf16x8*)((char*)P + byte) = pv;
  }
  __syncthreads();

  // PV: ctx[48][64] = P @ V
  {
    f32x4 acc2[3];
    #pragma unroll
    for (int m = 0; m < 3; ++m) acc2[m] = (f32x4){0.f, 0.f, 0.f, 0.f};
    for (int kst = 0; kst < 16; ++kst) {
      int vrow = wv * 16 + r16;
      int baddr = ((vrow << 10) | (kst << 6) | (kq << 4)) ^ ((vrow & 7) << 4);
      bf16x8 bfr = *(const bf16x8*)((const char*)KV + baddr);
      #pragma unroll
      for (int m = 0; m < 3; ++m) {
        int prow = m * 16 + r16;
        int aaddr = ((prow << 10) | (kst << 6) | (kq << 4)) ^ ((prow & 7) << 4);
        bf16x8 afr2 = *(const bf16x8*)((const char*)P + aaddr);
        acc2[m] = __builtin_amdgcn_mfma_f32_16x16x32_bf16(afr2, bfr, acc2[m], 0, 0, 0);
      }
    }
    int d = wv * 16 + r16;
    #pragma unroll
    for (int m = 0; m < 3; ++m)
      #pragma unroll
      for (int r = 0; r < 4; ++r) {
        int u = m * 16 + kq * 4 + r;
        if (u < NSAMP) {
          size_t off = (size_t)bv * (SEQL * DMOD) + (size_t)topi[u] * DMOD + head * 64 + d;
          ctxb[off] = f2b(acc2[m][r]);
        }
      }
  }
}

// ---------------- residual add + layernorm (vectorized: 2 rows/block) ----------------
template<int BMODE, int OUT>
__global__ __launch_bounds__(256) void add_ln(const float* __restrict__ a,
                                              const unsigned short* __restrict__ b,
                                              const float* __restrict__ g,
                                              const float* __restrict__ be,
                                              float* __restrict__ out,
                                              unsigned short* __restrict__ outb,
                                              unsigned short* __restrict__ outh,
                                              unsigned short* __restrict__ outl) {
  int row = blockIdx.x * 2 + (threadIdx.x >> 7);
  int t = threadIdx.x & 127;
  int wave = threadIdx.x >> 6;
  int lane = threadIdx.x & 63;
  size_t base = (size_t)row * DMOD + t * 4;
  float4 x = *(const float4*)(a + base);
  if (BMODE == 2) {
    ushort4 r4 = *(const ushort4*)(b + base);
    x.x += b2f(r4.x); x.y += b2f(r4.y); x.z += b2f(r4.z); x.w += b2f(r4.w);
  }
  float s1 = x.x + x.y + x.z + x.w;
  float s2 = x.x * x.x + x.y * x.y + x.z * x.z + x.w * x.w;
  #pragma unroll
  for (int off = 32; off > 0; off >>= 1) {
    s1 += __shfl_xor(s1, off);
    s2 += __shfl_xor(s2, off);
  }
  __shared__ float sh[8];
  if (lane == 0) { sh[wave * 2] = s1; sh[wave * 2 + 1] = s2; }
  __syncthreads();
  int mate = wave ^ 1;
  s1 += sh[mate * 2];
  s2 += sh[mate * 2 + 1];
  float mu = s1 * (1.0f / 512.0f);
  float var = s2 * (1.0f / 512.0f) - mu * mu;
  float rstd = rsqrtf(var + 1e-5f);
  float4 gg = *(const float4*)(g + t * 4);
  float4 bb = *(const float4*)(be + t * 4);
  float4 o;
  o.x = (x.x - mu) * rstd * gg.x + bb.x;
  o.y = (x.y - mu) * rstd * gg.y + bb.y;
  o.z = (x.z - mu) * rstd * gg.z + bb.z;
  o.w = (x.w - mu) * rstd * gg.w + bb.w;
  *(float4*)(out + base) = o;
  if (OUT == 1) {
    ushort4 ob;
    ob.x = f2b(o.x); ob.y = f2b(o.y); ob.z = f2b(o.z); ob.w = f2b(o.w);
    *(ushort4*)(outb + base) = ob;
  }
  if (OUT == 2) {
    ushort4 hi4, lo4;
    hi4.x = f2b(o.x); lo4.x = f2b(o.x - b2f(hi4.x));
    hi4.y = f2b(o.y); lo4.y = f2b(o.y - b2f(hi4.y));
    hi4.z = f2b(o.z); lo4.z = f2b(o.z - b2f(hi4.z));
    hi4.w = f2b(o.w); lo4.w = f2b(o.w - b2f(hi4.w));
    *(ushort4*)(outh + base) = hi4;
    *(ushort4*)(outl + base) = lo4;
  }
}

// ---------------- head via MFMA: partial[blk*4+w][2688], K-chunk 512/block ----------------
__global__ __launch_bounds__(256) void head_partial_mfma(const unsigned short* __restrict__ hbf,
                                                         const float* __restrict__ Wh,
                                                         float* __restrict__ partial) {
  __shared__ __align__(16) unsigned short Hs[32 * 512];   // 32 KB
  __shared__ __align__(16) unsigned short Ws[96 * 512];   // 96 KB
  int blk = blockIdx.x;            // 0..511
  int k0 = blk * 512;
  int tid = threadIdx.x;
  int wv = tid >> 6, lane = tid & 63;
  int r16 = lane & 15, kq = lane >> 4;

  for (int c = tid; c < 32 * 64; c += 256) {
    int row = c >> 6, col8 = c & 63;
    int src = row < 28 ? row : 0;
    bf16x8 v = *(const bf16x8*)(hbf + (size_t)src * 262144 + k0 + col8 * 8);
    int byte = ((row << 10) | (col8 << 4)) ^ ((row & 7) << 4);
    *(bf16x8*)((char*)Hs + byte) = v;
  }
  for (int c = tid; c < 96 * 64; c += 256) {
    int row = c >> 6, col8 = c & 63;
    const float* src = Wh + (size_t)row * 262144 + k0 + col8 * 8;
    float4 va = *(const float4*)(src);
    float4 vb = *(const float4*)(src + 4);
    bf16x8 o8;
    o8[0] = (short)f2b(va.x); o8[1] = (short)f2b(va.y);
    o8[2] = (short)f2b(va.z); o8[3] = (short)f2b(va.w);
    o8[4] = (short)f2b(vb.x); o8[5] = (short)f2b(vb.y);
    o8[6] = (short)f2b(vb.z); o8[7] = (short)f2b(vb.w);
    int byte = ((row << 10) | (col8 << 4)) ^ ((row & 7) << 4);
    *(bf16x8*)((char*)Ws + byte) = o8;
  }
  __syncthreads();

  f32x4 acc[2][6];
  #pragma unroll
  for (int mt = 0; mt < 2; ++mt)
    #pragma unroll
    for (int nt = 0; nt < 6; ++nt) acc[mt][nt] = (f32x4){0.f, 0.f, 0.f, 0.f};

  #pragma unroll
  for (int kk = 0; kk < 4; ++kk) {
    int kfrag = wv * 4 + kk;     // k = kfrag*32 + kq*8
    bf16x8 afr[2];
    #pragma unroll
    for (int mt = 0; mt < 2; ++mt) {
      int row = mt * 16 + r16;
      int byte = ((row << 10) | (kfrag << 6) | (kq << 4)) ^ ((row & 7) << 4);
      afr[mt] = *(const bf16x8*)((const char*)Hs + byte);
    }
    #pragma unroll
    for (int nt = 0; nt < 6; ++nt) {
      int row = nt * 16 + r16;
      int byte = ((row << 10) | (kfrag << 6) | (kq << 4)) ^ ((row & 7) << 4);
      bf16x8 bfr = *(const bf16x8*)((const char*)Ws + byte);
      #pragma unroll
      for (int mt = 0; mt < 2; ++mt)
        acc[mt][nt] = __builtin_amdgcn_mfma_f32_16x16x32_bf16(afr[mt], bfr, acc[mt][nt], 0, 0, 0);
    }
  }
  size_t prow = (size_t)(blk * 4 + wv) * 2688;
  #pragma unroll
  for (int mt = 0; mt < 2; ++mt)
    #pragma unroll
    for (int nt = 0; nt < 6; ++nt)
      #pragma unroll
      for (int r = 0; r < 4; ++r) {
        int m = mt * 16 + kq * 4 + r;
        int n = nt * 16 + r16;
        if (m < 28) partial[prow + m * 96 + n] = acc[mt][nt][r];
      }
}

// ---------------- head reduce: 84 blocks x 1024 threads (coalesced + parallel) ----------------
__global__ __launch_bounds__(1024) void head_reduce(const float* __restrict__ partial,
                                                    const float* __restrict__ bh_,
                                                    float* __restrict__ out) {
  int blk = blockIdx.x;            // 0..83, columns blk*32..blk*32+31
  int o0 = blk * 32;
  int oo = threadIdx.x & 31;
  int rp = threadIdx.x >> 5;       // 0..31
  float s = 0.f;
  for (int r = rp; r < 2048; r += 32)
    s += partial[(size_t)r * 2688 + o0 + oo];
  __shared__ float red[1024];
  red[threadIdx.x] = s;
  __syncthreads();
  if (rp == 0) {
    float tot = 0.f;
    #pragma unroll
    for (int k = 0; k < 32; ++k) tot += red[k * 32 + oo];
    int o = o0 + oo;
    int m = o / 96, p = o % 96;
    int b = m / NVARS, v = m % NVARS;
    out[(size_t)b * (NPRED * NVARS) + (size_t)p * NVARS + v] = tot + bh_[p];
  }
}

extern "C" void kernel_launch(void* const* d_in, const int* in_sizes, int n_in,
                              void* d_out, int out_size, void* d_ws, size_t ws_size,
                              hipStream_t stream) {
  const float* x_enc = (const float*)d_in[0];
  const float* w_emb = (const float*)d_in[1];
  const float* b_emb = (const float*)d_in[2];
  const float* w_pos = (const float*)d_in[3];
  const float* Wq = (const float*)d_in[4];
  const float* bq = (const float*)d_in[5];
  const float* Wk = (const float*)d_in[6];
  const float* bk = (const float*)d_in[7];
  const float* Wv = (const float*)d_in[8];
  const float* bv_ = (const float*)d_in[9];
  const float* Wo = (const float*)d_in[10];
  const float* bo = (const float*)d_in[11];
  const float* W1 = (const float*)d_in[12];
  const float* b1 = (const float*)d_in[13];
  const float* W2 = (const float*)d_in[14];
  const float* b2 = (const float*)d_in[15];
  const float* g1 = (const float*)d_in[16];
  const float* be1 = (const float*)d_in[17];
  const float* g2 = (const float*)d_in[18];
  const float* be2 = (const float*)d_in[19];
  const float* gF = (const float*)d_in[20];
  const float* bF = (const float*)d_in[21];
  const float* Wh = (const float*)d_in[22];
  const float* bh_ = (const float*)d_in[23];
  float* out = (float*)d_out;

  const size_t S = (size_t)SBIG;
  const size_t SB = S * 4;                    // 29,360,128 B
  char* ws = (char*)d_ws;
  float* h    = (float*)(ws);                 // [0, SB)
  float* QKb  = (float*)(ws + SB);            // [SB, 3SB): [14336][1024] fp32
  unsigned short* Vb   = (unsigned short*)(ws + 3 * SB);            // 14.7 MB
  unsigned short* Ob_b = (unsigned short*)(ws + 3 * SB + SB / 2);   // 14.7 MB
  // weight scratch region [4SB, 5SB)
  unsigned short* Wqk_hi = (unsigned short*)(ws + 4 * SB);                  // 1 MB
  unsigned short* Wqk_lo = (unsigned short*)(ws + 4 * SB + 0x100000);       // 1 MB
  unsigned short* Wv_b = (unsigned short*)(ws + 4 * SB + 0x200000);         // 0.5 MB
  unsigned short* Wo_b = (unsigned short*)(ws + 4 * SB + 0x280000);         // 0.5 MB
  unsigned short* W1_b = (unsigned short*)(ws + 4 * SB + 0x300000);         // 2 MB
  unsigned short* W2_b = (unsigned short*)(ws + 4 * SB + 0x500000);         // 2 MB
  unsigned short* h_hi = (unsigned short*)(ws + 5 * SB);           // SB/2
  unsigned short* h_lo = (unsigned short*)(ws + 5 * SB + SB / 2);  // SB/2
  // phase aliases:
  unsigned short* CTXb = h_hi;                 // after QK+V gemms consumed h_hi
  unsigned short* h_bf = h_lo;                 // after QK gemm consumed h_lo
  unsigned short* FFNb = (unsigned short*)QKb; // after attn consumed QK
  float* partial = QKb;                        // head phase (22 MB <= 2SB)
  int*   idx = (int*)(ws + 6 * SB);                        // 70KB (transposed)
  float* vpart = (float*)(ws + 6 * SB + 0x20000);          // 448KB (224*512 f)
  int*   top = (int*)(ws + 6 * SB + 0xA0000);              // 31KB
  if (ws_size < 6 * SB + 0xC0000) return;

  dim3 b256(256);
  int gVec = (int)(S / 4 / 256);   // 7168

  embed_kernel<<<gVec, b256, 0, stream>>>(x_enc, w_emb, b_emb, w_pos, h, h_hi, h_lo);

  for (int l = 0; l < 2; ++l) {
    const float* Wql = Wq + (size_t)l * DMOD * DMOD;
    const float* Wkl = Wk + (size_t)l * DMOD * DMOD;
    const float* Wvl = Wv + (size_t)l * DMOD * DMOD;
    const float* Wol = Wo + (size_t)l * DMOD * DMOD;
    const float* W1l = W1 + (size_t)l * DFFN * DMOD;
    const float* W2l = W2 + (size_t)l * DMOD * DFFN;

    prep_weights<<<3072, b256, 0, stream>>>(Wql, Wkl, Wvl, Wol, W1l, W2l,
                                            Wqk_hi, Wqk_lo, Wv_b, Wo_b, W1_b, W2_b);

    dim3 gqk(QKS / 128, NROWS / 128);
    gemm_mfma3<<<gqk, b256, 0, stream>>>(h_hi, h_lo, Wqk_hi, Wqk_lo,
                                         bq + l * DMOD, bk + l * DMOD,
                                         QKb, NROWS, QKS, DMOD, QKS);
    dim3 gv(DMOD / 128, NROWS / 128);
    gemm_mfma<0, 1><<<gv, b256, 0, stream>>>(h_hi, Wv_b, bv_ + l * DMOD,
                                             (float*)0, Vb, NROWS, DMOD, DMOD);

    make_idx_kernel<<<(SEQL * NSAMP + 255) / 256, b256, 0, stream>>>(l, idx);
    m2_topk_kernel<<<NBH, dim3(512), 0, stream>>>(QKb, idx, top);
    vmean_part_kernel<<<NBV * 8, b256, 0, stream>>>(Vb, vpart);
    ctx_fill_kernel<<<gVec, b256, 0, stream>>>(vpart, CTXb);
    attn2_kernel<<<NBH, b256, 0, stream>>>(QKb, Vb, top, CTXb);

    dim3 go(DMOD / 128, NROWS / 128);
    gemm_mfma<0, 1><<<go, b256, 0, stream>>>(CTXb, Wo_b, bo + l * DMOD,
                                             (float*)0, Ob_b, NROWS, DMOD, DMOD);
    add_ln<2, 1><<<NROWS / 2, b256, 0, stream>>>(h, Ob_b, g1 + l * DMOD, be1 + l * DMOD,
                                                 h, h_bf, (unsigned short*)0, (unsigned short*)0);

    dim3 gf1(DFFN / 128, NROWS / 128);
    gemm_mfma<1, 1><<<gf1, b256, 0, stream>>>(h_bf, W1_b, b1 + l * DFFN,
                                              (float*)0, FFNb, NROWS, DFFN, DMOD);
    dim3 gf2(DMOD / 128, NROWS / 128);
    gemm_mfma<0, 1><<<gf2, b256, 0, stream>>>(FFNb, W2_b, b2 + l * DMOD,
                                              (float*)0, Ob_b, NROWS, DMOD, DFFN);
    if (l == 0) {
      add_ln<2, 2><<<NROWS / 2, b256, 0, stream>>>(h, Ob_b, g2 + l * DMOD, be2 + l * DMOD,
                                                   h, (unsigned short*)0, h_hi, h_lo);
    } else {
      add_ln<2, 0><<<NROWS / 2, b256, 0, stream>>>(h, Ob_b, g2 + l * DMOD, be2 + l * DMOD,
                                                   h, (unsigned short*)0, (unsigned short*)0, (unsigned short*)0);
    }
  }

  add_ln<0, 1><<<NROWS / 2, b256, 0, stream>>>(h, (const unsigned short*)0, gF, bF,
                                               h, h_bf, (unsigned short*)0, (unsigned short*)0);
  head_partial_mfma<<<512, b256, 0, stream>>>(h_bf, Wh, partial);
  head_reduce<<<84, dim3(1024), 0, stream>>>(partial, bh_, out);
}

// Round 16
// 670.754 us; speedup vs baseline: 1.5211x; 1.0091x over previous
//
#include <hip/hip_runtime.h>
#include <math.h>

#define SEQL 512
#define DMOD 512
#define NHEAD 8
#define DHEAD 64
#define DFFN 2048
#define NBATCH 4
#define NVARS 7
#define NBV 28          // NBATCH*NVARS
#define NBH 224         // NBV*NHEAD
#define NROWS 14336     // NBV*SEQL
#define NSAMP 35        // U_part = u = 35
#define NPRED 96
#define SBIG 7340032    // NBV*SEQL*DMOD floats
#define QKS 1024        // fused QK row stride

typedef short bf16x8 __attribute__((ext_vector_type(8)));
typedef float f32x4 __attribute__((ext_vector_type(4)));

#define GLDS(gptr, lptr) \
  __builtin_amdgcn_global_load_lds((const __attribute__((address_space(1))) void*)(gptr), \
                                   (__attribute__((address_space(3))) void*)(lptr), 16, 0, 0)

__device__ inline unsigned short f2b(float f) {
  unsigned u = __builtin_bit_cast(unsigned, f);
  unsigned r = (u + 0x7FFFu + ((u >> 16) & 1u)) >> 16;
  return (unsigned short)r;
}
__device__ inline float b2f(unsigned short h) {
  return __builtin_bit_cast(float, (unsigned)h << 16);
}

// ---------------- threefry2x32 (matches jax._src.prng) ----------------
__device__ inline void threefry2x32(unsigned k0, unsigned k1,
                                    unsigned x0, unsigned x1,
                                    unsigned &o0, unsigned &o1) {
  unsigned ks2 = k0 ^ k1 ^ 0x1BD11BDAu;
  unsigned ks[3] = {k0, k1, ks2};
  x0 += k0; x1 += k1;
  const unsigned rot[2][4] = {{13u,15u,26u,6u},{17u,29u,16u,24u}};
  #pragma unroll
  for (int i = 0; i < 5; ++i) {
    #pragma unroll
    for (int j = 0; j < 4; ++j) {
      unsigned r = rot[i & 1][j];
      x0 += x1;
      x1 = (x1 << r) | (x1 >> (32u - r));
      x1 ^= x0;
    }
    x0 += ks[(i + 1) % 3];
    x1 += ks[(i + 2) % 3] + (unsigned)(i + 1);
  }
  o0 = x0; o1 = x1;
}

// writes TRANSPOSED layout idx_t[u*512 + q]
__global__ void make_idx_kernel(int layer, int* idx_t) {
  int i = blockIdx.x * 256 + threadIdx.x;
  if (i >= SEQL * NSAMP) return;
  unsigned kl0, kl1, o0, o1;
  threefry2x32(0u, 42u, 0u, (unsigned)layer, kl0, kl1);
  threefry2x32(kl0, kl1, (unsigned)i, (unsigned)(SEQL * NSAMP + i), o0, o1);
  int q = i / NSAMP, u = i % NSAMP;
  idx_t[u * SEQL + q] = (int)(o1 & 511u);
}

// ---------------- embedding (vectorized, fused hi/lo split) ----------------
__global__ void embed_kernel(const float* __restrict__ x_enc,
                             const float* __restrict__ w_emb,
                             const float* __restrict__ b_emb,
                             const float* __restrict__ w_pos,
                             float* __restrict__ h,
                             unsigned short* __restrict__ h_hi,
                             unsigned short* __restrict__ h_lo) {
  size_t i = (size_t)blockIdx.x * 256 + threadIdx.x;
  if (i >= (size_t)(SBIG / 4)) return;
  size_t e = i * 4;
  int dm = (int)(e & 511);
  int l  = (int)((e >> 9) & 511);
  int bv = (int)(e >> 18);
  int b = bv / NVARS, v = bv % NVARS;
  float xs = x_enc[((size_t)b * SEQL + l) * NVARS + v];
  float4 we = *(const float4*)(w_emb + dm);
  float4 bb = *(const float4*)(b_emb + dm);
  float4 wp = *(const float4*)(w_pos + (size_t)l * DMOD + dm);
  float4 val;
  val.x = xs * we.x + bb.x + wp.x;
  val.y = xs * we.y + bb.y + wp.y;
  val.z = xs * we.z + bb.z + wp.z;
  val.w = xs * we.w + bb.w + wp.w;
  *(float4*)(h + e) = val;
  ushort4 hi4, lo4;
  hi4.x = f2b(val.x); lo4.x = f2b(val.x - b2f(hi4.x));
  hi4.y = f2b(val.y); lo4.y = f2b(val.y - b2f(hi4.y));
  hi4.z = f2b(val.z); lo4.z = f2b(val.z - b2f(hi4.z));
  hi4.w = f2b(val.w); lo4.w = f2b(val.w - b2f(hi4.w));
  *(ushort4*)(h_hi + e) = hi4;
  *(ushort4*)(h_lo + e) = lo4;
}

// ---------------- fused per-layer weight prep (one dispatch) ----------------
__global__ void prep_weights(const float* __restrict__ Wq, const float* __restrict__ Wk,
                             const float* __restrict__ Wv, const float* __restrict__ Wo,
                             const float* __restrict__ W1, const float* __restrict__ W2,
                             unsigned short* __restrict__ Wqk_hi, unsigned short* __restrict__ Wqk_lo,
                             unsigned short* __restrict__ Wv_b, unsigned short* __restrict__ Wo_b,
                             unsigned short* __restrict__ W1_b, unsigned short* __restrict__ W2_b) {
  const int Q4 = 65536;   // 262144/4
  int g = blockIdx.x * 256 + threadIdx.x;
  if (g < 2 * Q4) {
    const float* src = g < Q4 ? Wq : Wk;
    unsigned short* hi = Wqk_hi + (g < Q4 ? 0 : DMOD * DMOD);
    unsigned short* lo = Wqk_lo + (g < Q4 ? 0 : DMOD * DMOD);
    int off = (g < Q4 ? g : g - Q4) * 4;
    float4 v = *(const float4*)(src + off);
    ushort4 h4, l4;
    h4.x = f2b(v.x); l4.x = f2b(v.x - b2f(h4.x));
    h4.y = f2b(v.y); l4.y = f2b(v.y - b2f(h4.y));
    h4.z = f2b(v.z); l4.z = f2b(v.z - b2f(h4.z));
    h4.w = f2b(v.w); l4.w = f2b(v.w - b2f(h4.w));
    *(ushort4*)(hi + off) = h4;
    *(ushort4*)(lo + off) = l4;
    return;
  }
  const float* src;
  unsigned short* dst;
  int off;
  if (g < 3 * Q4)      { src = Wv; dst = Wv_b; off = (g - 2 * Q4) * 4; }
  else if (g < 4 * Q4) { src = Wo; dst = Wo_b; off = (g - 3 * Q4) * 4; }
  else if (g < 4 * Q4 + 262144) { src = W1; dst = W1_b; off = (g - 4 * Q4) * 4; }
  else                 { src = W2; dst = W2_b; off = (g - 4 * Q4 - 262144) * 4; }
  float4 v = *(const float4*)(src + off);
  ushort4 o;
  o.x = f2b(v.x); o.y = f2b(v.y); o.z = f2b(v.z); o.w = f2b(v.w);
  *(ushort4*)(dst + off) = o;
}

// ---------------- split-bf16 MFMA GEMM (3-pass hi/lo): C = A@W^T + [bq|bk] ----------------
__global__ __launch_bounds__(256) void gemm_mfma3(const unsigned short* __restrict__ Ah,
                                                  const unsigned short* __restrict__ Al,
                                                  const unsigned short* __restrict__ Bh,
                                                  const unsigned short* __restrict__ Bl,
                                                  const float* __restrict__ bq,
                                                  const float* __restrict__ bk,
                                                  float* __restrict__ C,
                                                  int M, int N, int K, int ldc) {
  __shared__ __align__(16) unsigned short AsH[128 * 64];
  __shared__ __align__(16) unsigned short AsL[128 * 64];
  __shared__ __align__(16) unsigned short BsH[128 * 64];
  __shared__ __align__(16) unsigned short BsL[128 * 64];
  int nwg = gridDim.x * gridDim.y;
  int flat = blockIdx.y * gridDim.x + blockIdx.x;
  int swz = (flat & 7) * (nwg >> 3) + (flat >> 3);
  int bxs = swz % gridDim.x, bys = swz / gridDim.x;
  int bm = bys * 128, bn = bxs * 128;
  int tid = threadIdx.x;
  int wave = tid >> 6, lane = tid & 63;
  int wr = wave >> 1, wc = wave & 1;
  int r16 = lane & 15, kq = lane >> 4;

  f32x4 acc[4][4];
  #pragma unroll
  for (int i = 0; i < 4; ++i)
    #pragma unroll
    for (int j = 0; j < 4; ++j) acc[i][j] = (f32x4){0.f, 0.f, 0.f, 0.f};

  for (int kt = 0; kt < K; kt += 64) {
    __syncthreads();
    #pragma unroll
    for (int i = 0; i < 4; ++i) {
      int c = i * 256 + tid;
      int row = c >> 3, kb = c & 7;
      int kbs = kb ^ (row & 7);             // pre-swizzled source
      size_t offA = (size_t)(bm + row) * K + kt + kbs * 8;
      size_t offB = (size_t)(bn + row) * K + kt + kbs * 8;
      int ldst = (i * 256 + (tid & 192)) << 4;   // wave-uniform linear dest
      GLDS(Ah + offA, (char*)AsH + ldst);
      GLDS(Al + offA, (char*)AsL + ldst);
      GLDS(Bh + offB, (char*)BsH + ldst);
      GLDS(Bl + offB, (char*)BsL + ldst);
    }
    __syncthreads();
    #pragma unroll
    for (int ks = 0; ks < 2; ++ks) {
      bf16x8 ah[4], al[4], bh[4], bl[4];
      #pragma unroll
      for (int mi = 0; mi < 4; ++mi) {
        int row = wr * 64 + mi * 16 + r16;
        int addr = ((row << 7) | (ks << 6) | (kq << 4)) ^ ((row & 7) << 4);
        ah[mi] = *(const bf16x8*)((const char*)AsH + addr);
        al[mi] = *(const bf16x8*)((const char*)AsL + addr);
      }
      #pragma unroll
      for (int ni = 0; ni < 4; ++ni) {
        int row = wc * 64 + ni * 16 + r16;
        int addr = ((row << 7) | (ks << 6) | (kq << 4)) ^ ((row & 7) << 4);
        bh[ni] = *(const bf16x8*)((const char*)BsH + addr);
        bl[ni] = *(const bf16x8*)((const char*)BsL + addr);
      }
      #pragma unroll
      for (int mi = 0; mi < 4; ++mi)
        #pragma unroll
        for (int ni = 0; ni < 4; ++ni) {
          acc[mi][ni] = __builtin_amdgcn_mfma_f32_16x16x32_bf16(ah[mi], bh[ni], acc[mi][ni], 0, 0, 0);
          acc[mi][ni] = __builtin_amdgcn_mfma_f32_16x16x32_bf16(ah[mi], bl[ni], acc[mi][ni], 0, 0, 0);
          acc[mi][ni] = __builtin_amdgcn_mfma_f32_16x16x32_bf16(al[mi], bh[ni], acc[mi][ni], 0, 0, 0);
        }
    }
  }
  int crow0 = bm + wr * 64 + (lane >> 4) * 4;
  int ccol0 = bn + wc * 64 + (lane & 15);
  #pragma unroll
  for (int mi = 0; mi < 4; ++mi) {
    #pragma unroll
    for (int ni = 0; ni < 4; ++ni) {
      int col = ccol0 + ni * 16;
      float bvv = col < 512 ? bq[col] : bk[col - 512];
      #pragma unroll
      for (int r = 0; r < 4; ++r) {
        int row = crow0 + mi * 16 + r;
        C[(size_t)row * ldc + col] = acc[mi][ni][r] + bvv;
      }
    }
  }
}

// ---------------- bf16 MFMA GEMM, 2-phase double-buffered LDS ----------------
template<int ACT, int OUTBF>
__global__ __launch_bounds__(256) void gemm_mfma(const unsigned short* __restrict__ A,
                                                 const unsigned short* __restrict__ W,
                                                 const float* __restrict__ bias,
                                                 float* __restrict__ Cf,
                                                 unsigned short* __restrict__ Cb,
                                                 int M, int N, int K) {
  __shared__ __align__(16) unsigned short As[2][128 * 64];   // 16 KB x2
  __shared__ __align__(16) unsigned short Bs[2][128 * 64];   // 16 KB x2
  int nwg = gridDim.x * gridDim.y;
  int flat = blockIdx.y * gridDim.x + blockIdx.x;
  int swz = (flat & 7) * (nwg >> 3) + (flat >> 3);
  int bxs = swz % gridDim.x, bys = swz / gridDim.x;
  int bm = bys * 128, bn = bxs * 128;
  int tid = threadIdx.x;
  int wave = tid >> 6, lane = tid & 63;
  int wr = wave >> 1, wc = wave & 1;
  int r16 = lane & 15, kq = lane >> 4;

  f32x4 acc[4][4];
  #pragma unroll
  for (int i = 0; i < 4; ++i)
    #pragma unroll
    for (int j = 0; j < 4; ++j) acc[i][j] = (f32x4){0.f, 0.f, 0.f, 0.f};

#define STAGE_MM(buf, ktv) \
  { \
    for (int i_ = 0; i_ < 4; ++i_) { \
      int c_ = i_ * 256 + tid; \
      int row_ = c_ >> 3, kb_ = c_ & 7; \
      int kbs_ = kb_ ^ (row_ & 7); \
      size_t offA_ = (size_t)(bm + row_) * K + (ktv) + kbs_ * 8; \
      size_t offB_ = (size_t)(bn + row_) * K + (ktv) + kbs_ * 8; \
      int ldst_ = (i_ * 256 + (tid & 192)) << 4; \
      GLDS(A + offA_, (char*)As[buf] + ldst_); \
      GLDS(W + offB_, (char*)Bs[buf] + ldst_); \
    } \
  }

  int nkt = K >> 6;
  STAGE_MM(0, 0);
  __syncthreads();                 // compiler drains vmcnt before barrier
  for (int t = 0; t < nkt; ++t) {
    int cur = t & 1;
    if (t + 1 < nkt) STAGE_MM(cur ^ 1, (t + 1) << 6);
    const char* Ab = (const char*)As[cur];
    const char* Bb = (const char*)Bs[cur];
    #pragma unroll
    for (int ks = 0; ks < 2; ++ks) {
      bf16x8 afr[4], bfr[4];
      #pragma unroll
      for (int mi = 0; mi < 4; ++mi) {
        int row = wr * 64 + mi * 16 + r16;
        int addr = ((row << 7) | (ks << 6) | (kq << 4)) ^ ((row & 7) << 4);
        afr[mi] = *(const bf16x8*)(Ab + addr);
      }
      #pragma unroll
      for (int ni = 0; ni < 4; ++ni) {
        int row = wc * 64 + ni * 16 + r16;
        int addr = ((row << 7) | (ks << 6) | (kq << 4)) ^ ((row & 7) << 4);
        bfr[ni] = *(const bf16x8*)(Bb + addr);
      }
      #pragma unroll
      for (int mi = 0; mi < 4; ++mi)
        #pragma unroll
        for (int ni = 0; ni < 4; ++ni)
          acc[mi][ni] = __builtin_amdgcn_mfma_f32_16x16x32_bf16(afr[mi], bfr[ni], acc[mi][ni], 0, 0, 0);
    }
    __syncthreads();               // drains the in-flight next-buf GLDS too
  }
#undef STAGE_MM

  int crow0 = bm + wr * 64 + (lane >> 4) * 4;
  int ccol0 = bn + wc * 64 + (lane & 15);
  #pragma unroll
  for (int mi = 0; mi < 4; ++mi) {
    #pragma unroll
    for (int ni = 0; ni < 4; ++ni) {
      int col = ccol0 + ni * 16;
      float bvv = bias[col];
      #pragma unroll
      for (int r = 0; r < 4; ++r) {
        int row = crow0 + mi * 16 + r;
        float v = acc[mi][ni][r] + bvv;
        if (ACT) {
          // gelu(tanh approx) = x * sigmoid(2*0.79788456(x+0.044715x^3))
          float x = v;
          float u = x * __builtin_fmaf(0.044715f * x, x, 1.0f);
          float tme = __expf(-1.5957691216057308f * u);
          v = x * __builtin_amdgcn_rcpf(1.0f + tme);
        }
        if (OUTBF) Cb[(size_t)row * N + col] = f2b(v);
        else       Cf[(size_t)row * N + col] = v;
      }
    }
  }
}

// ---------------- M measure + barrier-free in-wave top-k: block per (bh) ----------------
__global__ __launch_bounds__(512) void m2_topk_kernel(const float* __restrict__ QK,
                                                      const int* __restrict__ idx_t,
                                                      int* __restrict__ top) {
  int bh = blockIdx.x;
  int bv = bh >> 3, head = bh & 7;
  int tid = threadIdx.x;                 // 0..511, one q-row each
  int lane = tid & 63, wv8 = tid >> 6;
  __shared__ float Ks[512 * 64];         // 128 KB, word(l,db) = l*64 + ((db^(l&15))<<2)
  const float* base = QK + (size_t)bv * (SEQL * QKS);
  for (int c = tid; c < 512 * 16; c += 512) {
    int l = c >> 4, db = c & 15;
    float4 v = *(const float4*)(base + (size_t)l * QKS + 512 + head * 64 + db * 4);
    *(float4*)(Ks + l * 64 + ((db ^ (l & 15)) << 2)) = v;
  }
  float q[64];
  const float* qp = base + (size_t)tid * QKS + head * 64;
  #pragma unroll
  for (int d4 = 0; d4 < 64; d4 += 4) {
    float4 qv = *(const float4*)(qp + d4);
    q[d4 + 0] = qv.x; q[d4 + 1] = qv.y; q[d4 + 2] = qv.z; q[d4 + 3] = qv.w;
  }
  __syncthreads();
  float mx = -INFINITY, sm = 0.f;
  #pragma unroll 2
  for (int u = 0; u < NSAMP; ++u) {
    int kidx = idx_t[u * SEQL + tid];   // coalesced
    const float* kr = Ks + kidx * 64;
    int x = kidx & 15;
    float s = 0.f;
    #pragma unroll
    for (int db = 0; db < 16; ++db) {
      float4 kv = *(const float4*)(kr + ((db ^ x) << 2));
      s += q[db * 4 + 0] * kv.x + q[db * 4 + 1] * kv.y
         + q[db * 4 + 2] * kv.z + q[db * 4 + 3] * kv.w;
    }
    mx = fmaxf(mx, s);
    sm += s;
  }
  float Mval = mx - sm * (1.0f / 512.0f);
  __syncthreads();                       // all Ks reads done; reuse LDS
  float* vals = Ks;                      // [512]
  vals[tid] = Mval;
  __syncthreads();
  if (wv8 == 0) {
    // wave 0 holds all 512 M-values: lane holds slots {lane, lane+64, ...}
    float v[8];
    #pragma unroll
    for (int s = 0; s < 8; ++s) v[s] = vals[lane + s * 64];
    int* tp = top + bh * NSAMP;
    for (int t = 0; t < NSAMP; ++t) {
      // local argmax over 8 slots (ascending index, strict > keeps smallest)
      float bvv = v[0]; int bs = 0;
      #pragma unroll
      for (int s = 1; s < 8; ++s)
        if (v[s] > bvv) { bvv = v[s]; bs = s; }
      int bi = lane + bs * 64;
      // wave argmax, tie -> smaller index
      #pragma unroll
      for (int off = 32; off > 0; off >>= 1) {
        float ov = __shfl_xor(bvv, off);
        int oi = __shfl_xor(bi, off);
        if (ov > bvv || (ov == bvv && oi < bi)) { bvv = ov; bi = oi; }
      }
      if (lane == 0) tp[t] = bi;
      // invalidate winner (static register indexing)
      int bslot = bi >> 6, blane = bi & 63;
      #pragma unroll
      for (int s = 0; s < 8; ++s)
        if (s == bslot && lane == blane) v[s] = -INFINITY;
    }
  }
}

// ---------------- mean of V partials: block per (bv, rowgroup of 64) ----------------
__global__ __launch_bounds__(256) void vmean_part_kernel(const unsigned short* __restrict__ Vb,
                                                         float* __restrict__ part) {
  int blk = blockIdx.x;                // 0..223 = bv*8+g
  int bv = blk >> 3, grp = blk & 7;
  int t = threadIdx.x;                 // cols 2t, 2t+1
  const unsigned short* vb = Vb + (size_t)bv * (SEQL * DMOD) + (size_t)grp * 64 * DMOD + t * 2;
  float s0 = 0.f, s1 = 0.f;
  #pragma unroll 4
  for (int l = 0; l < 64; ++l) {
    unsigned u = *(const unsigned*)(vb + (size_t)l * DMOD);
    s0 += b2f((unsigned short)(u & 0xffffu));
    s1 += b2f((unsigned short)(u >> 16));
  }
  part[(size_t)blk * DMOD + t * 2]     = s0;
  part[(size_t)blk * DMOD + t * 2 + 1] = s1;
}

// ---------------- ctx = broadcast vmean (sums 8 partials, bf16 out) ----------------
__global__ void ctx_fill_kernel(const float* __restrict__ part,
                                unsigned short* __restrict__ ctxb) {
  size_t i = (size_t)blockIdx.x * 256 + threadIdx.x;
  if (i >= (size_t)(SBIG / 4)) return;
  size_t e = i * 4;
  int dm = (int)(e & 511);
  int bv = (int)(e >> 18);
  float4 vm = {0.f, 0.f, 0.f, 0.f};
  #pragma unroll
  for (int g = 0; g < 8; ++g) {
    float4 p = *(const float4*)(part + (size_t)(bv * 8 + g) * DMOD + dm);
    vm.x += p.x; vm.y += p.y; vm.z += p.z; vm.w += p.w;
  }
  const float inv = 1.0f / 512.0f;
  ushort4 o;
  o.x = f2b(vm.x * inv); o.y = f2b(vm.y * inv);
  o.z = f2b(vm.z * inv); o.w = f2b(vm.w * inv);
  *(ushort4*)(ctxb + e) = o;
}

// ---------------- MFMA attention for selected queries: block per (bh) ----------------
__global__ __launch_bounds__(256) void attn2_kernel(const float* __restrict__ QK,
                                                    const unsigned short* __restrict__ Vb,
                                                    const int* __restrict__ top,
                                                    unsigned short* __restrict__ ctxb) {
  __shared__ __align__(16) unsigned short KV[512 * 64];
  __shared__ __align__(16) unsigned short P[48 * 512];
  __shared__ __align__(16) unsigned short Qs[48 * 64];
  __shared__ int topi[NSAMP];
  int bh = blockIdx.x;
  int bv = bh >> 3, head = bh & 7;
  int tid = threadIdx.x;
  int wv = tid >> 6, lane = tid & 63;
  int r16 = lane & 15, kq = lane >> 4;
  const float* base = QK + (size_t)bv * (SEQL * QKS);
  const unsigned short* vbase = Vb + (size_t)bv * (SEQL * DMOD) + head * 64;

  if (tid < NSAMP) topi[tid] = top[bh * NSAMP + tid];
  __syncthreads();

  for (int c = tid; c < NSAMP * 16; c += 256) {
    int u = c >> 4, dq = c & 15;
    float4 q4 = *(const float4*)(base + (size_t)topi[u] * QKS + head * 64 + dq * 4);
    ushort4 o;
    o.x = f2b(q4.x * 0.125f); o.y = f2b(q4.y * 0.125f);
    o.z = f2b(q4.z * 0.125f); o.w = f2b(q4.w * 0.125f);
    int byte = ((u << 7) | (dq << 3)) ^ ((u & 7) << 4);
    *(ushort4*)((char*)Qs + byte) = o;
  }
  for (int c = tid; c < 512 * 16; c += 256) {
    int l = c >> 4, dq = c & 15;
    float4 k4 = *(const float4*)(base + (size_t)l * QKS + 512 + head * 64 + dq * 4);
    ushort4 o;
    o.x = f2b(k4.x); o.y = f2b(k4.y); o.z = f2b(k4.z); o.w = f2b(k4.w);
    int byte = ((l << 7) | (dq << 3)) ^ ((l & 7) << 4);
    *(ushort4*)((char*)KV + byte) = o;
  }
  __syncthreads();

  // QK^T: scores[48][512]
  {
    f32x4 acc[3][8];
    #pragma unroll
    for (int m = 0; m < 3; ++m)
      #pragma unroll
      for (int j = 0; j < 8; ++j) acc[m][j] = (f32x4){0.f, 0.f, 0.f, 0.f};
    bf16x8 afr[3][2];
    #pragma unroll
    for (int m = 0; m < 3; ++m)
      #pragma unroll
      for (int ks = 0; ks < 2; ++ks) {
        int row = m * 16 + r16;
        int addr = ((row << 7) | (ks << 6) | (kq << 4)) ^ ((row & 7) << 4);
        afr[m][ks] = *(const bf16x8*)((const char*)Qs + addr);
      }
    #pragma unroll
    for (int j = 0; j < 8; ++j) {
      int nrow = (wv * 8 + j) * 16 + r16;
      #pragma unroll
      for (int ks = 0; ks < 2; ++ks) {
        int addr = ((nrow << 7) | (ks << 6) | (kq << 4)) ^ ((nrow & 7) << 4);
        bf16x8 bfr = *(const bf16x8*)((const char*)KV + addr);
        #pragma unroll
        for (int m = 0; m < 3; ++m)
          acc[m][j] = __builtin_amdgcn_mfma_f32_16x16x32_bf16(afr[m][ks], bfr, acc[m][j], 0, 0, 0);
      }
    }
    #pragma unroll
    for (int m = 0; m < 3; ++m)
      #pragma unroll
      for (int j = 0; j < 8; ++j) {
        int l = (wv * 8 + j) * 16 + r16;
        #pragma unroll
        for (int r = 0; r < 4; ++r) {
          int u = m * 16 + kq * 4 + r;
          int byte = ((u << 10) | (l << 1)) ^ ((u & 7) << 4);
          *(unsigned short*)((char*)P + byte) = f2b(acc[m][j][r]);
        }
      }
  }
  __syncthreads();

  // stage V^T into KV region (K dead) from bf16 V
  for (int c = tid; c < 512 * 8; c += 256) {
    int l = c >> 3, dq = c & 7;
    bf16x8 v8 = *(const bf16x8*)(vbase + (size_t)l * DMOD + dq * 8);
    #pragma unroll
    for (int j = 0; j < 8; ++j) {
      int d = dq * 8 + j;
      int byte = ((d << 10) | (l << 1)) ^ ((d & 7) << 4);
      *(unsigned short*)((char*)KV + byte) = (unsigned short)v8[j];
    }
  }
  // softmax on P rows
  for (int u = wv; u < NSAMP; u += 4) {
    int byte = ((u << 10) | (lane << 4)) ^ ((u & 7) << 4);
    bf16x8 sv = *(const bf16x8*)((const char*)P + byte);
    float s[8];
    #pragma unroll
    for (int j = 0; j < 8; ++j) s[j] = b2f((unsigned short)sv[j]);
    float mx = s[0];
    #pragma unroll
    for (int j = 1; j < 8; ++j) mx = fmaxf(mx, s[j]);
    #pragma unroll
    for (int off = 32; off > 0; off >>= 1) mx = fmaxf(mx, __shfl_xor(mx, off));
    float e[8], sm = 0.f;
    #pragma unroll
    for (int j = 0; j < 8; ++j) { e[j] = __expf(s[j] - mx); sm += e[j]; }
    #pragma unroll
    for (int off = 32; off > 0; off >>= 1) sm += __shfl_xor(sm, off);
    float inv = 1.0f / sm;
    bf16x8 pv;
    #pragma unroll
    for (int j = 0; j < 8; ++j) pv[j] = (short)f2b(e[j] * inv);
    *(bf16x8*)((char*)P + byte) = pv;
  }
  __syncthreads();

  // PV: ctx[48][64] = P @ V
  {
    f32x4 acc2[3];
    #pragma unroll
    for (int m = 0; m < 3; ++m) acc2[m] = (f32x4){0.f, 0.f, 0.f, 0.f};
    for (int kst = 0; kst < 16; ++kst) {
      int vrow = wv * 16 + r16;
      int baddr = ((vrow << 10) | (kst << 6) | (kq << 4)) ^ ((vrow & 7) << 4);
      bf16x8 bfr = *(const bf16x8*)((const char*)KV + baddr);
      #pragma unroll
      for (int m = 0; m < 3; ++m) {
        int prow = m * 16 + r16;
        int aaddr = ((prow << 10) | (kst << 6) | (kq << 4)) ^ ((prow & 7) << 4);
        bf16x8 afr2 = *(const bf16x8*)((const char*)P + aaddr);
        acc2[m] = __builtin_amdgcn_mfma_f32_16x16x32_bf16(afr2, bfr, acc2[m], 0, 0, 0);
      }
    }
    int d = wv * 16 + r16;
    #pragma unroll
    for (int m = 0; m < 3; ++m)
      #pragma unroll
      for (int r = 0; r < 4; ++r) {
        int u = m * 16 + kq * 4 + r;
        if (u < NSAMP) {
          size_t off = (size_t)bv * (SEQL * DMOD) + (size_t)topi[u] * DMOD + head * 64 + d;
          ctxb[off] = f2b(acc2[m][r]);
        }
      }
  }
}

// ---------------- residual add + layernorm (vectorized: 2 rows/block) ----------------
template<int BMODE, int OUT>
__global__ __launch_bounds__(256) void add_ln(const float* __restrict__ a,
                                              const unsigned short* __restrict__ b,
                                              const float* __restrict__ g,
                                              const float* __restrict__ be,
                                              float* __restrict__ out,
                                              unsigned short* __restrict__ outb,
                                              unsigned short* __restrict__ outh,
                                              unsigned short* __restrict__ outl) {
  int row = blockIdx.x * 2 + (threadIdx.x >> 7);
  int t = threadIdx.x & 127;
  int wave = threadIdx.x >> 6;
  int lane = threadIdx.x & 63;
  size_t base = (size_t)row * DMOD + t * 4;
  float4 x = *(const float4*)(a + base);
  if (BMODE == 2) {
    ushort4 r4 = *(const ushort4*)(b + base);
    x.x += b2f(r4.x); x.y += b2f(r4.y); x.z += b2f(r4.z); x.w += b2f(r4.w);
  }
  float s1 = x.x + x.y + x.z + x.w;
  float s2 = x.x * x.x + x.y * x.y + x.z * x.z + x.w * x.w;
  #pragma unroll
  for (int off = 32; off > 0; off >>= 1) {
    s1 += __shfl_xor(s1, off);
    s2 += __shfl_xor(s2, off);
  }
  __shared__ float sh[8];
  if (lane == 0) { sh[wave * 2] = s1; sh[wave * 2 + 1] = s2; }
  __syncthreads();
  int mate = wave ^ 1;
  s1 += sh[mate * 2];
  s2 += sh[mate * 2 + 1];
  float mu = s1 * (1.0f / 512.0f);
  float var = s2 * (1.0f / 512.0f) - mu * mu;
  float rstd = rsqrtf(var + 1e-5f);
  float4 gg = *(const float4*)(g + t * 4);
  float4 bb = *(const float4*)(be + t * 4);
  float4 o;
  o.x = (x.x - mu) * rstd * gg.x + bb.x;
  o.y = (x.y - mu) * rstd * gg.y + bb.y;
  o.z = (x.z - mu) * rstd * gg.z + bb.z;
  o.w = (x.w - mu) * rstd * gg.w + bb.w;
  *(float4*)(out + base) = o;
  if (OUT == 1) {
    ushort4 ob;
    ob.x = f2b(o.x); ob.y = f2b(o.y); ob.z = f2b(o.z); ob.w = f2b(o.w);
    *(ushort4*)(outb + base) = ob;
  }
  if (OUT == 2) {
    ushort4 hi4, lo4;
    hi4.x = f2b(o.x); lo4.x = f2b(o.x - b2f(hi4.x));
    hi4.y = f2b(o.y); lo4.y = f2b(o.y - b2f(hi4.y));
    hi4.z = f2b(o.z); lo4.z = f2b(o.z - b2f(hi4.z));
    hi4.w = f2b(o.w); lo4.w = f2b(o.w - b2f(hi4.w));
    *(ushort4*)(outh + base) = hi4;
    *(ushort4*)(outl + base) = lo4;
  }
}

// ---------------- head via MFMA: partial[blk*4+w][2688], K-chunk 512/block ----------------
__global__ __launch_bounds__(256) void head_partial_mfma(const unsigned short* __restrict__ hbf,
                                                         const float* __restrict__ Wh,
                                                         float* __restrict__ partial) {
  __shared__ __align__(16) unsigned short Hs[32 * 512];   // 32 KB
  __shared__ __align__(16) unsigned short Ws[96 * 512];   // 96 KB
  int blk = blockIdx.x;            // 0..511
  int k0 = blk * 512;
  int tid = threadIdx.x;
  int wv = tid >> 6, lane = tid & 63;
  int r16 = lane & 15, kq = lane >> 4;

  for (int c = tid; c < 32 * 64; c += 256) {
    int row = c >> 6, col8 = c & 63;
    int src = row < 28 ? row : 0;
    bf16x8 v = *(const bf16x8*)(hbf + (size_t)src * 262144 + k0 + col8 * 8);
    int byte = ((row << 10) | (col8 << 4)) ^ ((row & 7) << 4);
    *(bf16x8*)((char*)Hs + byte) = v;
  }
  for (int c = tid; c < 96 * 64; c += 256) {
    int row = c >> 6, col8 = c & 63;
    const float* src = Wh + (size_t)row * 262144 + k0 + col8 * 8;
    float4 va = *(const float4*)(src);
    float4 vb = *(const float4*)(src + 4);
    bf16x8 o8;
    o8[0] = (short)f2b(va.x); o8[1] = (short)f2b(va.y);
    o8[2] = (short)f2b(va.z); o8[3] = (short)f2b(va.w);
    o8[4] = (short)f2b(vb.x); o8[5] = (short)f2b(vb.y);
    o8[6] = (short)f2b(vb.z); o8[7] = (short)f2b(vb.w);
    int byte = ((row << 10) | (col8 << 4)) ^ ((row & 7) << 4);
    *(bf16x8*)((char*)Ws + byte) = o8;
  }
  __syncthreads();

  f32x4 acc[2][6];
  #pragma unroll
  for (int mt = 0; mt < 2; ++mt)
    #pragma unroll
    for (int nt = 0; nt < 6; ++nt) acc[mt][nt] = (f32x4){0.f, 0.f, 0.f, 0.f};

  #pragma unroll
  for (int kk = 0; kk < 4; ++kk) {
    int kfrag = wv * 4 + kk;     // k = kfrag*32 + kq*8
    bf16x8 afr[2];
    #pragma unroll
    for (int mt = 0; mt < 2; ++mt) {
      int row = mt * 16 + r16;
      int byte = ((row << 10) | (kfrag << 6) | (kq << 4)) ^ ((row & 7) << 4);
      afr[mt] = *(const bf16x8*)((const char*)Hs + byte);
    }
    #pragma unroll
    for (int nt = 0; nt < 6; ++nt) {
      int row = nt * 16 + r16;
      int byte = ((row << 10) | (kfrag << 6) | (kq << 4)) ^ ((row & 7) << 4);
      bf16x8 bfr = *(const bf16x8*)((const char*)Ws + byte);
      #pragma unroll
      for (int mt = 0; mt < 2; ++mt)
        acc[mt][nt] = __builtin_amdgcn_mfma_f32_16x16x32_bf16(afr[mt], bfr, acc[mt][nt], 0, 0, 0);
    }
  }
  size_t prow = (size_t)(blk * 4 + wv) * 2688;
  #pragma unroll
  for (int mt = 0; mt < 2; ++mt)
    #pragma unroll
    for (int nt = 0; nt < 6; ++nt)
      #pragma unroll
      for (int r = 0; r < 4; ++r) {
        int m = mt * 16 + kq * 4 + r;
        int n = nt * 16 + r16;
        if (m < 28) partial[prow + m * 96 + n] = acc[mt][nt][r];
      }
}

// ---------------- head reduce: 84 blocks x 1024 threads (coalesced + parallel) ----------------
__global__ __launch_bounds__(1024) void head_reduce(const float* __restrict__ partial,
                                                    const float* __restrict__ bh_,
                                                    float* __restrict__ out) {
  int blk = blockIdx.x;            // 0..83, columns blk*32..blk*32+31
  int o0 = blk * 32;
  int oo = threadIdx.x & 31;
  int rp = threadIdx.x >> 5;       // 0..31
  float s = 0.f;
  for (int r = rp; r < 2048; r += 32)
    s += partial[(size_t)r * 2688 + o0 + oo];
  __shared__ float red[1024];
  red[threadIdx.x] = s;
  __syncthreads();
  if (rp == 0) {
    float tot = 0.f;
    #pragma unroll
    for (int k = 0; k < 32; ++k) tot += red[k * 32 + oo];
    int o = o0 + oo;
    int m = o / 96, p = o % 96;
    int b = m / NVARS, v = m % NVARS;
    out[(size_t)b * (NPRED * NVARS) + (size_t)p * NVARS + v] = tot + bh_[p];
  }
}

extern "C" void kernel_launch(void* const* d_in, const int* in_sizes, int n_in,
                              void* d_out, int out_size, void* d_ws, size_t ws_size,
                              hipStream_t stream) {
  const float* x_enc = (const float*)d_in[0];
  const float* w_emb = (const float*)d_in[1];
  const float* b_emb = (const float*)d_in[2];
  const float* w_pos = (const float*)d_in[3];
  const float* Wq = (const float*)d_in[4];
  const float* bq = (const float*)d_in[5];
  const float* Wk = (const float*)d_in[6];
  const float* bk = (const float*)d_in[7];
  const float* Wv = (const float*)d_in[8];
  const float* bv_ = (const float*)d_in[9];
  const float* Wo = (const float*)d_in[10];
  const float* bo = (const float*)d_in[11];
  const float* W1 = (const float*)d_in[12];
  const float* b1 = (const float*)d_in[13];
  const float* W2 = (const float*)d_in[14];
  const float* b2 = (const float*)d_in[15];
  const float* g1 = (const float*)d_in[16];
  const float* be1 = (const float*)d_in[17];
  const float* g2 = (const float*)d_in[18];
  const float* be2 = (const float*)d_in[19];
  const float* gF = (const float*)d_in[20];
  const float* bF = (const float*)d_in[21];
  const float* Wh = (const float*)d_in[22];
  const float* bh_ = (const float*)d_in[23];
  float* out = (float*)d_out;

  const size_t S = (size_t)SBIG;
  const size_t SB = S * 4;                    // 29,360,128 B
  char* ws = (char*)d_ws;
  float* h    = (float*)(ws);                 // [0, SB)
  float* QKb  = (float*)(ws + SB);            // [SB, 3SB): [14336][1024] fp32
  unsigned short* Vb   = (unsigned short*)(ws + 3 * SB);            // 14.7 MB
  unsigned short* Ob_b = (unsigned short*)(ws + 3 * SB + SB / 2);   // 14.7 MB
  // weight scratch region [4SB, 5SB)
  unsigned short* Wqk_hi = (unsigned short*)(ws + 4 * SB);                  // 1 MB
  unsigned short* Wqk_lo = (unsigned short*)(ws + 4 * SB + 0x100000);       // 1 MB
  unsigned short* Wv_b = (unsigned short*)(ws + 4 * SB + 0x200000);         // 0.5 MB
  unsigned short* Wo_b = (unsigned short*)(ws + 4 * SB + 0x280000);         // 0.5 MB
  unsigned short* W1_b = (unsigned short*)(ws + 4 * SB + 0x300000);         // 2 MB
  unsigned short* W2_b = (unsigned short*)(ws + 4 * SB + 0x500000);         // 2 MB
  unsigned short* h_hi = (unsigned short*)(ws + 5 * SB);           // SB/2
  unsigned short* h_lo = (unsigned short*)(ws + 5 * SB + SB / 2);  // SB/2
  // phase aliases:
  unsigned short* CTXb = h_hi;                 // after QK+V gemms consumed h_hi
  unsigned short* h_bf = h_lo;                 // after QK gemm consumed h_lo
  unsigned short* FFNb = (unsigned short*)QKb; // after attn consumed QK
  float* partial = QKb;                        // head phase (22 MB <= 2SB)
  int*   idx = (int*)(ws + 6 * SB);                        // 70KB (transposed)
  float* vpart = (float*)(ws + 6 * SB + 0x20000);          // 448KB (224*512 f)
  int*   top = (int*)(ws + 6 * SB + 0xA0000);              // 31KB
  if (ws_size < 6 * SB + 0xC0000) return;

  dim3 b256(256);
  int gVec = (int)(S / 4 / 256);   // 7168

  embed_kernel<<<gVec, b256, 0, stream>>>(x_enc, w_emb, b_emb, w_pos, h, h_hi, h_lo);

  for (int l = 0; l < 2; ++l) {
    const float* Wql = Wq + (size_t)l * DMOD * DMOD;
    const float* Wkl = Wk + (size_t)l * DMOD * DMOD;
    const float* Wvl = Wv + (size_t)l * DMOD * DMOD;
    const float* Wol = Wo + (size_t)l * DMOD * DMOD;
    const float* W1l = W1 + (size_t)l * DFFN * DMOD;
    const float* W2l = W2 + (size_t)l * DMOD * DFFN;

    prep_weights<<<3072, b256, 0, stream>>>(Wql, Wkl, Wvl, Wol, W1l, W2l,
                                            Wqk_hi, Wqk_lo, Wv_b, Wo_b, W1_b, W2_b);

    dim3 gqk(QKS / 128, NROWS / 128);
    gemm_mfma3<<<gqk, b256, 0, stream>>>(h_hi, h_lo, Wqk_hi, Wqk_lo,
                                         bq + l * DMOD, bk + l * DMOD,
                                         QKb, NROWS, QKS, DMOD, QKS);
    dim3 gv(DMOD / 128, NROWS / 128);
    gemm_mfma<0, 1><<<gv, b256, 0, stream>>>(h_hi, Wv_b, bv_ + l * DMOD,
                                             (float*)0, Vb, NROWS, DMOD, DMOD);

    make_idx_kernel<<<(SEQL * NSAMP + 255) / 256, b256, 0, stream>>>(l, idx);
    m2_topk_kernel<<<NBH, dim3(512), 0, stream>>>(QKb, idx, top);
    vmean_part_kernel<<<NBV * 8, b256, 0, stream>>>(Vb, vpart);
    ctx_fill_kernel<<<gVec, b256, 0, stream>>>(vpart, CTXb);
    attn2_kernel<<<NBH, b256, 0, stream>>>(QKb, Vb, top, CTXb);

    dim3 go(DMOD / 128, NROWS / 128);
    gemm_mfma<0, 1><<<go, b256, 0, stream>>>(CTXb, Wo_b, bo + l * DMOD,
                                             (float*)0, Ob_b, NROWS, DMOD, DMOD);
    add_ln<2, 1><<<NROWS / 2, b256, 0, stream>>>(h, Ob_b, g1 + l * DMOD, be1 + l * DMOD,
                                                 h, h_bf, (unsigned short*)0, (unsigned short*)0);

    dim3 gf1(DFFN / 128, NROWS / 128);
    gemm_mfma<1, 1><<<gf1, b256, 0, stream>>>(h_bf, W1_b, b1 + l * DFFN,
                                              (float*)0, FFNb, NROWS, DFFN, DMOD);
    dim3 gf2(DMOD / 128, NROWS / 128);
    gemm_mfma<0, 1><<<gf2, b256, 0, stream>>>(FFNb, W2_b, b2 + l * DMOD,
                                              (float*)0, Ob_b, NROWS, DMOD, DFFN);
    if (l == 0) {
      add_ln<2, 2><<<NROWS / 2, b256, 0, stream>>>(h, Ob_b, g2 + l * DMOD, be2 + l * DMOD,
                                                   h, (unsigned short*)0, h_hi, h_lo);
    } else {
      add_ln<2, 0><<<NROWS / 2, b256, 0, stream>>>(h, Ob_b, g2 + l * DMOD, be2 + l * DMOD,
                                                   h, (unsigned short*)0, (unsigned short*)0, (unsigned short*)0);
    }
  }

  add_ln<0, 1><<<NROWS / 2, b256, 0, stream>>>(h, (const unsigned short*)0, gF, bF,
                                               h, h_bf, (unsigned short*)0, (unsigned short*)0);
  head_partial_mfma<<<512, b256, 0, stream>>>(h_bf, Wh, partial);
  head_reduce<<<84, dim3(1024), 0, stream>>>(partial, bh_, out);
}